// Round 2
// baseline (3384.472 us; speedup 1.0000x reference)
//
#include <hip/hip_runtime.h>

// ---------------------------------------------------------------------------
// Part_65712999629561: ParticleTransformer-ish forward, N=2048, P=64, E=32,
// H=4, D=8, 4 particle layers + 2 cls layers. f32 throughout.
// Kernel A1/A2: batch stats per particle index p (mean over (n,c)).
// Kernel B: one block per sample, fully fused.
// R1: online-softmax attention (chunked 16 keys) to kill VGPR spills;
//     __launch_bounds__(256,2) caps at 128 VGPR.
// ---------------------------------------------------------------------------

__device__ __forceinline__ float4 ld4(const float* p){ return *reinterpret_cast<const float4*>(p); }
__device__ __forceinline__ float dot4(float4 a, float4 b){ return a.x*b.x + a.y*b.y + a.z*b.z + a.w*b.w; }
__device__ __forceinline__ float geluf(float v){ return 0.5f*v*(1.0f + erff(v*0.70710678118654752f)); }

// ---------------- Kernel A: batchnorm stats --------------------------------
__global__ void bn_stats_partial(const float* __restrict__ x, const float* __restrict__ fm,
                                 float* __restrict__ part) {
  int p  = threadIdx.x & 63;
  int rg = threadIdx.x >> 6;
  float s = 0.f, s2 = 0.f;
  for (int R = blockIdx.x*4 + rg; R < 2048*64; R += 1024) {
    int n_ = R >> 6, c = R & 63;
    float v = (c < 60) ? x[n_*3840 + c*64 + p] : fm[n_*256 + (c-60)*64 + p];
    s += v; s2 += v*v;
  }
  __shared__ float sm[256], sm2[256];
  sm[threadIdx.x] = s; sm2[threadIdx.x] = s2;
  __syncthreads();
  if (threadIdx.x < 64) {
    part[blockIdx.x*128 + p]      = sm[p]+sm[64+p]+sm[128+p]+sm[192+p];
    part[blockIdx.x*128 + 64 + p] = sm2[p]+sm2[64+p]+sm2[128+p]+sm2[192+p];
  }
}

__global__ void bn_stats_final(const float* __restrict__ part, float* __restrict__ stats) {
  int p = threadIdx.x; // 64 threads
  float s = 0.f, s2 = 0.f;
  for (int b = 0; b < 256; b++){ s += part[b*128+p]; s2 += part[b*128+64+p]; }
  float mean = s * (1.f/131072.f);
  float var  = s2 * (1.f/131072.f) - mean*mean;
  stats[p]      = mean;
  stats[64+p]   = rsqrtf(var + 1e-5f);
}

// ---------------- row-LN helpers (256 threads, 64 rows, 4 lanes/row) --------
__device__ __forceinline__ void ln_rows32(const float* src, float* dst, int tid){
  int r = tid>>2, g = tid&3;
  const float* row = src + r*36;
  float v[8]; float s = 0.f;
  #pragma unroll
  for (int k=0;k<8;k++){ v[k] = row[g*8+k]; s += v[k]; }
  s += __shfl_xor(s,1); s += __shfl_xor(s,2);
  float mean = s * 0.03125f;
  float q = 0.f;
  #pragma unroll
  for (int k=0;k<8;k++){ float d = v[k]-mean; q += d*d; }
  q += __shfl_xor(q,1); q += __shfl_xor(q,2);
  float irs = rsqrtf(q*0.03125f + 1e-5f);
  float* drow = dst + r*36;
  #pragma unroll
  for (int k=0;k<8;k++) drow[g*8+k] = (v[k]-mean)*irs;
}

__device__ __forceinline__ void ln_rows64(const float* src, float* dst, int tid){
  int r = tid>>2, g = tid&3;
  const float* row = src + r*68;
  float v[16]; float s = 0.f;
  #pragma unroll
  for (int k=0;k<16;k++){ v[k] = row[g*16+k]; s += v[k]; }
  s += __shfl_xor(s,1); s += __shfl_xor(s,2);
  float mean = s * 0.015625f;
  float q = 0.f;
  #pragma unroll
  for (int k=0;k<16;k++){ float d = v[k]-mean; q += d*d; }
  q += __shfl_xor(q,1); q += __shfl_xor(q,2);
  float irs = rsqrtf(q*0.015625f + 1e-5f);
  float* drow = dst + r*68;
  #pragma unroll
  for (int k=0;k<16;k++) drow[g*16+k] = (v[k]-mean)*irs;
}

// ---------------- Kernel B: fused forward, 1 block / sample ----------------
__global__ __launch_bounds__(256, 2) void fused_fwd(
    const float* __restrict__ x, const float* __restrict__ fm, const int* __restrict__ ji,
    const float* __restrict__ bn_w, const float* __restrict__ bn_b,
    const float* __restrict__ e1w, const float* __restrict__ e1b,
    const float* __restrict__ e2w, const float* __restrict__ e2b,
    const float* __restrict__ c1w_g, const float* __restrict__ c1b_g,
    const float* __restrict__ c2w_g, const float* __restrict__ c2b_g,
    const float* __restrict__ pb_in_w, const float* __restrict__ pb_in_b,
    const float* __restrict__ pb_out_w, const float* __restrict__ pb_out_b,
    const float* __restrict__ pb_f1_w, const float* __restrict__ pb_f1_b,
    const float* __restrict__ pb_f2_w, const float* __restrict__ pb_f2_b,
    const float* __restrict__ pb_wres,
    const float* __restrict__ cb_in_w, const float* __restrict__ cb_in_b,
    const float* __restrict__ cb_out_w, const float* __restrict__ cb_out_b,
    const float* __restrict__ cb_f1_w, const float* __restrict__ cb_f1_b,
    const float* __restrict__ cb_f2_w, const float* __restrict__ cb_f2_b,
    const float* __restrict__ cb_wres, const float* __restrict__ cb_cattn,
    const float* __restrict__ cls_tok, const float* __restrict__ norm_w, const float* __restrict__ norm_b,
    const float* __restrict__ m1w, const float* __restrict__ m1b,
    const float* __restrict__ mhw, const float* __restrict__ mhb,
    const float* __restrict__ mfw, const float* __restrict__ mfb,
    const float* __restrict__ stats, float* __restrict__ out)
{
  const int n   = blockIdx.x;
  const int tid = threadIdx.x;

  __shared__ __align__(16) float SX[64*68];   // generic 64x64 (stride 68) / 64x32 (stride 36)
  __shared__ __align__(16) float SY[64*68];   // k_t (32x68) @0, v_t (32x68) @2176; also 64-wide scratch
  __shared__ __align__(16) float SW[3584];    // staged weights (stride 36 or 68), biases @3456, wres @3488
  __shared__ __align__(16) float SH[64*36];   // persistent h (64 tokens x 32)
  __shared__ float SBIAS[324];                // attn bias [h][l][s], l,s<9
  __shared__ float SSTAT[128];                // scale/shift per p
  __shared__ __align__(16) float SV[320];     // small vectors for cls stage
  __shared__ __align__(16) float csh[32];     // cls vector
  __shared__ int s_njet;

  // ---- Phase 0+1: stats, njet, particle quantities, conv weights into SX scratch
  if (tid < 64) {
    float mu = stats[tid], rs = stats[64+tid];
    float sc = rs * bn_w[tid];
    SSTAT[tid]      = sc;
    SSTAT[64+tid]   = bn_b[tid] - mu*sc;
  }
  if (tid == 0) s_njet = ji[n*2+1];
  if (tid < 64) {
    int p = tid;
    float e_  = fm[n*256 + p];
    float px_ = fm[n*256 + 64 + p];
    float py_ = fm[n*256 + 128 + p];
    float pz_ = fm[n*256 + 192 + p];
    float pt_ = sqrtf(px_*px_ + py_*py_ + 1e-8f);
    float y_  = 0.5f * logf((e_ + pz_ + 1e-8f) / (e_ - pz_ + 1e-8f));
    float ph_ = atan2f(py_, px_ + 1e-8f);
    if (ph_ < 0.f) ph_ += 6.283185307179586f;
    SX[0*64+p]=e_; SX[1*64+p]=px_; SX[2*64+p]=py_; SX[3*64+p]=pz_;
    SX[4*64+p]=pt_; SX[5*64+p]=y_; SX[6*64+p]=ph_;
  }
  SX[1472 + tid] = c1w_g[tid];
  if (tid < 4)  SX[1472+256+tid] = c1b_g[tid];
  if (tid < 64) SX[1472+260+tid] = c2w_g[tid];
  if (tid < 4)  SX[1472+324+tid] = c2b_g[tid];
  __syncthreads();

  // ---- Phase 2: conv1 (stride4, k4): out [4][16][16], thread = (ho,wo)
  {
    int ho = tid>>4, wo = tid&15;
    float a0=0.f,a1=0.f,a2=0.f,a3=0.f;
    const float* pq = SX;
    const float* cw = SX + 1472;
    #pragma unroll
    for (int kh=0; kh<4; kh++){
      int r = ho*4+kh;
      float er=pq[r], pxr=pq[64+r], pyr=pq[128+r], pzr=pq[192+r], ptr_=pq[256+r], yr=pq[320+r], phr=pq[384+r];
      #pragma unroll
      for (int kw=0; kw<4; kw++){
        int c = wo*4+kw;
        if (r == c) continue;
        float ec=pq[c], pxc=pq[64+c], pyc=pq[128+c], pzc=pq[192+c], ptc=pq[256+c], yc=pq[320+c], phc=pq[384+c];
        float dy = yr-yc, dp = phr-phc;
        float delta = sqrtf(fabsf(dy*dy + dp*dp));
        float pmin = fminf(ptr_, ptc);
        float kt = pmin * delta;
        float zz = pmin / (ptr_ + ptc + 1e-8f);
        float sx_ = pxr+pxc, sy_ = pyr+pyc, sz_ = pzr+pzc;
        float m2 = er*er + ec*ec - (sx_*sx_ + sy_*sy_ + sz_*sz_);
        int wb = kh*4+kw;
        a0 += delta*cw[0*64+wb] + kt*cw[0*64+16+wb] + zz*cw[0*64+32+wb] + m2*cw[0*64+48+wb];
        a1 += delta*cw[1*64+wb] + kt*cw[1*64+16+wb] + zz*cw[1*64+32+wb] + m2*cw[1*64+48+wb];
        a2 += delta*cw[2*64+wb] + kt*cw[2*64+16+wb] + zz*cw[2*64+32+wb] + m2*cw[2*64+48+wb];
        a3 += delta*cw[3*64+wb] + kt*cw[3*64+16+wb] + zz*cw[3*64+32+wb] + m2*cw[3*64+48+wb];
      }
    }
    SX[448 + 0*256 + tid] = a0 + SX[1472+256+0];
    SX[448 + 1*256 + tid] = a1 + SX[1472+256+1];
    SX[448 + 2*256 + tid] = a2 + SX[1472+256+2];
    SX[448 + 3*256 + tid] = a3 + SX[1472+256+3];
  }
  __syncthreads();

  // ---- Phase 3: conv2 (stride2, k2, pad1) -> SBIAS [co][i][j] (9x9)
  for (int idx = tid; idx < 324; idx += 256) {
    int co = idx/81, rem = idx%81, i = rem/9, j = rem%9;
    float s = SX[1472+324+co];
    #pragma unroll
    for (int ci=0; ci<4; ci++){
      #pragma unroll
      for (int kh=0; kh<2; kh++){
        int ri = 2*i - 1 + kh;
        if (ri < 0 || ri >= 16) continue;
        #pragma unroll
        for (int kw=0; kw<2; kw++){
          int cj = 2*j - 1 + kw;
          if (cj < 0 || cj >= 16) continue;
          s += SX[1472+260 + co*16 + ci*4 + kh*2 + kw] * SX[448 + ci*256 + ri*16 + cj];
        }
      }
    }
    SBIAS[idx] = s;
  }
  __syncthreads();

  // ---- Phase 4: stage normalized xc -> SX [t=c][p], stride 68
  {
    int p = tid & 63;
    float sc = SSTAT[p], sh = SSTAT[64+p];
    for (int c = tid>>6; c < 64; c += 4) {
      float v = (c < 60) ? x[n*3840 + c*64 + p] : fm[n*256 + (c-60)*64 + p];
      SX[c*68 + p] = v*sc + sh;
    }
  }
  __syncthreads();

  // ---- Phase 5: ln rows -> SY
  ln_rows64(SX, SY, tid);
  __syncthreads();

  // ---- Phase 6: e1 GEMM (64x64x64) + gelu -> SX. Weights staged in 2 halves.
  {
    int t = tid>>2, g = tid&3;
    float acc[16];
    for (int idx = tid; idx < 2048; idx += 256){ int o = idx>>5, jj = idx&31; SW[o*36+jj] = e1w[o*64 + jj]; }
    for (int idx = tid; idx < 64; idx += 256) SW[3456+idx] = e1b[idx];
    __syncthreads();
    #pragma unroll
    for (int ee=0; ee<16; ee++) acc[ee] = SW[3456 + g + 4*ee];
    #pragma unroll
    for (int j=0;j<32;j+=4){
      float4 av = ld4(SY + t*68 + j);
      #pragma unroll
      for (int ee=0; ee<16; ee++) acc[ee] += dot4(av, ld4(SW + (g+4*ee)*36 + j));
    }
    __syncthreads();
    for (int idx = tid; idx < 2048; idx += 256){ int o = idx>>5, jj = idx&31; SW[o*36+jj] = e1w[o*64 + 32 + jj]; }
    __syncthreads();
    #pragma unroll
    for (int j=0;j<32;j+=4){
      float4 av = ld4(SY + t*68 + 32 + j);
      #pragma unroll
      for (int ee=0; ee<16; ee++) acc[ee] += dot4(av, ld4(SW + (g+4*ee)*36 + j));
    }
    #pragma unroll
    for (int ee=0; ee<16; ee++) SX[t*68 + g + 4*ee] = geluf(acc[ee]);
  }
  __syncthreads();

  // ---- Phase 7: ln rows SX -> SY; stage e2 (32x64, stride 68) + bias
  ln_rows64(SX, SY, tid);
  for (int idx = tid; idx < 2048; idx += 256){ int o = idx>>6, j = idx&63; SW[o*68+j] = e2w[idx]; }
  for (int idx = tid; idx < 32; idx += 256) SW[3456+idx] = e2b[idx];
  __syncthreads();

  // ---- Phase 8: e2 GEMM (64x32x64) + gelu -> SH (stride 36)
  {
    int t = tid>>2, g = tid&3;
    float acc[8];
    #pragma unroll
    for (int ee=0; ee<8; ee++) acc[ee] = SW[3456 + g + 4*ee];
    #pragma unroll
    for (int j=0;j<64;j+=4){
      float4 av = ld4(SY + t*68 + j);
      #pragma unroll
      for (int ee=0; ee<8; ee++) acc[ee] += dot4(av, ld4(SW + (g+4*ee)*68 + j));
    }
    #pragma unroll
    for (int ee=0; ee<8; ee++) SH[t*36 + g + 4*ee] = geluf(acc[ee]);
  }
  __syncthreads();

  // ================== 4 particle transformer layers =========================
  for (int li = 0; li < 4; li++) {
    const float* in_w  = pb_in_w  + li*3072;
    const float* in_b  = pb_in_b  + li*96;
    const float* out_w = pb_out_w + li*1024;
    const float* out_b = pb_out_b + li*32;
    const float* f1w   = pb_f1_w  + li*2048;
    const float* f1b   = pb_f1_b  + li*64;
    const float* f2w   = pb_f2_w  + li*2048;
    const float* f2b   = pb_f2_b  + li*32;
    const float* wres  = pb_wres  + li*32;

    // L1: a = ln(h) -> SX (stride 36); stage in_w (96x32 -> stride 36) + in_b
    ln_rows32(SH, SX, tid);
    for (int idx = tid; idx < 3072; idx += 256){ int e = idx>>5, j = idx&31; SW[e*36+j] = in_w[idx]; }
    for (int idx = tid; idx < 96; idx += 256) SW[3456+idx] = in_b[idx];
    __syncthreads();

    // L2: k,v GEMM (64 tokens x 64 outs), write transposed into SY
    {
      int t = tid>>2, g = tid&3;
      float acc[16];
      #pragma unroll
      for (int ee=0; ee<16; ee++) acc[ee] = SW[3456 + 32 + g + 4*ee];
      #pragma unroll
      for (int j=0;j<32;j+=4){
        float4 av = ld4(SX + t*36 + j);
        #pragma unroll
        for (int ee=0; ee<16; ee++) acc[ee] += dot4(av, ld4(SW + (32+g+4*ee)*36 + j));
      }
      #pragma unroll
      for (int ee=0; ee<16; ee++){
        int ew = 32 + g + 4*ee;
        if (ew < 64) SY[(ew-32)*68 + t] = acc[ee];
        else         SY[2176 + (ew-64)*68 + t] = acc[ee];
      }
    }
    __syncthreads();

    // L3: attention (online softmax over 16-key chunks). wave=head, lane=query.
    float od[8];
    {
      int hh = tid>>6, l = tid&63;
      float qd[8];
      #pragma unroll
      for (int d=0;d<8;d++){
        int e = hh*8+d;
        float a_ = SW[3456+e];
        #pragma unroll
        for (int k=0;k<8;k++) a_ += dot4(ld4(SX + l*36 + k*4), ld4(SW + e*36 + k*4));
        qd[d] = a_ * 0.35355339059327373f;
      }
      int njet = s_njet;
      float m = -3.4e38f, lsum = 0.f;
      #pragma unroll
      for (int d=0;d<8;d++) od[d] = 0.f;
      #pragma unroll
      for (int s0 = 0; s0 < 64; s0 += 16) {
        float sc[16];
        #pragma unroll
        for (int j=0;j<16;j++) sc[j]=0.f;
        #pragma unroll
        for (int d=0;d<8;d++){
          const float* kr = SY + (hh*8+d)*68 + s0;
          float qv = qd[d];
          #pragma unroll
          for (int j=0;j<16;j+=4){
            float4 kv4 = ld4(kr+j);
            sc[j]  +=qv*kv4.x; sc[j+1]+=qv*kv4.y;
            sc[j+2]+=qv*kv4.z; sc[j+3]+=qv*kv4.w;
          }
        }
        float cm = -3.4e38f;
        #pragma unroll
        for (int j=0;j<16;j++){
          int s = s0+j;
          float a_ = sc[j];
          if (s0 == 0 && l < 9 && j < 9) a_ += SBIAS[hh*81 + l*9 + j];
          a_ = (s >= njet) ? -1000000000.0f : a_;
          sc[j] = a_;
          cm = fmaxf(cm, a_);
        }
        float nm = fmaxf(m, cm);
        float corr = __expf(m - nm);        // first chunk: exp(-inf)=0
        lsum *= corr;
        #pragma unroll
        for (int d=0;d<8;d++) od[d] *= corr;
        #pragma unroll
        for (int j=0;j<16;j++){ sc[j] = __expf(sc[j]-nm); lsum += sc[j]; }
        #pragma unroll
        for (int d=0;d<8;d++){
          const float* vr = SY + 2176 + (hh*8+d)*68 + s0;
          float a_ = 0.f;
          #pragma unroll
          for (int j=0;j<16;j+=4){
            float4 vv = ld4(vr+j);
            a_ += sc[j]*vv.x + sc[j+1]*vv.y + sc[j+2]*vv.z + sc[j+3]*vv.w;
          }
          od[d] += a_;
        }
        m = nm;
      }
      float inv = 1.f/lsum;
      #pragma unroll
      for (int d=0;d<8;d++) od[d] *= inv;
    }
    __syncthreads();          // everyone done reading SX (a) and SW
    {
      int hh = tid>>6, l = tid&63;
      #pragma unroll
      for (int d=0;d<8;d++) SX[l*36 + hh*8 + d] = od[d];
    }
    for (int idx = tid; idx < 1024; idx += 256){ int e = idx>>5, j = idx&31; SW[e*36+j] = out_w[idx]; }
    for (int idx = tid; idx < 32; idx += 256) SW[3456+idx] = out_b[idx];
    __syncthreads();

    // L4: out-proj GEMM -> y in SY (stride 36)
    {
      int t = tid>>2, g = tid&3;
      float acc[8];
      #pragma unroll
      for (int ee=0; ee<8; ee++) acc[ee] = SW[3456 + g + 4*ee];
      #pragma unroll
      for (int j=0;j<32;j+=4){
        float4 av = ld4(SX + t*36 + j);
        #pragma unroll
        for (int ee=0; ee<8; ee++) acc[ee] += dot4(av, ld4(SW + (g+4*ee)*36 + j));
      }
      #pragma unroll
      for (int ee=0; ee<8; ee++) SY[t*36 + g + 4*ee] = acc[ee];
    }
    __syncthreads();

    // L5: h = ln(y) + h
    {
      int r = tid>>2, g = tid&3;
      const float* row = SY + r*36;
      float v[8]; float s = 0.f;
      #pragma unroll
      for (int k=0;k<8;k++){ v[k] = row[g*8+k]; s += v[k]; }
      s += __shfl_xor(s,1); s += __shfl_xor(s,2);
      float mean = s * 0.03125f;
      float q = 0.f;
      #pragma unroll
      for (int k=0;k<8;k++){ float d = v[k]-mean; q += d*d; }
      q += __shfl_xor(q,1); q += __shfl_xor(q,2);
      float irs = rsqrtf(q*0.03125f + 1e-5f);
      #pragma unroll
      for (int k=0;k<8;k++){ int e = g*8+k; SH[r*36+e] = (v[k]-mean)*irs + SH[r*36+e]; }
    }
    __syncthreads();

    // L6: t = ln(h) -> SX; stage f1 (64x32)
    ln_rows32(SH, SX, tid);
    for (int idx = tid; idx < 2048; idx += 256){ int e = idx>>5, j = idx&31; SW[e*36+j] = f1w[idx]; }
    for (int idx = tid; idx < 64; idx += 256) SW[3456+idx] = f1b[idx];
    __syncthreads();

    // L7: g1 = gelu(GEMM 64x64x32) -> SY stride 68
    {
      int t = tid>>2, g = tid&3;
      float acc[16];
      #pragma unroll
      for (int ee=0; ee<16; ee++) acc[ee] = SW[3456 + g + 4*ee];
      #pragma unroll
      for (int j=0;j<32;j+=4){
        float4 av = ld4(SX + t*36 + j);
        #pragma unroll
        for (int ee=0; ee<16; ee++) acc[ee] += dot4(av, ld4(SW + (g+4*ee)*36 + j));
      }
      #pragma unroll
      for (int ee=0; ee<16; ee++) SY[t*68 + g + 4*ee] = geluf(acc[ee]);
    }
    __syncthreads();

    // L8: ln64 rows SY -> SX; stage f2 (32x64, stride 68) + bias + wres
    ln_rows64(SY, SX, tid);
    for (int idx = tid; idx < 2048; idx += 256){ int e = idx>>6, j = idx&63; SW[e*68+j] = f2w[idx]; }
    for (int idx = tid; idx < 32; idx += 256){ SW[3456+idx] = f2b[idx]; SW[3488+idx] = wres[idx]; }
    __syncthreads();

    // L9: g2 GEMM (64x32x64); h = g2 + wres*h
    {
      int t = tid>>2, g = tid&3;
      float acc[8];
      #pragma unroll
      for (int ee=0; ee<8; ee++) acc[ee] = SW[3456 + g + 4*ee];
      #pragma unroll
      for (int j=0;j<64;j+=4){
        float4 av = ld4(SX + t*68 + j);
        #pragma unroll
        for (int ee=0; ee<8; ee++) acc[ee] += dot4(av, ld4(SW + (g+4*ee)*68 + j));
      }
      #pragma unroll
      for (int ee=0; ee<8; ee++){ int e = g+4*ee; SH[t*36+e] = acc[ee] + SW[3488+e]*SH[t*36+e]; }
    }
    __syncthreads();
  }

  // ================== cls-attention layers ==================================
  ln_rows32(SH, SX, tid);
  if (tid < 32) csh[tid] = cls_tok[tid];
  __syncthreads();

  for (int cl = 0; cl < 2; cl++) {
    const float* iw = cb_in_w + cl*3072;
    const float* ib = cb_in_b + cl*96;

    // C1: u0 = ln(csh) -> SV[0..31]; stage iw/ib
    if (tid < 32) {
      float v = csh[tid];
      float s = v;
      s += __shfl_xor(s,1); s += __shfl_xor(s,2); s += __shfl_xor(s,4); s += __shfl_xor(s,8); s += __shfl_xor(s,16);
      float mean = s * 0.03125f;
      float d = v - mean;
      float q = d*d;
      q += __shfl_xor(q,1); q += __shfl_xor(q,2); q += __shfl_xor(q,4); q += __shfl_xor(q,8); q += __shfl_xor(q,16);
      float irs = rsqrtf(q*0.03125f + 1e-5f);
      SV[tid] = d*irs;
    }
    for (int idx = tid; idx < 3072; idx += 256){ int e = idx>>5, j = idx&31; SW[e*36+j] = iw[idx]; }
    for (int idx = tid; idx < 96; idx += 256) SW[3456+idx] = ib[idx];
    __syncthreads();

    // C2: q from raw cls (tid<32) -> SV[32..63]; C3: k,v over 65 rows -> SY
    if (tid < 32) {
      int e = tid;
      float a_ = SW[3456+e];
      #pragma unroll
      for (int k=0;k<8;k++) a_ += dot4(ld4(&csh[k*4]), ld4(SW + e*36 + k*4));
      SV[32+e] = a_ * 0.35355339059327373f;
    }
    {
      int g = tid & 3;
      for (int s = tid>>2; s < 65; s += 64) {
        const float* u = (s == 0) ? SV : (SX + (s-1)*36);
        float4 uv[8];
        #pragma unroll
        for (int k=0;k<8;k++) uv[k] = ld4(u + k*4);
        #pragma unroll
        for (int ee=0; ee<16; ee++){
          int ew = 32 + g + 4*ee;
          float a_ = SW[3456+ew];
          #pragma unroll
          for (int k=0;k<8;k++) a_ += dot4(uv[k], ld4(SW + ew*36 + k*4));
          if (ew < 64) SY[(ew-32)*68 + s] = a_;
          else         SY[2176 + (ew-64)*68 + s] = a_;
        }
      }
    }
    __syncthreads();

    // C4: attention over 65 keys; wave=head, lane=key (lane0 also key 64)
    {
      int hh = tid>>6, l = tid&63;
      int njet = s_njet;
      float q8[8];
      #pragma unroll
      for (int d=0;d<8;d++) q8[d] = SV[32 + hh*8 + d];
      float sc_ = 0.f;
      #pragma unroll
      for (int d=0;d<8;d++) sc_ += q8[d]*SY[(hh*8+d)*68 + l];
      if (l > 0 && (l-1) >= njet) sc_ = -1000000000.0f;
      float sc64 = 0.f;
      if (l == 0){
        #pragma unroll
        for (int d=0;d<8;d++) sc64 += q8[d]*SY[(hh*8+d)*68 + 64];
        if (63 >= njet) sc64 = -1000000000.0f;
      }
      float mx = sc_;
      if (l == 0) mx = fmaxf(mx, sc64);
      mx = fmaxf(mx, __shfl_xor(mx,1));  mx = fmaxf(mx, __shfl_xor(mx,2));
      mx = fmaxf(mx, __shfl_xor(mx,4));  mx = fmaxf(mx, __shfl_xor(mx,8));
      mx = fmaxf(mx, __shfl_xor(mx,16)); mx = fmaxf(mx, __shfl_xor(mx,32));
      float p   = __expf(sc_ - mx);
      float p64 = (l==0) ? __expf(sc64 - mx) : 0.f;
      float ssum = p + p64;
      ssum += __shfl_xor(ssum,1); ssum += __shfl_xor(ssum,2); ssum += __shfl_xor(ssum,4);
      ssum += __shfl_xor(ssum,8); ssum += __shfl_xor(ssum,16); ssum += __shfl_xor(ssum,32);
      float inv = 1.f/ssum;
      #pragma unroll
      for (int d=0;d<8;d++){
        float term = p * SY[2176 + (hh*8+d)*68 + l];
        if (l == 0) term += p64 * SY[2176 + (hh*8+d)*68 + 64];
        term += __shfl_xor(term,1); term += __shfl_xor(term,2); term += __shfl_xor(term,4);
        term += __shfl_xor(term,8); term += __shfl_xor(term,16); term += __shfl_xor(term,32);
        if (l == 0) SV[64 + hh*8 + d] = term*inv;
      }
    }
    __syncthreads();

    // C5: out proj + cattn permute -> SV[96..127]
    if (tid < 32) {
      int e = tid;
      const float* wrow = cb_out_w + (cl*32 + e)*32;
      float a_ = cb_out_b[cl*32 + e];
      #pragma unroll
      for (int j=0;j<32;j++) a_ += SV[64+j]*wrow[j];
      float ca = cb_cattn[cl*4 + (e>>3)];
      SV[96 + (e&7)*4 + (e>>3)] = a_*ca;
    }
    __syncthreads();

    // C6: cls = ln(a2) + cls
    if (tid < 32) {
      float v = SV[96+tid];
      float s = v;
      s += __shfl_xor(s,1); s += __shfl_xor(s,2); s += __shfl_xor(s,4); s += __shfl_xor(s,8); s += __shfl_xor(s,16);
      float mean = s * 0.03125f;
      float d = v - mean;
      float q = d*d;
      q += __shfl_xor(q,1); q += __shfl_xor(q,2); q += __shfl_xor(q,4); q += __shfl_xor(q,8); q += __shfl_xor(q,16);
      float irs = rsqrtf(q*0.03125f + 1e-5f);
      csh[tid] = d*irs + csh[tid];
    }
    __syncthreads();

    // C7: FFN on cls vector
    if (tid < 32) {
      float v = csh[tid];
      float s = v;
      s += __shfl_xor(s,1); s += __shfl_xor(s,2); s += __shfl_xor(s,4); s += __shfl_xor(s,8); s += __shfl_xor(s,16);
      float mean = s * 0.03125f;
      float d = v - mean;
      float q = d*d;
      q += __shfl_xor(q,1); q += __shfl_xor(q,2); q += __shfl_xor(q,4); q += __shfl_xor(q,8); q += __shfl_xor(q,16);
      float irs = rsqrtf(q*0.03125f + 1e-5f);
      SV[tid] = d*irs;
    }
    __syncthreads();
    if (tid < 64) {
      int o = tid;
      const float* wrow = cb_f1_w + (cl*64+o)*32;
      float a_ = cb_f1_b[cl*64+o];
      #pragma unroll
      for (int j=0;j<32;j++) a_ += SV[j]*wrow[j];
      SV[128+o] = geluf(a_);
    }
    __syncthreads();
    if (tid < 64) {
      float v = SV[128+tid];
      float s = v;
      s += __shfl_xor(s,1); s += __shfl_xor(s,2); s += __shfl_xor(s,4); s += __shfl_xor(s,8);
      s += __shfl_xor(s,16); s += __shfl_xor(s,32);
      float mean = s * 0.015625f;
      float d = v - mean;
      float q = d*d;
      q += __shfl_xor(q,1); q += __shfl_xor(q,2); q += __shfl_xor(q,4); q += __shfl_xor(q,8);
      q += __shfl_xor(q,16); q += __shfl_xor(q,32);
      float irs = rsqrtf(q*0.015625f + 1e-5f);
      SV[192+tid] = d*irs;
    }
    __syncthreads();
    if (tid < 32) {
      int e = tid;
      const float* wrow = cb_f2_w + (cl*32+e)*64;
      float a_ = cb_f2_b[cl*32+e];
      #pragma unroll
      for (int j=0;j<64;j++) a_ += SV[192+j]*wrow[j];
      csh[e] = a_ + cb_wres[cl*32+e]*csh[e];
    }
    __syncthreads();
  }

  // ================== head ==================================================
  if (tid < 32) {
    float v = csh[tid];
    float s = v;
    s += __shfl_xor(s,1); s += __shfl_xor(s,2); s += __shfl_xor(s,4); s += __shfl_xor(s,8); s += __shfl_xor(s,16);
    float mean = s * 0.03125f;
    float d = v - mean;
    float q = d*d;
    q += __shfl_xor(q,1); q += __shfl_xor(q,2); q += __shfl_xor(q,4); q += __shfl_xor(q,8); q += __shfl_xor(q,16);
    float irs = rsqrtf(q*0.03125f + 1e-5f);
    SV[tid] = d*irs*norm_w[tid] + norm_b[tid];
  }
  __syncthreads();
  if (tid < 32) {
    float a_ = m1b[tid];
    const float* wrow = m1w + tid*32;
    #pragma unroll
    for (int j=0;j<32;j++) a_ += SV[j]*wrow[j];
    SV[64+tid] = fmaxf(a_, 0.f);
  }
  __syncthreads();
  if (tid < 32) {
    float a_ = mhb[tid];
    const float* wrow = mhw + tid*32;
    #pragma unroll
    for (int j=0;j<32;j++) a_ += SV[64+j]*wrow[j];
    SV[128+tid] = fmaxf(a_, 0.f);
  }
  __syncthreads();
  if (tid == 0) {
    float a_ = mfb[0];
    #pragma unroll
    for (int j=0;j<32;j++) a_ += SV[128+j]*mfw[j];
    out[n] = 1.f/(1.f + expf(-a_));
  }
}

// ---------------------------------------------------------------------------
extern "C" void kernel_launch(void* const* d_in, const int* in_sizes, int n_in,
                              void* d_out, int out_size, void* d_ws, size_t ws_size,
                              hipStream_t stream) {
  (void)in_sizes; (void)n_in; (void)out_size; (void)ws_size;
  const float* x     = (const float*)d_in[0];
  const float* fm    = (const float*)d_in[1];
  const int*   ji    = (const int*)  d_in[2];
  const float* bn_w  = (const float*)d_in[3];
  const float* bn_b  = (const float*)d_in[4];
  const float* e1w   = (const float*)d_in[5];
  const float* e1b   = (const float*)d_in[6];
  const float* e2w   = (const float*)d_in[7];
  const float* e2b   = (const float*)d_in[8];
  const float* c1w   = (const float*)d_in[9];
  const float* c1b   = (const float*)d_in[10];
  const float* c2w   = (const float*)d_in[11];
  const float* c2b   = (const float*)d_in[12];
  const float* pb_in_w  = (const float*)d_in[13];
  const float* pb_in_b  = (const float*)d_in[14];
  const float* pb_out_w = (const float*)d_in[15];
  const float* pb_out_b = (const float*)d_in[16];
  const float* pb_f1_w  = (const float*)d_in[17];
  const float* pb_f1_b  = (const float*)d_in[18];
  const float* pb_f2_w  = (const float*)d_in[19];
  const float* pb_f2_b  = (const float*)d_in[20];
  const float* pb_wres  = (const float*)d_in[21];
  const float* cb_in_w  = (const float*)d_in[22];
  const float* cb_in_b  = (const float*)d_in[23];
  const float* cb_out_w = (const float*)d_in[24];
  const float* cb_out_b = (const float*)d_in[25];
  const float* cb_f1_w  = (const float*)d_in[26];
  const float* cb_f1_b  = (const float*)d_in[27];
  const float* cb_f2_w  = (const float*)d_in[28];
  const float* cb_f2_b  = (const float*)d_in[29];
  const float* cb_wres  = (const float*)d_in[30];
  const float* cb_cattn = (const float*)d_in[31];
  const float* cls_tok  = (const float*)d_in[32];
  const float* norm_w   = (const float*)d_in[33];
  const float* norm_b   = (const float*)d_in[34];
  const float* m1w      = (const float*)d_in[35];
  const float* m1b      = (const float*)d_in[36];
  const float* mhw      = (const float*)d_in[37];
  const float* mhb      = (const float*)d_in[38];
  const float* mfw      = (const float*)d_in[39];
  const float* mfb      = (const float*)d_in[40];

  float* part  = (float*)d_ws;            // 256*128 floats
  float* stats = part + 256*128;          // 128 floats

  bn_stats_partial<<<256, 256, 0, stream>>>(x, fm, part);
  bn_stats_final<<<1, 64, 0, stream>>>(part, stats);
  fused_fwd<<<2048, 256, 0, stream>>>(
      x, fm, ji, bn_w, bn_b, e1w, e1b, e2w, e2b, c1w, c1b, c2w, c2b,
      pb_in_w, pb_in_b, pb_out_w, pb_out_b, pb_f1_w, pb_f1_b, pb_f2_w, pb_f2_b, pb_wres,
      cb_in_w, cb_in_b, cb_out_w, cb_out_b, cb_f1_w, cb_f1_b, cb_f2_w, cb_f2_b,
      cb_wres, cb_cattn, cls_tok, norm_w, norm_b, m1w, m1b, mhw, mhb, mfw, mfb,
      stats, (float*)d_out);
}

// Round 3
// 2336.646 us; speedup vs baseline: 1.4484x; 1.4484x over previous
//
#include <hip/hip_runtime.h>

// ---------------------------------------------------------------------------
// Part_65712999629561: ParticleTransformer-ish forward, N=2048, P=64, E=32,
// H=4, D=8, 4 particle layers + 2 cls layers. f32 throughout.
// Kernel A1/A2: batch stats per particle index p (mean over (n,c)).
// Kernel B: one block per sample, fully fused.
// R1: online-softmax attention (chunked 16 keys) to cut attention reg demand.
// R2: __launch_bounds__(256) only — the (256,2) variant lowered to a 128-VGPR
//     cap and spilled 8.7 GB/dispatch. Let allocator land in the 129-256 band
//     (2 waves/SIMD, same occupancy as LDS cap of 2 blocks/CU) with no spill.
// ---------------------------------------------------------------------------

__device__ __forceinline__ float4 ld4(const float* p){ return *reinterpret_cast<const float4*>(p); }
__device__ __forceinline__ float dot4(float4 a, float4 b){ return a.x*b.x + a.y*b.y + a.z*b.z + a.w*b.w; }
__device__ __forceinline__ float geluf(float v){ return 0.5f*v*(1.0f + erff(v*0.70710678118654752f)); }

// ---------------- Kernel A: batchnorm stats --------------------------------
__global__ void bn_stats_partial(const float* __restrict__ x, const float* __restrict__ fm,
                                 float* __restrict__ part) {
  int p  = threadIdx.x & 63;
  int rg = threadIdx.x >> 6;
  float s = 0.f, s2 = 0.f;
  for (int R = blockIdx.x*4 + rg; R < 2048*64; R += 1024) {
    int n_ = R >> 6, c = R & 63;
    float v = (c < 60) ? x[n_*3840 + c*64 + p] : fm[n_*256 + (c-60)*64 + p];
    s += v; s2 += v*v;
  }
  __shared__ float sm[256], sm2[256];
  sm[threadIdx.x] = s; sm2[threadIdx.x] = s2;
  __syncthreads();
  if (threadIdx.x < 64) {
    part[blockIdx.x*128 + p]      = sm[p]+sm[64+p]+sm[128+p]+sm[192+p];
    part[blockIdx.x*128 + 64 + p] = sm2[p]+sm2[64+p]+sm2[128+p]+sm2[192+p];
  }
}

__global__ void bn_stats_final(const float* __restrict__ part, float* __restrict__ stats) {
  int p = threadIdx.x; // 64 threads
  float s = 0.f, s2 = 0.f;
  for (int b = 0; b < 256; b++){ s += part[b*128+p]; s2 += part[b*128+64+p]; }
  float mean = s * (1.f/131072.f);
  float var  = s2 * (1.f/131072.f) - mean*mean;
  stats[p]      = mean;
  stats[64+p]   = rsqrtf(var + 1e-5f);
}

// ---------------- row-LN helpers (256 threads, 64 rows, 4 lanes/row) --------
__device__ __forceinline__ void ln_rows32(const float* src, float* dst, int tid){
  int r = tid>>2, g = tid&3;
  const float* row = src + r*36;
  float v[8]; float s = 0.f;
  #pragma unroll
  for (int k=0;k<8;k++){ v[k] = row[g*8+k]; s += v[k]; }
  s += __shfl_xor(s,1); s += __shfl_xor(s,2);
  float mean = s * 0.03125f;
  float q = 0.f;
  #pragma unroll
  for (int k=0;k<8;k++){ float d = v[k]-mean; q += d*d; }
  q += __shfl_xor(q,1); q += __shfl_xor(q,2);
  float irs = rsqrtf(q*0.03125f + 1e-5f);
  float* drow = dst + r*36;
  #pragma unroll
  for (int k=0;k<8;k++) drow[g*8+k] = (v[k]-mean)*irs;
}

__device__ __forceinline__ void ln_rows64(const float* src, float* dst, int tid){
  int r = tid>>2, g = tid&3;
  const float* row = src + r*68;
  float v[16]; float s = 0.f;
  #pragma unroll
  for (int k=0;k<16;k++){ v[k] = row[g*16+k]; s += v[k]; }
  s += __shfl_xor(s,1); s += __shfl_xor(s,2);
  float mean = s * 0.015625f;
  float q = 0.f;
  #pragma unroll
  for (int k=0;k<16;k++){ float d = v[k]-mean; q += d*d; }
  q += __shfl_xor(q,1); q += __shfl_xor(q,2);
  float irs = rsqrtf(q*0.015625f + 1e-5f);
  float* drow = dst + r*68;
  #pragma unroll
  for (int k=0;k<16;k++) drow[g*16+k] = (v[k]-mean)*irs;
}

// ---------------- Kernel B: fused forward, 1 block / sample ----------------
__global__ __launch_bounds__(256) void fused_fwd(
    const float* __restrict__ x, const float* __restrict__ fm, const int* __restrict__ ji,
    const float* __restrict__ bn_w, const float* __restrict__ bn_b,
    const float* __restrict__ e1w, const float* __restrict__ e1b,
    const float* __restrict__ e2w, const float* __restrict__ e2b,
    const float* __restrict__ c1w_g, const float* __restrict__ c1b_g,
    const float* __restrict__ c2w_g, const float* __restrict__ c2b_g,
    const float* __restrict__ pb_in_w, const float* __restrict__ pb_in_b,
    const float* __restrict__ pb_out_w, const float* __restrict__ pb_out_b,
    const float* __restrict__ pb_f1_w, const float* __restrict__ pb_f1_b,
    const float* __restrict__ pb_f2_w, const float* __restrict__ pb_f2_b,
    const float* __restrict__ pb_wres,
    const float* __restrict__ cb_in_w, const float* __restrict__ cb_in_b,
    const float* __restrict__ cb_out_w, const float* __restrict__ cb_out_b,
    const float* __restrict__ cb_f1_w, const float* __restrict__ cb_f1_b,
    const float* __restrict__ cb_f2_w, const float* __restrict__ cb_f2_b,
    const float* __restrict__ cb_wres, const float* __restrict__ cb_cattn,
    const float* __restrict__ cls_tok, const float* __restrict__ norm_w, const float* __restrict__ norm_b,
    const float* __restrict__ m1w, const float* __restrict__ m1b,
    const float* __restrict__ mhw, const float* __restrict__ mhb,
    const float* __restrict__ mfw, const float* __restrict__ mfb,
    const float* __restrict__ stats, float* __restrict__ out)
{
  const int n   = blockIdx.x;
  const int tid = threadIdx.x;

  __shared__ __align__(16) float SX[64*68];   // generic 64x64 (stride 68) / 64x32 (stride 36)
  __shared__ __align__(16) float SY[64*68];   // k_t (32x68) @0, v_t (32x68) @2176; also 64-wide scratch
  __shared__ __align__(16) float SW[3584];    // staged weights (stride 36 or 68), biases @3456, wres @3488
  __shared__ __align__(16) float SH[64*36];   // persistent h (64 tokens x 32)
  __shared__ float SBIAS[324];                // attn bias [h][l][s], l,s<9
  __shared__ float SSTAT[128];                // scale/shift per p
  __shared__ __align__(16) float SV[320];     // small vectors for cls stage
  __shared__ __align__(16) float csh[32];     // cls vector
  __shared__ int s_njet;

  // ---- Phase 0+1: stats, njet, particle quantities, conv weights into SX scratch
  if (tid < 64) {
    float mu = stats[tid], rs = stats[64+tid];
    float sc = rs * bn_w[tid];
    SSTAT[tid]      = sc;
    SSTAT[64+tid]   = bn_b[tid] - mu*sc;
  }
  if (tid == 0) s_njet = ji[n*2+1];
  if (tid < 64) {
    int p = tid;
    float e_  = fm[n*256 + p];
    float px_ = fm[n*256 + 64 + p];
    float py_ = fm[n*256 + 128 + p];
    float pz_ = fm[n*256 + 192 + p];
    float pt_ = sqrtf(px_*px_ + py_*py_ + 1e-8f);
    float y_  = 0.5f * logf((e_ + pz_ + 1e-8f) / (e_ - pz_ + 1e-8f));
    float ph_ = atan2f(py_, px_ + 1e-8f);
    if (ph_ < 0.f) ph_ += 6.283185307179586f;
    SX[0*64+p]=e_; SX[1*64+p]=px_; SX[2*64+p]=py_; SX[3*64+p]=pz_;
    SX[4*64+p]=pt_; SX[5*64+p]=y_; SX[6*64+p]=ph_;
  }
  SX[1472 + tid] = c1w_g[tid];
  if (tid < 4)  SX[1472+256+tid] = c1b_g[tid];
  if (tid < 64) SX[1472+260+tid] = c2w_g[tid];
  if (tid < 4)  SX[1472+324+tid] = c2b_g[tid];
  __syncthreads();

  // ---- Phase 2: conv1 (stride4, k4): out [4][16][16], thread = (ho,wo)
  {
    int ho = tid>>4, wo = tid&15;
    float a0=0.f,a1=0.f,a2=0.f,a3=0.f;
    const float* pq = SX;
    const float* cw = SX + 1472;
    #pragma unroll
    for (int kh=0; kh<4; kh++){
      int r = ho*4+kh;
      float er=pq[r], pxr=pq[64+r], pyr=pq[128+r], pzr=pq[192+r], ptr_=pq[256+r], yr=pq[320+r], phr=pq[384+r];
      #pragma unroll
      for (int kw=0; kw<4; kw++){
        int c = wo*4+kw;
        if (r == c) continue;
        float ec=pq[c], pxc=pq[64+c], pyc=pq[128+c], pzc=pq[192+c], ptc=pq[256+c], yc=pq[320+c], phc=pq[384+c];
        float dy = yr-yc, dp = phr-phc;
        float delta = sqrtf(fabsf(dy*dy + dp*dp));
        float pmin = fminf(ptr_, ptc);
        float kt = pmin * delta;
        float zz = pmin / (ptr_ + ptc + 1e-8f);
        float sx_ = pxr+pxc, sy_ = pyr+pyc, sz_ = pzr+pzc;
        float m2 = er*er + ec*ec - (sx_*sx_ + sy_*sy_ + sz_*sz_);
        int wb = kh*4+kw;
        a0 += delta*cw[0*64+wb] + kt*cw[0*64+16+wb] + zz*cw[0*64+32+wb] + m2*cw[0*64+48+wb];
        a1 += delta*cw[1*64+wb] + kt*cw[1*64+16+wb] + zz*cw[1*64+32+wb] + m2*cw[1*64+48+wb];
        a2 += delta*cw[2*64+wb] + kt*cw[2*64+16+wb] + zz*cw[2*64+32+wb] + m2*cw[2*64+48+wb];
        a3 += delta*cw[3*64+wb] + kt*cw[3*64+16+wb] + zz*cw[3*64+32+wb] + m2*cw[3*64+48+wb];
      }
    }
    SX[448 + 0*256 + tid] = a0 + SX[1472+256+0];
    SX[448 + 1*256 + tid] = a1 + SX[1472+256+1];
    SX[448 + 2*256 + tid] = a2 + SX[1472+256+2];
    SX[448 + 3*256 + tid] = a3 + SX[1472+256+3];
  }
  __syncthreads();

  // ---- Phase 3: conv2 (stride2, k2, pad1) -> SBIAS [co][i][j] (9x9)
  for (int idx = tid; idx < 324; idx += 256) {
    int co = idx/81, rem = idx%81, i = rem/9, j = rem%9;
    float s = SX[1472+324+co];
    #pragma unroll
    for (int ci=0; ci<4; ci++){
      #pragma unroll
      for (int kh=0; kh<2; kh++){
        int ri = 2*i - 1 + kh;
        if (ri < 0 || ri >= 16) continue;
        #pragma unroll
        for (int kw=0; kw<2; kw++){
          int cj = 2*j - 1 + kw;
          if (cj < 0 || cj >= 16) continue;
          s += SX[1472+260 + co*16 + ci*4 + kh*2 + kw] * SX[448 + ci*256 + ri*16 + cj];
        }
      }
    }
    SBIAS[idx] = s;
  }
  __syncthreads();

  // ---- Phase 4: stage normalized xc -> SX [t=c][p], stride 68
  {
    int p = tid & 63;
    float sc = SSTAT[p], sh = SSTAT[64+p];
    for (int c = tid>>6; c < 64; c += 4) {
      float v = (c < 60) ? x[n*3840 + c*64 + p] : fm[n*256 + (c-60)*64 + p];
      SX[c*68 + p] = v*sc + sh;
    }
  }
  __syncthreads();

  // ---- Phase 5: ln rows -> SY
  ln_rows64(SX, SY, tid);
  __syncthreads();

  // ---- Phase 6: e1 GEMM (64x64x64) + gelu -> SX. Weights staged in 2 halves.
  {
    int t = tid>>2, g = tid&3;
    float acc[16];
    for (int idx = tid; idx < 2048; idx += 256){ int o = idx>>5, jj = idx&31; SW[o*36+jj] = e1w[o*64 + jj]; }
    for (int idx = tid; idx < 64; idx += 256) SW[3456+idx] = e1b[idx];
    __syncthreads();
    #pragma unroll
    for (int ee=0; ee<16; ee++) acc[ee] = SW[3456 + g + 4*ee];
    #pragma unroll
    for (int j=0;j<32;j+=4){
      float4 av = ld4(SY + t*68 + j);
      #pragma unroll
      for (int ee=0; ee<16; ee++) acc[ee] += dot4(av, ld4(SW + (g+4*ee)*36 + j));
    }
    __syncthreads();
    for (int idx = tid; idx < 2048; idx += 256){ int o = idx>>5, jj = idx&31; SW[o*36+jj] = e1w[o*64 + 32 + jj]; }
    __syncthreads();
    #pragma unroll
    for (int j=0;j<32;j+=4){
      float4 av = ld4(SY + t*68 + 32 + j);
      #pragma unroll
      for (int ee=0; ee<16; ee++) acc[ee] += dot4(av, ld4(SW + (g+4*ee)*36 + j));
    }
    #pragma unroll
    for (int ee=0; ee<16; ee++) SX[t*68 + g + 4*ee] = geluf(acc[ee]);
  }
  __syncthreads();

  // ---- Phase 7: ln rows SX -> SY; stage e2 (32x64, stride 68) + bias
  ln_rows64(SX, SY, tid);
  for (int idx = tid; idx < 2048; idx += 256){ int o = idx>>6, j = idx&63; SW[o*68+j] = e2w[idx]; }
  for (int idx = tid; idx < 32; idx += 256) SW[3456+idx] = e2b[idx];
  __syncthreads();

  // ---- Phase 8: e2 GEMM (64x32x64) + gelu -> SH (stride 36)
  {
    int t = tid>>2, g = tid&3;
    float acc[8];
    #pragma unroll
    for (int ee=0; ee<8; ee++) acc[ee] = SW[3456 + g + 4*ee];
    #pragma unroll
    for (int j=0;j<64;j+=4){
      float4 av = ld4(SY + t*68 + j);
      #pragma unroll
      for (int ee=0; ee<8; ee++) acc[ee] += dot4(av, ld4(SW + (g+4*ee)*68 + j));
    }
    #pragma unroll
    for (int ee=0; ee<8; ee++) SH[t*36 + g + 4*ee] = geluf(acc[ee]);
  }
  __syncthreads();

  // ================== 4 particle transformer layers =========================
  for (int li = 0; li < 4; li++) {
    const float* in_w  = pb_in_w  + li*3072;
    const float* in_b  = pb_in_b  + li*96;
    const float* out_w = pb_out_w + li*1024;
    const float* out_b = pb_out_b + li*32;
    const float* f1w   = pb_f1_w  + li*2048;
    const float* f1b   = pb_f1_b  + li*64;
    const float* f2w   = pb_f2_w  + li*2048;
    const float* f2b   = pb_f2_b  + li*32;
    const float* wres  = pb_wres  + li*32;

    // L1: a = ln(h) -> SX (stride 36); stage in_w (96x32 -> stride 36) + in_b
    ln_rows32(SH, SX, tid);
    for (int idx = tid; idx < 3072; idx += 256){ int e = idx>>5, j = idx&31; SW[e*36+j] = in_w[idx]; }
    for (int idx = tid; idx < 96; idx += 256) SW[3456+idx] = in_b[idx];
    __syncthreads();

    // L2: k,v GEMM (64 tokens x 64 outs), write transposed into SY
    {
      int t = tid>>2, g = tid&3;
      float acc[16];
      #pragma unroll
      for (int ee=0; ee<16; ee++) acc[ee] = SW[3456 + 32 + g + 4*ee];
      #pragma unroll
      for (int j=0;j<32;j+=4){
        float4 av = ld4(SX + t*36 + j);
        #pragma unroll
        for (int ee=0; ee<16; ee++) acc[ee] += dot4(av, ld4(SW + (32+g+4*ee)*36 + j));
      }
      #pragma unroll
      for (int ee=0; ee<16; ee++){
        int ew = 32 + g + 4*ee;
        if (ew < 64) SY[(ew-32)*68 + t] = acc[ee];
        else         SY[2176 + (ew-64)*68 + t] = acc[ee];
      }
    }
    __syncthreads();

    // L3: attention (online softmax over 16-key chunks). wave=head, lane=query.
    float od[8];
    {
      int hh = tid>>6, l = tid&63;
      float qd[8];
      #pragma unroll
      for (int d=0;d<8;d++){
        int e = hh*8+d;
        float a_ = SW[3456+e];
        #pragma unroll
        for (int k=0;k<8;k++) a_ += dot4(ld4(SX + l*36 + k*4), ld4(SW + e*36 + k*4));
        qd[d] = a_ * 0.35355339059327373f;
      }
      int njet = s_njet;
      float m = -3.4e38f, lsum = 0.f;
      #pragma unroll
      for (int d=0;d<8;d++) od[d] = 0.f;
      #pragma unroll
      for (int s0 = 0; s0 < 64; s0 += 16) {
        float sc[16];
        #pragma unroll
        for (int j=0;j<16;j++) sc[j]=0.f;
        #pragma unroll
        for (int d=0;d<8;d++){
          const float* kr = SY + (hh*8+d)*68 + s0;
          float qv = qd[d];
          #pragma unroll
          for (int j=0;j<16;j+=4){
            float4 kv4 = ld4(kr+j);
            sc[j]  +=qv*kv4.x; sc[j+1]+=qv*kv4.y;
            sc[j+2]+=qv*kv4.z; sc[j+3]+=qv*kv4.w;
          }
        }
        float cm = -3.4e38f;
        #pragma unroll
        for (int j=0;j<16;j++){
          int s = s0+j;
          float a_ = sc[j];
          if (s0 == 0 && l < 9 && j < 9) a_ += SBIAS[hh*81 + l*9 + j];
          a_ = (s >= njet) ? -1000000000.0f : a_;
          sc[j] = a_;
          cm = fmaxf(cm, a_);
        }
        float nm = fmaxf(m, cm);
        float corr = __expf(m - nm);        // first chunk: exp(-inf)=0
        lsum *= corr;
        #pragma unroll
        for (int d=0;d<8;d++) od[d] *= corr;
        #pragma unroll
        for (int j=0;j<16;j++){ sc[j] = __expf(sc[j]-nm); lsum += sc[j]; }
        #pragma unroll
        for (int d=0;d<8;d++){
          const float* vr = SY + 2176 + (hh*8+d)*68 + s0;
          float a_ = 0.f;
          #pragma unroll
          for (int j=0;j<16;j+=4){
            float4 vv = ld4(vr+j);
            a_ += sc[j]*vv.x + sc[j+1]*vv.y + sc[j+2]*vv.z + sc[j+3]*vv.w;
          }
          od[d] += a_;
        }
        m = nm;
      }
      float inv = 1.f/lsum;
      #pragma unroll
      for (int d=0;d<8;d++) od[d] *= inv;
    }
    __syncthreads();          // everyone done reading SX (a) and SW
    {
      int hh = tid>>6, l = tid&63;
      #pragma unroll
      for (int d=0;d<8;d++) SX[l*36 + hh*8 + d] = od[d];
    }
    for (int idx = tid; idx < 1024; idx += 256){ int e = idx>>5, j = idx&31; SW[e*36+j] = out_w[idx]; }
    for (int idx = tid; idx < 32; idx += 256) SW[3456+idx] = out_b[idx];
    __syncthreads();

    // L4: out-proj GEMM -> y in SY (stride 36)
    {
      int t = tid>>2, g = tid&3;
      float acc[8];
      #pragma unroll
      for (int ee=0; ee<8; ee++) acc[ee] = SW[3456 + g + 4*ee];
      #pragma unroll
      for (int j=0;j<32;j+=4){
        float4 av = ld4(SX + t*36 + j);
        #pragma unroll
        for (int ee=0; ee<8; ee++) acc[ee] += dot4(av, ld4(SW + (g+4*ee)*36 + j));
      }
      #pragma unroll
      for (int ee=0; ee<8; ee++) SY[t*36 + g + 4*ee] = acc[ee];
    }
    __syncthreads();

    // L5: h = ln(y) + h
    {
      int r = tid>>2, g = tid&3;
      const float* row = SY + r*36;
      float v[8]; float s = 0.f;
      #pragma unroll
      for (int k=0;k<8;k++){ v[k] = row[g*8+k]; s += v[k]; }
      s += __shfl_xor(s,1); s += __shfl_xor(s,2);
      float mean = s * 0.03125f;
      float q = 0.f;
      #pragma unroll
      for (int k=0;k<8;k++){ float d = v[k]-mean; q += d*d; }
      q += __shfl_xor(q,1); q += __shfl_xor(q,2);
      float irs = rsqrtf(q*0.03125f + 1e-5f);
      #pragma unroll
      for (int k=0;k<8;k++){ int e = g*8+k; SH[r*36+e] = (v[k]-mean)*irs + SH[r*36+e]; }
    }
    __syncthreads();

    // L6: t = ln(h) -> SX; stage f1 (64x32)
    ln_rows32(SH, SX, tid);
    for (int idx = tid; idx < 2048; idx += 256){ int e = idx>>5, j = idx&31; SW[e*36+j] = f1w[idx]; }
    for (int idx = tid; idx < 64; idx += 256) SW[3456+idx] = f1b[idx];
    __syncthreads();

    // L7: g1 = gelu(GEMM 64x64x32) -> SY stride 68
    {
      int t = tid>>2, g = tid&3;
      float acc[16];
      #pragma unroll
      for (int ee=0; ee<16; ee++) acc[ee] = SW[3456 + g + 4*ee];
      #pragma unroll
      for (int j=0;j<32;j+=4){
        float4 av = ld4(SX + t*36 + j);
        #pragma unroll
        for (int ee=0; ee<16; ee++) acc[ee] += dot4(av, ld4(SW + (g+4*ee)*36 + j));
      }
      #pragma unroll
      for (int ee=0; ee<16; ee++) SY[t*68 + g + 4*ee] = geluf(acc[ee]);
    }
    __syncthreads();

    // L8: ln64 rows SY -> SX; stage f2 (32x64, stride 68) + bias + wres
    ln_rows64(SY, SX, tid);
    for (int idx = tid; idx < 2048; idx += 256){ int e = idx>>6, j = idx&63; SW[e*68+j] = f2w[idx]; }
    for (int idx = tid; idx < 32; idx += 256){ SW[3456+idx] = f2b[idx]; SW[3488+idx] = wres[idx]; }
    __syncthreads();

    // L9: g2 GEMM (64x32x64); h = g2 + wres*h
    {
      int t = tid>>2, g = tid&3;
      float acc[8];
      #pragma unroll
      for (int ee=0; ee<8; ee++) acc[ee] = SW[3456 + g + 4*ee];
      #pragma unroll
      for (int j=0;j<64;j+=4){
        float4 av = ld4(SX + t*68 + j);
        #pragma unroll
        for (int ee=0; ee<8; ee++) acc[ee] += dot4(av, ld4(SW + (g+4*ee)*68 + j));
      }
      #pragma unroll
      for (int ee=0; ee<8; ee++){ int e = g+4*ee; SH[t*36+e] = acc[ee] + SW[3488+e]*SH[t*36+e]; }
    }
    __syncthreads();
  }

  // ================== cls-attention layers ==================================
  ln_rows32(SH, SX, tid);
  if (tid < 32) csh[tid] = cls_tok[tid];
  __syncthreads();

  for (int cl = 0; cl < 2; cl++) {
    const float* iw = cb_in_w + cl*3072;
    const float* ib = cb_in_b + cl*96;

    // C1: u0 = ln(csh) -> SV[0..31]; stage iw/ib
    if (tid < 32) {
      float v = csh[tid];
      float s = v;
      s += __shfl_xor(s,1); s += __shfl_xor(s,2); s += __shfl_xor(s,4); s += __shfl_xor(s,8); s += __shfl_xor(s,16);
      float mean = s * 0.03125f;
      float d = v - mean;
      float q = d*d;
      q += __shfl_xor(q,1); q += __shfl_xor(q,2); q += __shfl_xor(q,4); q += __shfl_xor(q,8); q += __shfl_xor(q,16);
      float irs = rsqrtf(q*0.03125f + 1e-5f);
      SV[tid] = d*irs;
    }
    for (int idx = tid; idx < 3072; idx += 256){ int e = idx>>5, j = idx&31; SW[e*36+j] = iw[idx]; }
    for (int idx = tid; idx < 96; idx += 256) SW[3456+idx] = ib[idx];
    __syncthreads();

    // C2: q from raw cls (tid<32) -> SV[32..63]; C3: k,v over 65 rows -> SY
    if (tid < 32) {
      int e = tid;
      float a_ = SW[3456+e];
      #pragma unroll
      for (int k=0;k<8;k++) a_ += dot4(ld4(&csh[k*4]), ld4(SW + e*36 + k*4));
      SV[32+e] = a_ * 0.35355339059327373f;
    }
    {
      int g = tid & 3;
      for (int s = tid>>2; s < 65; s += 64) {
        const float* u = (s == 0) ? SV : (SX + (s-1)*36);
        float4 uv[8];
        #pragma unroll
        for (int k=0;k<8;k++) uv[k] = ld4(u + k*4);
        #pragma unroll
        for (int ee=0; ee<16; ee++){
          int ew = 32 + g + 4*ee;
          float a_ = SW[3456+ew];
          #pragma unroll
          for (int k=0;k<8;k++) a_ += dot4(uv[k], ld4(SW + ew*36 + k*4));
          if (ew < 64) SY[(ew-32)*68 + s] = a_;
          else         SY[2176 + (ew-64)*68 + s] = a_;
        }
      }
    }
    __syncthreads();

    // C4: attention over 65 keys; wave=head, lane=key (lane0 also key 64)
    {
      int hh = tid>>6, l = tid&63;
      int njet = s_njet;
      float q8[8];
      #pragma unroll
      for (int d=0;d<8;d++) q8[d] = SV[32 + hh*8 + d];
      float sc_ = 0.f;
      #pragma unroll
      for (int d=0;d<8;d++) sc_ += q8[d]*SY[(hh*8+d)*68 + l];
      if (l > 0 && (l-1) >= njet) sc_ = -1000000000.0f;
      float sc64 = 0.f;
      if (l == 0){
        #pragma unroll
        for (int d=0;d<8;d++) sc64 += q8[d]*SY[(hh*8+d)*68 + 64];
        if (63 >= njet) sc64 = -1000000000.0f;
      }
      float mx = sc_;
      if (l == 0) mx = fmaxf(mx, sc64);
      mx = fmaxf(mx, __shfl_xor(mx,1));  mx = fmaxf(mx, __shfl_xor(mx,2));
      mx = fmaxf(mx, __shfl_xor(mx,4));  mx = fmaxf(mx, __shfl_xor(mx,8));
      mx = fmaxf(mx, __shfl_xor(mx,16)); mx = fmaxf(mx, __shfl_xor(mx,32));
      float p   = __expf(sc_ - mx);
      float p64 = (l==0) ? __expf(sc64 - mx) : 0.f;
      float ssum = p + p64;
      ssum += __shfl_xor(ssum,1); ssum += __shfl_xor(ssum,2); ssum += __shfl_xor(ssum,4);
      ssum += __shfl_xor(ssum,8); ssum += __shfl_xor(ssum,16); ssum += __shfl_xor(ssum,32);
      float inv = 1.f/ssum;
      #pragma unroll
      for (int d=0;d<8;d++){
        float term = p * SY[2176 + (hh*8+d)*68 + l];
        if (l == 0) term += p64 * SY[2176 + (hh*8+d)*68 + 64];
        term += __shfl_xor(term,1); term += __shfl_xor(term,2); term += __shfl_xor(term,4);
        term += __shfl_xor(term,8); term += __shfl_xor(term,16); term += __shfl_xor(term,32);
        if (l == 0) SV[64 + hh*8 + d] = term*inv;
      }
    }
    __syncthreads();

    // C5: out proj + cattn permute -> SV[96..127]
    if (tid < 32) {
      int e = tid;
      const float* wrow = cb_out_w + (cl*32 + e)*32;
      float a_ = cb_out_b[cl*32 + e];
      #pragma unroll
      for (int j=0;j<32;j++) a_ += SV[64+j]*wrow[j];
      float ca = cb_cattn[cl*4 + (e>>3)];
      SV[96 + (e&7)*4 + (e>>3)] = a_*ca;
    }
    __syncthreads();

    // C6: cls = ln(a2) + cls
    if (tid < 32) {
      float v = SV[96+tid];
      float s = v;
      s += __shfl_xor(s,1); s += __shfl_xor(s,2); s += __shfl_xor(s,4); s += __shfl_xor(s,8); s += __shfl_xor(s,16);
      float mean = s * 0.03125f;
      float d = v - mean;
      float q = d*d;
      q += __shfl_xor(q,1); q += __shfl_xor(q,2); q += __shfl_xor(q,4); q += __shfl_xor(q,8); q += __shfl_xor(q,16);
      float irs = rsqrtf(q*0.03125f + 1e-5f);
      csh[tid] = d*irs + csh[tid];
    }
    __syncthreads();

    // C7: FFN on cls vector
    if (tid < 32) {
      float v = csh[tid];
      float s = v;
      s += __shfl_xor(s,1); s += __shfl_xor(s,2); s += __shfl_xor(s,4); s += __shfl_xor(s,8); s += __shfl_xor(s,16);
      float mean = s * 0.03125f;
      float d = v - mean;
      float q = d*d;
      q += __shfl_xor(q,1); q += __shfl_xor(q,2); q += __shfl_xor(q,4); q += __shfl_xor(q,8); q += __shfl_xor(q,16);
      float irs = rsqrtf(q*0.03125f + 1e-5f);
      SV[tid] = d*irs;
    }
    __syncthreads();
    if (tid < 64) {
      int o = tid;
      const float* wrow = cb_f1_w + (cl*64+o)*32;
      float a_ = cb_f1_b[cl*64+o];
      #pragma unroll
      for (int j=0;j<32;j++) a_ += SV[j]*wrow[j];
      SV[128+o] = geluf(a_);
    }
    __syncthreads();
    if (tid < 64) {
      float v = SV[128+tid];
      float s = v;
      s += __shfl_xor(s,1); s += __shfl_xor(s,2); s += __shfl_xor(s,4); s += __shfl_xor(s,8);
      s += __shfl_xor(s,16); s += __shfl_xor(s,32);
      float mean = s * 0.015625f;
      float d = v - mean;
      float q = d*d;
      q += __shfl_xor(q,1); q += __shfl_xor(q,2); q += __shfl_xor(q,4); q += __shfl_xor(q,8);
      q += __shfl_xor(q,16); q += __shfl_xor(q,32);
      float irs = rsqrtf(q*0.015625f + 1e-5f);
      SV[192+tid] = d*irs;
    }
    __syncthreads();
    if (tid < 32) {
      int e = tid;
      const float* wrow = cb_f2_w + (cl*32+e)*64;
      float a_ = cb_f2_b[cl*32+e];
      #pragma unroll
      for (int j=0;j<64;j++) a_ += SV[192+j]*wrow[j];
      csh[e] = a_ + cb_wres[cl*32+e]*csh[e];
    }
    __syncthreads();
  }

  // ================== head ==================================================
  if (tid < 32) {
    float v = csh[tid];
    float s = v;
    s += __shfl_xor(s,1); s += __shfl_xor(s,2); s += __shfl_xor(s,4); s += __shfl_xor(s,8); s += __shfl_xor(s,16);
    float mean = s * 0.03125f;
    float d = v - mean;
    float q = d*d;
    q += __shfl_xor(q,1); q += __shfl_xor(q,2); q += __shfl_xor(q,4); q += __shfl_xor(q,8); q += __shfl_xor(q,16);
    float irs = rsqrtf(q*0.03125f + 1e-5f);
    SV[tid] = d*irs*norm_w[tid] + norm_b[tid];
  }
  __syncthreads();
  if (tid < 32) {
    float a_ = m1b[tid];
    const float* wrow = m1w + tid*32;
    #pragma unroll
    for (int j=0;j<32;j++) a_ += SV[j]*wrow[j];
    SV[64+tid] = fmaxf(a_, 0.f);
  }
  __syncthreads();
  if (tid < 32) {
    float a_ = mhb[tid];
    const float* wrow = mhw + tid*32;
    #pragma unroll
    for (int j=0;j<32;j++) a_ += SV[64+j]*wrow[j];
    SV[128+tid] = fmaxf(a_, 0.f);
  }
  __syncthreads();
  if (tid == 0) {
    float a_ = mfb[0];
    #pragma unroll
    for (int j=0;j<32;j++) a_ += SV[128+j]*mfw[j];
    out[n] = 1.f/(1.f + expf(-a_));
  }
}

// ---------------------------------------------------------------------------
extern "C" void kernel_launch(void* const* d_in, const int* in_sizes, int n_in,
                              void* d_out, int out_size, void* d_ws, size_t ws_size,
                              hipStream_t stream) {
  (void)in_sizes; (void)n_in; (void)out_size; (void)ws_size;
  const float* x     = (const float*)d_in[0];
  const float* fm    = (const float*)d_in[1];
  const int*   ji    = (const int*)  d_in[2];
  const float* bn_w  = (const float*)d_in[3];
  const float* bn_b  = (const float*)d_in[4];
  const float* e1w   = (const float*)d_in[5];
  const float* e1b   = (const float*)d_in[6];
  const float* e2w   = (const float*)d_in[7];
  const float* e2b   = (const float*)d_in[8];
  const float* c1w   = (const float*)d_in[9];
  const float* c1b   = (const float*)d_in[10];
  const float* c2w   = (const float*)d_in[11];
  const float* c2b   = (const float*)d_in[12];
  const float* pb_in_w  = (const float*)d_in[13];
  const float* pb_in_b  = (const float*)d_in[14];
  const float* pb_out_w = (const float*)d_in[15];
  const float* pb_out_b = (const float*)d_in[16];
  const float* pb_f1_w  = (const float*)d_in[17];
  const float* pb_f1_b  = (const float*)d_in[18];
  const float* pb_f2_w  = (const float*)d_in[19];
  const float* pb_f2_b  = (const float*)d_in[20];
  const float* pb_wres  = (const float*)d_in[21];
  const float* cb_in_w  = (const float*)d_in[22];
  const float* cb_in_b  = (const float*)d_in[23];
  const float* cb_out_w = (const float*)d_in[24];
  const float* cb_out_b = (const float*)d_in[25];
  const float* cb_f1_w  = (const float*)d_in[26];
  const float* cb_f1_b  = (const float*)d_in[27];
  const float* cb_f2_w  = (const float*)d_in[28];
  const float* cb_f2_b  = (const float*)d_in[29];
  const float* cb_wres  = (const float*)d_in[30];
  const float* cb_cattn = (const float*)d_in[31];
  const float* cls_tok  = (const float*)d_in[32];
  const float* norm_w   = (const float*)d_in[33];
  const float* norm_b   = (const float*)d_in[34];
  const float* m1w      = (const float*)d_in[35];
  const float* m1b      = (const float*)d_in[36];
  const float* mhw      = (const float*)d_in[37];
  const float* mhb      = (const float*)d_in[38];
  const float* mfw      = (const float*)d_in[39];
  const float* mfb      = (const float*)d_in[40];

  float* part  = (float*)d_ws;            // 256*128 floats
  float* stats = part + 256*128;          // 128 floats

  bn_stats_partial<<<256, 256, 0, stream>>>(x, fm, part);
  bn_stats_final<<<1, 64, 0, stream>>>(part, stats);
  fused_fwd<<<2048, 256, 0, stream>>>(
      x, fm, ji, bn_w, bn_b, e1w, e1b, e2w, e2b, c1w, c1b, c2w, c2b,
      pb_in_w, pb_in_b, pb_out_w, pb_out_b, pb_f1_w, pb_f1_b, pb_f2_w, pb_f2_b, pb_wres,
      cb_in_w, cb_in_b, cb_out_w, cb_out_b, cb_f1_w, cb_f1_b, cb_f2_w, cb_f2_b,
      cb_wres, cb_cattn, cls_tok, norm_w, norm_b, m1w, m1b, mhw, mhb, mfw, mfb,
      stats, (float*)d_out);
}

// Round 4
// 1825.381 us; speedup vs baseline: 1.8541x; 1.2801x over previous
//
#include <hip/hip_runtime.h>

// ---------------------------------------------------------------------------
// Part_65712999629561: ParticleTransformer-ish forward, N=2048, P=64, E=32,
// H=4, D=8, 4 particle layers + 2 cls layers. f32 throughout.
// R3 post-mortem: megakernel demanded >256 VGPR somewhere -> 2.6 GB scratch
// traffic/dispatch = the runtime. R4: split into small kernels (embed, 4x
// layer, cls) with h (16 MB) + bias (2.6 MB) staged in d_ws. Each kernel's
// pressure is bounded; h round-trip costs ~200 MB total vs 2.6 GB scratch.
// ---------------------------------------------------------------------------

__device__ __forceinline__ float4 ld4(const float* p){ return *reinterpret_cast<const float4*>(p); }
__device__ __forceinline__ float dot4(float4 a, float4 b){ return a.x*b.x + a.y*b.y + a.z*b.z + a.w*b.w; }
__device__ __forceinline__ float geluf(float v){ return 0.5f*v*(1.0f + erff(v*0.70710678118654752f)); }

// ---------------- Kernel A: batchnorm stats --------------------------------
__global__ void bn_stats_partial(const float* __restrict__ x, const float* __restrict__ fm,
                                 float* __restrict__ part) {
  int p  = threadIdx.x & 63;
  int rg = threadIdx.x >> 6;
  float s = 0.f, s2 = 0.f;
  for (int R = blockIdx.x*4 + rg; R < 2048*64; R += 1024) {
    int n_ = R >> 6, c = R & 63;
    float v = (c < 60) ? x[n_*3840 + c*64 + p] : fm[n_*256 + (c-60)*64 + p];
    s += v; s2 += v*v;
  }
  __shared__ float sm[256], sm2[256];
  sm[threadIdx.x] = s; sm2[threadIdx.x] = s2;
  __syncthreads();
  if (threadIdx.x < 64) {
    part[blockIdx.x*128 + p]      = sm[p]+sm[64+p]+sm[128+p]+sm[192+p];
    part[blockIdx.x*128 + 64 + p] = sm2[p]+sm2[64+p]+sm2[128+p]+sm2[192+p];
  }
}

__global__ void bn_stats_final(const float* __restrict__ part, float* __restrict__ stats) {
  int p = threadIdx.x; // 64 threads
  float s = 0.f, s2 = 0.f;
  for (int b = 0; b < 256; b++){ s += part[b*128+p]; s2 += part[b*128+64+p]; }
  float mean = s * (1.f/131072.f);
  float var  = s2 * (1.f/131072.f) - mean*mean;
  stats[p]      = mean;
  stats[64+p]   = rsqrtf(var + 1e-5f);
}

// ---------------- row-LN helpers (256 threads, 64 rows, 4 lanes/row) --------
__device__ __forceinline__ void ln_rows32(const float* src, float* dst, int tid){
  int r = tid>>2, g = tid&3;
  const float* row = src + r*36;
  float v[8]; float s = 0.f;
  #pragma unroll
  for (int k=0;k<8;k++){ v[k] = row[g*8+k]; s += v[k]; }
  s += __shfl_xor(s,1); s += __shfl_xor(s,2);
  float mean = s * 0.03125f;
  float q = 0.f;
  #pragma unroll
  for (int k=0;k<8;k++){ float d = v[k]-mean; q += d*d; }
  q += __shfl_xor(q,1); q += __shfl_xor(q,2);
  float irs = rsqrtf(q*0.03125f + 1e-5f);
  float* drow = dst + r*36;
  #pragma unroll
  for (int k=0;k<8;k++) drow[g*8+k] = (v[k]-mean)*irs;
}

__device__ __forceinline__ void ln_rows64(const float* src, float* dst, int tid){
  int r = tid>>2, g = tid&3;
  const float* row = src + r*68;
  float v[16]; float s = 0.f;
  #pragma unroll
  for (int k=0;k<16;k++){ v[k] = row[g*16+k]; s += v[k]; }
  s += __shfl_xor(s,1); s += __shfl_xor(s,2);
  float mean = s * 0.015625f;
  float q = 0.f;
  #pragma unroll
  for (int k=0;k<16;k++){ float d = v[k]-mean; q += d*d; }
  q += __shfl_xor(q,1); q += __shfl_xor(q,2);
  float irs = rsqrtf(q*0.015625f + 1e-5f);
  float* drow = dst + r*68;
  #pragma unroll
  for (int k=0;k<16;k++) drow[g*16+k] = (v[k]-mean)*irs;
}

// ============================ K_embed ======================================
// jet features + conv1 + conv2 (-> G_bias), BN-apply + ln + e1 + ln + e2
// -> G_h. One block per sample.
__global__ __launch_bounds__(256) void k_embed(
    const float* __restrict__ x, const float* __restrict__ fm,
    const float* __restrict__ stats,
    const float* __restrict__ bn_w, const float* __restrict__ bn_b,
    const float* __restrict__ e1w, const float* __restrict__ e1b,
    const float* __restrict__ e2w, const float* __restrict__ e2b,
    const float* __restrict__ c1w_g, const float* __restrict__ c1b_g,
    const float* __restrict__ c2w_g, const float* __restrict__ c2b_g,
    float* __restrict__ G_h, float* __restrict__ G_bias)
{
  const int n   = blockIdx.x;
  const int tid = threadIdx.x;

  __shared__ __align__(16) float SX[64*68];
  __shared__ __align__(16) float SY[64*68];
  __shared__ __align__(16) float SW[3584];
  __shared__ float SSTAT[128];

  // ---- Phase 0+1: stats, particle quantities, conv weights into SX scratch
  if (tid < 64) {
    float mu = stats[tid], rs = stats[64+tid];
    float sc = rs * bn_w[tid];
    SSTAT[tid]      = sc;
    SSTAT[64+tid]   = bn_b[tid] - mu*sc;
  }
  if (tid < 64) {
    int p = tid;
    float e_  = fm[n*256 + p];
    float px_ = fm[n*256 + 64 + p];
    float py_ = fm[n*256 + 128 + p];
    float pz_ = fm[n*256 + 192 + p];
    float pt_ = sqrtf(px_*px_ + py_*py_ + 1e-8f);
    float y_  = 0.5f * logf((e_ + pz_ + 1e-8f) / (e_ - pz_ + 1e-8f));
    float ph_ = atan2f(py_, px_ + 1e-8f);
    if (ph_ < 0.f) ph_ += 6.283185307179586f;
    SX[0*64+p]=e_; SX[1*64+p]=px_; SX[2*64+p]=py_; SX[3*64+p]=pz_;
    SX[4*64+p]=pt_; SX[5*64+p]=y_; SX[6*64+p]=ph_;
  }
  SX[1472 + tid] = c1w_g[tid];
  if (tid < 4)  SX[1472+256+tid] = c1b_g[tid];
  if (tid < 64) SX[1472+260+tid] = c2w_g[tid];
  if (tid < 4)  SX[1472+324+tid] = c2b_g[tid];
  __syncthreads();

  // ---- Phase 2: conv1 (stride4, k4): out [4][16][16], thread = (ho,wo)
  {
    int ho = tid>>4, wo = tid&15;
    float a0=0.f,a1=0.f,a2=0.f,a3=0.f;
    const float* pq = SX;
    const float* cw = SX + 1472;
    #pragma unroll
    for (int kh=0; kh<4; kh++){
      int r = ho*4+kh;
      float er=pq[r], pxr=pq[64+r], pyr=pq[128+r], pzr=pq[192+r], ptr_=pq[256+r], yr=pq[320+r], phr=pq[384+r];
      #pragma unroll
      for (int kw=0; kw<4; kw++){
        int c = wo*4+kw;
        if (r == c) continue;
        float ec=pq[c], pxc=pq[64+c], pyc=pq[128+c], pzc=pq[192+c], ptc=pq[256+c], yc=pq[320+c], phc=pq[384+c];
        float dy = yr-yc, dp = phr-phc;
        float delta = sqrtf(fabsf(dy*dy + dp*dp));
        float pmin = fminf(ptr_, ptc);
        float kt = pmin * delta;
        float zz = pmin / (ptr_ + ptc + 1e-8f);
        float sx_ = pxr+pxc, sy_ = pyr+pyc, sz_ = pzr+pzc;
        float m2 = er*er + ec*ec - (sx_*sx_ + sy_*sy_ + sz_*sz_);
        int wb = kh*4+kw;
        a0 += delta*cw[0*64+wb] + kt*cw[0*64+16+wb] + zz*cw[0*64+32+wb] + m2*cw[0*64+48+wb];
        a1 += delta*cw[1*64+wb] + kt*cw[1*64+16+wb] + zz*cw[1*64+32+wb] + m2*cw[1*64+48+wb];
        a2 += delta*cw[2*64+wb] + kt*cw[2*64+16+wb] + zz*cw[2*64+32+wb] + m2*cw[2*64+48+wb];
        a3 += delta*cw[3*64+wb] + kt*cw[3*64+16+wb] + zz*cw[3*64+32+wb] + m2*cw[3*64+48+wb];
      }
    }
    SX[448 + 0*256 + tid] = a0 + SX[1472+256+0];
    SX[448 + 1*256 + tid] = a1 + SX[1472+256+1];
    SX[448 + 2*256 + tid] = a2 + SX[1472+256+2];
    SX[448 + 3*256 + tid] = a3 + SX[1472+256+3];
  }
  __syncthreads();

  // ---- Phase 3: conv2 (stride2, k2, pad1) -> G_bias [n][co][i][j] (9x9)
  for (int idx = tid; idx < 324; idx += 256) {
    int co = idx/81, rem = idx%81, i = rem/9, j = rem%9;
    float s = SX[1472+324+co];
    #pragma unroll
    for (int ci=0; ci<4; ci++){
      #pragma unroll
      for (int kh=0; kh<2; kh++){
        int ri = 2*i - 1 + kh;
        if (ri < 0 || ri >= 16) continue;
        #pragma unroll
        for (int kw=0; kw<2; kw++){
          int cj = 2*j - 1 + kw;
          if (cj < 0 || cj >= 16) continue;
          s += SX[1472+260 + co*16 + ci*4 + kh*2 + kw] * SX[448 + ci*256 + ri*16 + cj];
        }
      }
    }
    G_bias[n*324 + idx] = s;
  }
  __syncthreads();

  // ---- Phase 4: stage normalized xc -> SX [t=c][p], stride 68
  {
    int p = tid & 63;
    float sc = SSTAT[p], sh = SSTAT[64+p];
    for (int c = tid>>6; c < 64; c += 4) {
      float v = (c < 60) ? x[n*3840 + c*64 + p] : fm[n*256 + (c-60)*64 + p];
      SX[c*68 + p] = v*sc + sh;
    }
  }
  __syncthreads();

  // ---- Phase 5: ln rows -> SY
  ln_rows64(SX, SY, tid);
  __syncthreads();

  // ---- Phase 6: e1 GEMM (64x64x64) + gelu -> SX. Weights staged in 2 halves.
  {
    int t = tid>>2, g = tid&3;
    float acc[16];
    for (int idx = tid; idx < 2048; idx += 256){ int o = idx>>5, jj = idx&31; SW[o*36+jj] = e1w[o*64 + jj]; }
    for (int idx = tid; idx < 64; idx += 256) SW[3456+idx] = e1b[idx];
    __syncthreads();
    #pragma unroll
    for (int ee=0; ee<16; ee++) acc[ee] = SW[3456 + g + 4*ee];
    #pragma unroll
    for (int j=0;j<32;j+=4){
      float4 av = ld4(SY + t*68 + j);
      #pragma unroll
      for (int ee=0; ee<16; ee++) acc[ee] += dot4(av, ld4(SW + (g+4*ee)*36 + j));
    }
    __syncthreads();
    for (int idx = tid; idx < 2048; idx += 256){ int o = idx>>5, jj = idx&31; SW[o*36+jj] = e1w[o*64 + 32 + jj]; }
    __syncthreads();
    #pragma unroll
    for (int j=0;j<32;j+=4){
      float4 av = ld4(SY + t*68 + 32 + j);
      #pragma unroll
      for (int ee=0; ee<16; ee++) acc[ee] += dot4(av, ld4(SW + (g+4*ee)*36 + j));
    }
    #pragma unroll
    for (int ee=0; ee<16; ee++) SX[t*68 + g + 4*ee] = geluf(acc[ee]);
  }
  __syncthreads();

  // ---- Phase 7: ln rows SX -> SY; stage e2 (32x64, stride 68) + bias
  ln_rows64(SX, SY, tid);
  for (int idx = tid; idx < 2048; idx += 256){ int o = idx>>6, j = idx&63; SW[o*68+j] = e2w[idx]; }
  for (int idx = tid; idx < 32; idx += 256) SW[3456+idx] = e2b[idx];
  __syncthreads();

  // ---- Phase 8: e2 GEMM (64x32x64) + gelu -> SX stride 36, then copy to G_h
  {
    int t = tid>>2, g = tid&3;
    float acc[8];
    #pragma unroll
    for (int ee=0; ee<8; ee++) acc[ee] = SW[3456 + g + 4*ee];
    #pragma unroll
    for (int j=0;j<64;j+=4){
      float4 av = ld4(SY + t*68 + j);
      #pragma unroll
      for (int ee=0; ee<8; ee++) acc[ee] += dot4(av, ld4(SW + (g+4*ee)*68 + j));
    }
    #pragma unroll
    for (int ee=0; ee<8; ee++) SX[t*36 + g + 4*ee] = geluf(acc[ee]);
  }
  __syncthreads();
  for (int idx = tid; idx < 2048; idx += 256) {
    int t = idx>>5, e = idx&31;
    G_h[n*2048 + idx] = SX[t*36 + e];
  }
}

// ============================ K_layer ======================================
// One particle-transformer layer. Weight pointers pre-offset on host.
__global__ __launch_bounds__(256) void k_layer(
    const int* __restrict__ ji,
    const float* __restrict__ in_w,  const float* __restrict__ in_b,
    const float* __restrict__ out_w, const float* __restrict__ out_b,
    const float* __restrict__ f1w,   const float* __restrict__ f1b,
    const float* __restrict__ f2w,   const float* __restrict__ f2b,
    const float* __restrict__ wres,
    float* __restrict__ G_h, const float* __restrict__ G_bias)
{
  const int n   = blockIdx.x;
  const int tid = threadIdx.x;

  __shared__ __align__(16) float SH[64*36];
  __shared__ __align__(16) float SX[64*36];
  __shared__ __align__(16) float SY[64*68];
  __shared__ __align__(16) float SW[3584];
  __shared__ float SBIAS[324];
  __shared__ int s_njet;

  if (tid == 0) s_njet = ji[n*2+1];
  for (int idx = tid; idx < 2048; idx += 256) {
    int t = idx>>5, e = idx&31;
    SH[t*36 + e] = G_h[n*2048 + idx];
  }
  for (int idx = tid; idx < 324; idx += 256) SBIAS[idx] = G_bias[n*324 + idx];
  __syncthreads();

  // L1: a = ln(h) -> SX (stride 36); stage in_w (96x32 -> stride 36) + in_b
  ln_rows32(SH, SX, tid);
  for (int idx = tid; idx < 3072; idx += 256){ int e = idx>>5, j = idx&31; SW[e*36+j] = in_w[idx]; }
  for (int idx = tid; idx < 96; idx += 256) SW[3456+idx] = in_b[idx];
  __syncthreads();

  // L2: k,v GEMM (64 tokens x 64 outs), write transposed into SY
  {
    int t = tid>>2, g = tid&3;
    float acc[16];
    #pragma unroll
    for (int ee=0; ee<16; ee++) acc[ee] = SW[3456 + 32 + g + 4*ee];
    #pragma unroll
    for (int j=0;j<32;j+=4){
      float4 av = ld4(SX + t*36 + j);
      #pragma unroll
      for (int ee=0; ee<16; ee++) acc[ee] += dot4(av, ld4(SW + (32+g+4*ee)*36 + j));
    }
    #pragma unroll
    for (int ee=0; ee<16; ee++){
      int ew = 32 + g + 4*ee;
      if (ew < 64) SY[(ew-32)*68 + t] = acc[ee];
      else         SY[2176 + (ew-64)*68 + t] = acc[ee];
    }
  }
  __syncthreads();

  // L3: attention (online softmax over 16-key chunks). wave=head, lane=query.
  float od[8];
  {
    int hh = tid>>6, l = tid&63;
    float qd[8];
    #pragma unroll
    for (int d=0;d<8;d++){
      int e = hh*8+d;
      float a_ = SW[3456+e];
      #pragma unroll
      for (int k=0;k<8;k++) a_ += dot4(ld4(SX + l*36 + k*4), ld4(SW + e*36 + k*4));
      qd[d] = a_ * 0.35355339059327373f;
    }
    int njet = s_njet;
    float m = -3.4e38f, lsum = 0.f;
    #pragma unroll
    for (int d=0;d<8;d++) od[d] = 0.f;
    #pragma unroll
    for (int s0 = 0; s0 < 64; s0 += 16) {
      float sc[16];
      #pragma unroll
      for (int j=0;j<16;j++) sc[j]=0.f;
      #pragma unroll
      for (int d=0;d<8;d++){
        const float* kr = SY + (hh*8+d)*68 + s0;
        float qv = qd[d];
        #pragma unroll
        for (int j=0;j<16;j+=4){
          float4 kv4 = ld4(kr+j);
          sc[j]  +=qv*kv4.x; sc[j+1]+=qv*kv4.y;
          sc[j+2]+=qv*kv4.z; sc[j+3]+=qv*kv4.w;
        }
      }
      float cm = -3.4e38f;
      #pragma unroll
      for (int j=0;j<16;j++){
        int s = s0+j;
        float a_ = sc[j];
        if (s0 == 0 && l < 9 && j < 9) a_ += SBIAS[hh*81 + l*9 + j];
        a_ = (s >= njet) ? -1000000000.0f : a_;
        sc[j] = a_;
        cm = fmaxf(cm, a_);
      }
      float nm = fmaxf(m, cm);
      float corr = __expf(m - nm);        // first chunk: exp(-inf)=0
      lsum *= corr;
      #pragma unroll
      for (int d=0;d<8;d++) od[d] *= corr;
      #pragma unroll
      for (int j=0;j<16;j++){ sc[j] = __expf(sc[j]-nm); lsum += sc[j]; }
      #pragma unroll
      for (int d=0;d<8;d++){
        const float* vr = SY + 2176 + (hh*8+d)*68 + s0;
        float a_ = 0.f;
        #pragma unroll
        for (int j=0;j<16;j+=4){
          float4 vv = ld4(vr+j);
          a_ += sc[j]*vv.x + sc[j+1]*vv.y + sc[j+2]*vv.z + sc[j+3]*vv.w;
        }
        od[d] += a_;
      }
      m = nm;
    }
    float inv = 1.f/lsum;
    #pragma unroll
    for (int d=0;d<8;d++) od[d] *= inv;
  }
  __syncthreads();          // everyone done reading SX (a) and SW
  {
    int hh = tid>>6, l = tid&63;
    #pragma unroll
    for (int d=0;d<8;d++) SX[l*36 + hh*8 + d] = od[d];
  }
  for (int idx = tid; idx < 1024; idx += 256){ int e = idx>>5, j = idx&31; SW[e*36+j] = out_w[idx]; }
  for (int idx = tid; idx < 32; idx += 256) SW[3456+idx] = out_b[idx];
  __syncthreads();

  // L4: out-proj GEMM -> y in SY (stride 36)
  {
    int t = tid>>2, g = tid&3;
    float acc[8];
    #pragma unroll
    for (int ee=0; ee<8; ee++) acc[ee] = SW[3456 + g + 4*ee];
    #pragma unroll
    for (int j=0;j<32;j+=4){
      float4 av = ld4(SX + t*36 + j);
      #pragma unroll
      for (int ee=0; ee<8; ee++) acc[ee] += dot4(av, ld4(SW + (g+4*ee)*36 + j));
    }
    #pragma unroll
    for (int ee=0; ee<8; ee++) SY[t*36 + g + 4*ee] = acc[ee];
  }
  __syncthreads();

  // L5: h = ln(y) + h
  {
    int r = tid>>2, g = tid&3;
    const float* row = SY + r*36;
    float v[8]; float s = 0.f;
    #pragma unroll
    for (int k=0;k<8;k++){ v[k] = row[g*8+k]; s += v[k]; }
    s += __shfl_xor(s,1); s += __shfl_xor(s,2);
    float mean = s * 0.03125f;
    float q = 0.f;
    #pragma unroll
    for (int k=0;k<8;k++){ float d = v[k]-mean; q += d*d; }
    q += __shfl_xor(q,1); q += __shfl_xor(q,2);
    float irs = rsqrtf(q*0.03125f + 1e-5f);
    #pragma unroll
    for (int k=0;k<8;k++){ int e = g*8+k; SH[r*36+e] = (v[k]-mean)*irs + SH[r*36+e]; }
  }
  __syncthreads();

  // L6: t = ln(h) -> SX; stage f1 (64x32)
  ln_rows32(SH, SX, tid);
  for (int idx = tid; idx < 2048; idx += 256){ int e = idx>>5, j = idx&31; SW[e*36+j] = f1w[idx]; }
  for (int idx = tid; idx < 64; idx += 256) SW[3456+idx] = f1b[idx];
  __syncthreads();

  // L7: g1 = gelu(GEMM 64x64x32) -> SY stride 68
  {
    int t = tid>>2, g = tid&3;
    float acc[16];
    #pragma unroll
    for (int ee=0; ee<16; ee++) acc[ee] = SW[3456 + g + 4*ee];
    #pragma unroll
    for (int j=0;j<32;j+=4){
      float4 av = ld4(SX + t*36 + j);
      #pragma unroll
      for (int ee=0; ee<16; ee++) acc[ee] += dot4(av, ld4(SW + (g+4*ee)*36 + j));
    }
    #pragma unroll
    for (int ee=0; ee<16; ee++) SY[t*68 + g + 4*ee] = geluf(acc[ee]);
  }
  __syncthreads();

  // L8: ln64 rows SY -> SX? (need stride-68 dst) -- use SY in-place pattern:
  // ln64 writes into SX stride 68 won't fit (SX is 64*36). Write into SY via
  // two-step: compute into registers then store back to SY stride 68.
  // Simpler: ln64 src SY -> dst SY (in-place safe: each lane reads/writes its
  // own 16 elements).
  {
    int r = tid>>2, g = tid&3;
    float* row = SY + r*68;
    float v[16]; float s = 0.f;
    #pragma unroll
    for (int k=0;k<16;k++){ v[k] = row[g*16+k]; s += v[k]; }
    s += __shfl_xor(s,1); s += __shfl_xor(s,2);
    float mean = s * 0.015625f;
    float q = 0.f;
    #pragma unroll
    for (int k=0;k<16;k++){ float d = v[k]-mean; q += d*d; }
    q += __shfl_xor(q,1); q += __shfl_xor(q,2);
    float irs = rsqrtf(q*0.015625f + 1e-5f);
    #pragma unroll
    for (int k=0;k<16;k++) row[g*16+k] = (v[k]-mean)*irs;
  }
  for (int idx = tid; idx < 2048; idx += 256){ int e = idx>>6, j = idx&63; SW[e*68+j] = f2w[idx]; }
  for (int idx = tid; idx < 32; idx += 256){ SW[3456+idx] = f2b[idx]; SW[3488+idx] = wres[idx]; }
  __syncthreads();

  // L9: g2 GEMM (64x32x64); h = g2 + wres*h -> SH, then copy out
  {
    int t = tid>>2, g = tid&3;
    float acc[8];
    #pragma unroll
    for (int ee=0; ee<8; ee++) acc[ee] = SW[3456 + g + 4*ee];
    #pragma unroll
    for (int j=0;j<64;j+=4){
      float4 av = ld4(SY + t*68 + j);
      #pragma unroll
      for (int ee=0; ee<8; ee++) acc[ee] += dot4(av, ld4(SW + (g+4*ee)*68 + j));
    }
    #pragma unroll
    for (int ee=0; ee<8; ee++){ int e = g+4*ee; SH[t*36+e] = acc[ee] + SW[3488+e]*SH[t*36+e]; }
  }
  __syncthreads();
  for (int idx = tid; idx < 2048; idx += 256) {
    int t = idx>>5, e = idx&31;
    G_h[n*2048 + idx] = SH[t*36 + e];
  }
}

// ============================ K_cls ========================================
// Both cls-attention layers + head. One block per sample.
__global__ __launch_bounds__(256) void k_cls(
    const int* __restrict__ ji,
    const float* __restrict__ cb_in_w, const float* __restrict__ cb_in_b,
    const float* __restrict__ cb_out_w, const float* __restrict__ cb_out_b,
    const float* __restrict__ cb_f1_w, const float* __restrict__ cb_f1_b,
    const float* __restrict__ cb_f2_w, const float* __restrict__ cb_f2_b,
    const float* __restrict__ cb_wres, const float* __restrict__ cb_cattn,
    const float* __restrict__ cls_tok, const float* __restrict__ norm_w, const float* __restrict__ norm_b,
    const float* __restrict__ m1w, const float* __restrict__ m1b,
    const float* __restrict__ mhw, const float* __restrict__ mhb,
    const float* __restrict__ mfw, const float* __restrict__ mfb,
    const float* __restrict__ G_h, float* __restrict__ out)
{
  const int n   = blockIdx.x;
  const int tid = threadIdx.x;

  __shared__ __align__(16) float SH[64*36];
  __shared__ __align__(16) float SX[64*36];
  __shared__ __align__(16) float SY[64*68];
  __shared__ __align__(16) float SW[3584];
  __shared__ __align__(16) float SV[320];
  __shared__ __align__(16) float csh[32];
  __shared__ int s_njet;

  if (tid == 0) s_njet = ji[n*2+1];
  for (int idx = tid; idx < 2048; idx += 256) {
    int t = idx>>5, e = idx&31;
    SH[t*36 + e] = G_h[n*2048 + idx];
  }
  __syncthreads();

  ln_rows32(SH, SX, tid);
  if (tid < 32) csh[tid] = cls_tok[tid];
  __syncthreads();

  for (int cl = 0; cl < 2; cl++) {
    const float* iw = cb_in_w + cl*3072;
    const float* ib = cb_in_b + cl*96;

    // C1: u0 = ln(csh) -> SV[0..31]; stage iw/ib
    if (tid < 32) {
      float v = csh[tid];
      float s = v;
      s += __shfl_xor(s,1); s += __shfl_xor(s,2); s += __shfl_xor(s,4); s += __shfl_xor(s,8); s += __shfl_xor(s,16);
      float mean = s * 0.03125f;
      float d = v - mean;
      float q = d*d;
      q += __shfl_xor(q,1); q += __shfl_xor(q,2); q += __shfl_xor(q,4); q += __shfl_xor(q,8); q += __shfl_xor(q,16);
      float irs = rsqrtf(q*0.03125f + 1e-5f);
      SV[tid] = d*irs;
    }
    for (int idx = tid; idx < 3072; idx += 256){ int e = idx>>5, j = idx&31; SW[e*36+j] = iw[idx]; }
    for (int idx = tid; idx < 96; idx += 256) SW[3456+idx] = ib[idx];
    __syncthreads();

    // C2: q from raw cls (tid<32) -> SV[32..63]; C3: k,v over 65 rows -> SY
    if (tid < 32) {
      int e = tid;
      float a_ = SW[3456+e];
      #pragma unroll
      for (int k=0;k<8;k++) a_ += dot4(ld4(&csh[k*4]), ld4(SW + e*36 + k*4));
      SV[32+e] = a_ * 0.35355339059327373f;
    }
    {
      int g = tid & 3;
      for (int s = tid>>2; s < 65; s += 64) {
        const float* u = (s == 0) ? SV : (SX + (s-1)*36);
        float4 uv[8];
        #pragma unroll
        for (int k=0;k<8;k++) uv[k] = ld4(u + k*4);
        #pragma unroll
        for (int ee=0; ee<16; ee++){
          int ew = 32 + g + 4*ee;
          float a_ = SW[3456+ew];
          #pragma unroll
          for (int k=0;k<8;k++) a_ += dot4(uv[k], ld4(SW + ew*36 + k*4));
          if (ew < 64) SY[(ew-32)*68 + s] = a_;
          else         SY[2176 + (ew-64)*68 + s] = a_;
        }
      }
    }
    __syncthreads();

    // C4: attention over 65 keys; wave=head, lane=key (lane0 also key 64)
    {
      int hh = tid>>6, l = tid&63;
      int njet = s_njet;
      float q8[8];
      #pragma unroll
      for (int d=0;d<8;d++) q8[d] = SV[32 + hh*8 + d];
      float sc_ = 0.f;
      #pragma unroll
      for (int d=0;d<8;d++) sc_ += q8[d]*SY[(hh*8+d)*68 + l];
      if (l > 0 && (l-1) >= njet) sc_ = -1000000000.0f;
      float sc64 = 0.f;
      if (l == 0){
        #pragma unroll
        for (int d=0;d<8;d++) sc64 += q8[d]*SY[(hh*8+d)*68 + 64];
        if (63 >= njet) sc64 = -1000000000.0f;
      }
      float mx = sc_;
      if (l == 0) mx = fmaxf(mx, sc64);
      mx = fmaxf(mx, __shfl_xor(mx,1));  mx = fmaxf(mx, __shfl_xor(mx,2));
      mx = fmaxf(mx, __shfl_xor(mx,4));  mx = fmaxf(mx, __shfl_xor(mx,8));
      mx = fmaxf(mx, __shfl_xor(mx,16)); mx = fmaxf(mx, __shfl_xor(mx,32));
      float p   = __expf(sc_ - mx);
      float p64 = (l==0) ? __expf(sc64 - mx) : 0.f;
      float ssum = p + p64;
      ssum += __shfl_xor(ssum,1); ssum += __shfl_xor(ssum,2); ssum += __shfl_xor(ssum,4);
      ssum += __shfl_xor(ssum,8); ssum += __shfl_xor(ssum,16); ssum += __shfl_xor(ssum,32);
      float inv = 1.f/ssum;
      #pragma unroll
      for (int d=0;d<8;d++){
        float term = p * SY[2176 + (hh*8+d)*68 + l];
        if (l == 0) term += p64 * SY[2176 + (hh*8+d)*68 + 64];
        term += __shfl_xor(term,1); term += __shfl_xor(term,2); term += __shfl_xor(term,4);
        term += __shfl_xor(term,8); term += __shfl_xor(term,16); term += __shfl_xor(term,32);
        if (l == 0) SV[64 + hh*8 + d] = term*inv;
      }
    }
    __syncthreads();

    // C5: out proj + cattn permute -> SV[96..127]
    if (tid < 32) {
      int e = tid;
      const float* wrow = cb_out_w + (cl*32 + e)*32;
      float a_ = cb_out_b[cl*32 + e];
      #pragma unroll
      for (int j=0;j<32;j++) a_ += SV[64+j]*wrow[j];
      float ca = cb_cattn[cl*4 + (e>>3)];
      SV[96 + (e&7)*4 + (e>>3)] = a_*ca;
    }
    __syncthreads();

    // C6: cls = ln(a2) + cls
    if (tid < 32) {
      float v = SV[96+tid];
      float s = v;
      s += __shfl_xor(s,1); s += __shfl_xor(s,2); s += __shfl_xor(s,4); s += __shfl_xor(s,8); s += __shfl_xor(s,16);
      float mean = s * 0.03125f;
      float d = v - mean;
      float q = d*d;
      q += __shfl_xor(q,1); q += __shfl_xor(q,2); q += __shfl_xor(q,4); q += __shfl_xor(q,8); q += __shfl_xor(q,16);
      float irs = rsqrtf(q*0.03125f + 1e-5f);
      csh[tid] = d*irs + csh[tid];
    }
    __syncthreads();

    // C7: FFN on cls vector
    if (tid < 32) {
      float v = csh[tid];
      float s = v;
      s += __shfl_xor(s,1); s += __shfl_xor(s,2); s += __shfl_xor(s,4); s += __shfl_xor(s,8); s += __shfl_xor(s,16);
      float mean = s * 0.03125f;
      float d = v - mean;
      float q = d*d;
      q += __shfl_xor(q,1); q += __shfl_xor(q,2); q += __shfl_xor(q,4); q += __shfl_xor(q,8); q += __shfl_xor(q,16);
      float irs = rsqrtf(q*0.03125f + 1e-5f);
      SV[tid] = d*irs;
    }
    __syncthreads();
    if (tid < 64) {
      int o = tid;
      const float* wrow = cb_f1_w + (cl*64+o)*32;
      float a_ = cb_f1_b[cl*64+o];
      #pragma unroll
      for (int j=0;j<32;j++) a_ += SV[j]*wrow[j];
      SV[128+o] = geluf(a_);
    }
    __syncthreads();
    if (tid < 64) {
      float v = SV[128+tid];
      float s = v;
      s += __shfl_xor(s,1); s += __shfl_xor(s,2); s += __shfl_xor(s,4); s += __shfl_xor(s,8);
      s += __shfl_xor(s,16); s += __shfl_xor(s,32);
      float mean = s * 0.015625f;
      float d = v - mean;
      float q = d*d;
      q += __shfl_xor(q,1); q += __shfl_xor(q,2); q += __shfl_xor(q,4); q += __shfl_xor(q,8);
      q += __shfl_xor(q,16); q += __shfl_xor(q,32);
      float irs = rsqrtf(q*0.015625f + 1e-5f);
      SV[192+tid] = d*irs;
    }
    __syncthreads();
    if (tid < 32) {
      int e = tid;
      const float* wrow = cb_f2_w + (cl*32+e)*64;
      float a_ = cb_f2_b[cl*32+e];
      #pragma unroll
      for (int j=0;j<64;j++) a_ += SV[192+j]*wrow[j];
      csh[e] = a_ + cb_wres[cl*32+e]*csh[e];
    }
    __syncthreads();
  }

  // ================== head ==================================================
  if (tid < 32) {
    float v = csh[tid];
    float s = v;
    s += __shfl_xor(s,1); s += __shfl_xor(s,2); s += __shfl_xor(s,4); s += __shfl_xor(s,8); s += __shfl_xor(s,16);
    float mean = s * 0.03125f;
    float d = v - mean;
    float q = d*d;
    q += __shfl_xor(q,1); q += __shfl_xor(q,2); q += __shfl_xor(q,4); q += __shfl_xor(q,8); q += __shfl_xor(q,16);
    float irs = rsqrtf(q*0.03125f + 1e-5f);
    SV[tid] = d*irs*norm_w[tid] + norm_b[tid];
  }
  __syncthreads();
  if (tid < 32) {
    float a_ = m1b[tid];
    const float* wrow = m1w + tid*32;
    #pragma unroll
    for (int j=0;j<32;j++) a_ += SV[j]*wrow[j];
    SV[64+tid] = fmaxf(a_, 0.f);
  }
  __syncthreads();
  if (tid < 32) {
    float a_ = mhb[tid];
    const float* wrow = mhw + tid*32;
    #pragma unroll
    for (int j=0;j<32;j++) a_ += SV[64+j]*wrow[j];
    SV[128+tid] = fmaxf(a_, 0.f);
  }
  __syncthreads();
  if (tid == 0) {
    float a_ = mfb[0];
    #pragma unroll
    for (int j=0;j<32;j++) a_ += SV[128+j]*mfw[j];
    out[n] = 1.f/(1.f + expf(-a_));
  }
}

// ---------------------------------------------------------------------------
extern "C" void kernel_launch(void* const* d_in, const int* in_sizes, int n_in,
                              void* d_out, int out_size, void* d_ws, size_t ws_size,
                              hipStream_t stream) {
  (void)in_sizes; (void)n_in; (void)out_size; (void)ws_size;
  const float* x     = (const float*)d_in[0];
  const float* fm    = (const float*)d_in[1];
  const int*   ji    = (const int*)  d_in[2];
  const float* bn_w  = (const float*)d_in[3];
  const float* bn_b  = (const float*)d_in[4];
  const float* e1w   = (const float*)d_in[5];
  const float* e1b   = (const float*)d_in[6];
  const float* e2w   = (const float*)d_in[7];
  const float* e2b   = (const float*)d_in[8];
  const float* c1w   = (const float*)d_in[9];
  const float* c1b   = (const float*)d_in[10];
  const float* c2w   = (const float*)d_in[11];
  const float* c2b   = (const float*)d_in[12];
  const float* pb_in_w  = (const float*)d_in[13];
  const float* pb_in_b  = (const float*)d_in[14];
  const float* pb_out_w = (const float*)d_in[15];
  const float* pb_out_b = (const float*)d_in[16];
  const float* pb_f1_w  = (const float*)d_in[17];
  const float* pb_f1_b  = (const float*)d_in[18];
  const float* pb_f2_w  = (const float*)d_in[19];
  const float* pb_f2_b  = (const float*)d_in[20];
  const float* pb_wres  = (const float*)d_in[21];
  const float* cb_in_w  = (const float*)d_in[22];
  const float* cb_in_b  = (const float*)d_in[23];
  const float* cb_out_w = (const float*)d_in[24];
  const float* cb_out_b = (const float*)d_in[25];
  const float* cb_f1_w  = (const float*)d_in[26];
  const float* cb_f1_b  = (const float*)d_in[27];
  const float* cb_f2_w  = (const float*)d_in[28];
  const float* cb_f2_b  = (const float*)d_in[29];
  const float* cb_wres  = (const float*)d_in[30];
  const float* cb_cattn = (const float*)d_in[31];
  const float* cls_tok  = (const float*)d_in[32];
  const float* norm_w   = (const float*)d_in[33];
  const float* norm_b   = (const float*)d_in[34];
  const float* m1w      = (const float*)d_in[35];
  const float* m1b      = (const float*)d_in[36];
  const float* mhw      = (const float*)d_in[37];
  const float* mhb      = (const float*)d_in[38];
  const float* mfw      = (const float*)d_in[39];
  const float* mfb      = (const float*)d_in[40];

  float* part   = (float*)d_ws;                 // 32768 floats
  float* stats  = part + 32768;                 // 128 floats
  float* G_h    = part + 40960;                 // 2048*2048 = 4,194,304 floats
  float* G_bias = G_h + 2048*2048;              // 2048*324  =   663,552 floats

  bn_stats_partial<<<256, 256, 0, stream>>>(x, fm, part);
  bn_stats_final<<<1, 64, 0, stream>>>(part, stats);
  k_embed<<<2048, 256, 0, stream>>>(x, fm, stats, bn_w, bn_b, e1w, e1b, e2w, e2b,
                                    c1w, c1b, c2w, c2b, G_h, G_bias);
  for (int li = 0; li < 4; li++) {
    k_layer<<<2048, 256, 0, stream>>>(ji,
        pb_in_w + li*3072, pb_in_b + li*96,
        pb_out_w + li*1024, pb_out_b + li*32,
        pb_f1_w + li*2048, pb_f1_b + li*64,
        pb_f2_w + li*2048, pb_f2_b + li*32,
        pb_wres + li*32, G_h, G_bias);
  }
  k_cls<<<2048, 256, 0, stream>>>(ji, cb_in_w, cb_in_b, cb_out_w, cb_out_b,
                                  cb_f1_w, cb_f1_b, cb_f2_w, cb_f2_b,
                                  cb_wres, cb_cattn, cls_tok, norm_w, norm_b,
                                  m1w, m1b, mhw, mhb, mfw, mfb, G_h, (float*)d_out);
}

// Round 5
// 1632.500 us; speedup vs baseline: 2.0732x; 1.1182x over previous
//
#include <hip/hip_runtime.h>

// ---------------------------------------------------------------------------
// Part_65712999629561: ParticleTransformer-ish forward, N=2048, P=64, E=32,
// H=4, D=8, 4 particle layers + 2 cls layers. f32 throughout.
// R4 post-mortem: k_embed spilled (256 VGPR, 1.85 GB traffic) — conv1 full
// unroll hoists 300+ LDS loads; attention s0 loop was FULL-unrolled (R1 bug),
// so online softmax never cut liveness.
// R5: (1) #pragma unroll 1 on attention chunk loop; (2) conv split into
// k_feat with unroll-1 kh loop; (3) k_embed2 = BN+e1+e2 only.
// ---------------------------------------------------------------------------

__device__ __forceinline__ float4 ld4(const float* p){ return *reinterpret_cast<const float4*>(p); }
__device__ __forceinline__ float dot4(float4 a, float4 b){ return a.x*b.x + a.y*b.y + a.z*b.z + a.w*b.w; }
__device__ __forceinline__ float geluf(float v){ return 0.5f*v*(1.0f + erff(v*0.70710678118654752f)); }

// ---------------- Kernel A: batchnorm stats --------------------------------
__global__ void bn_stats_partial(const float* __restrict__ x, const float* __restrict__ fm,
                                 float* __restrict__ part) {
  int p  = threadIdx.x & 63;
  int rg = threadIdx.x >> 6;
  float s = 0.f, s2 = 0.f;
  for (int R = blockIdx.x*4 + rg; R < 2048*64; R += 1024) {
    int n_ = R >> 6, c = R & 63;
    float v = (c < 60) ? x[n_*3840 + c*64 + p] : fm[n_*256 + (c-60)*64 + p];
    s += v; s2 += v*v;
  }
  __shared__ float sm[256], sm2[256];
  sm[threadIdx.x] = s; sm2[threadIdx.x] = s2;
  __syncthreads();
  if (threadIdx.x < 64) {
    part[blockIdx.x*128 + p]      = sm[p]+sm[64+p]+sm[128+p]+sm[192+p];
    part[blockIdx.x*128 + 64 + p] = sm2[p]+sm2[64+p]+sm2[128+p]+sm2[192+p];
  }
}

__global__ void bn_stats_final(const float* __restrict__ part, float* __restrict__ stats) {
  int p = threadIdx.x; // 64 threads
  float s = 0.f, s2 = 0.f;
  for (int b = 0; b < 256; b++){ s += part[b*128+p]; s2 += part[b*128+64+p]; }
  float mean = s * (1.f/131072.f);
  float var  = s2 * (1.f/131072.f) - mean*mean;
  stats[p]      = mean;
  stats[64+p]   = rsqrtf(var + 1e-5f);
}

// ---------------- row-LN helpers (256 threads, 64 rows, 4 lanes/row) --------
__device__ __forceinline__ void ln_rows32(const float* src, float* dst, int tid){
  int r = tid>>2, g = tid&3;
  const float* row = src + r*36;
  float v[8]; float s = 0.f;
  #pragma unroll
  for (int k=0;k<8;k++){ v[k] = row[g*8+k]; s += v[k]; }
  s += __shfl_xor(s,1); s += __shfl_xor(s,2);
  float mean = s * 0.03125f;
  float q = 0.f;
  #pragma unroll
  for (int k=0;k<8;k++){ float d = v[k]-mean; q += d*d; }
  q += __shfl_xor(q,1); q += __shfl_xor(q,2);
  float irs = rsqrtf(q*0.03125f + 1e-5f);
  float* drow = dst + r*36;
  #pragma unroll
  for (int k=0;k<8;k++) drow[g*8+k] = (v[k]-mean)*irs;
}

__device__ __forceinline__ void ln_rows64(const float* src, float* dst, int tid){
  int r = tid>>2, g = tid&3;
  const float* row = src + r*68;
  float v[16]; float s = 0.f;
  #pragma unroll
  for (int k=0;k<16;k++){ v[k] = row[g*16+k]; s += v[k]; }
  s += __shfl_xor(s,1); s += __shfl_xor(s,2);
  float mean = s * 0.015625f;
  float q = 0.f;
  #pragma unroll
  for (int k=0;k<16;k++){ float d = v[k]-mean; q += d*d; }
  q += __shfl_xor(q,1); q += __shfl_xor(q,2);
  float irs = rsqrtf(q*0.015625f + 1e-5f);
  float* drow = dst + r*68;
  #pragma unroll
  for (int k=0;k<16;k++) drow[g*16+k] = (v[k]-mean)*irs;
}

// ============================ K_feat =======================================
// jet features + conv1 + conv2 -> G_bias. One block per sample.
__global__ __launch_bounds__(256) void k_feat(
    const float* __restrict__ fm,
    const float* __restrict__ c1w_g, const float* __restrict__ c1b_g,
    const float* __restrict__ c2w_g, const float* __restrict__ c2b_g,
    float* __restrict__ G_bias)
{
  const int n   = blockIdx.x;
  const int tid = threadIdx.x;
  __shared__ float PQ[448];    // 7 x 64 particle quantities
  __shared__ float C1O[1024];  // conv1 out [4][16][16]
  __shared__ float CW[328];    // c1w[256], c1b[4]@256, c2w[64]@260, c2b[4]@324

  if (tid < 64) {
    int p = tid;
    float e_  = fm[n*256 + p];
    float px_ = fm[n*256 + 64 + p];
    float py_ = fm[n*256 + 128 + p];
    float pz_ = fm[n*256 + 192 + p];
    float pt_ = sqrtf(px_*px_ + py_*py_ + 1e-8f);
    float y_  = 0.5f * logf((e_ + pz_ + 1e-8f) / (e_ - pz_ + 1e-8f));
    float ph_ = atan2f(py_, px_ + 1e-8f);
    if (ph_ < 0.f) ph_ += 6.283185307179586f;
    PQ[0*64+p]=e_; PQ[1*64+p]=px_; PQ[2*64+p]=py_; PQ[3*64+p]=pz_;
    PQ[4*64+p]=pt_; PQ[5*64+p]=y_; PQ[6*64+p]=ph_;
  }
  CW[tid < 256 ? tid : 0] = c1w_g[tid < 256 ? tid : 0];
  if (tid < 4)  CW[256+tid] = c1b_g[tid];
  if (tid < 64) CW[260+tid] = c2w_g[tid];
  if (tid < 4)  CW[324+tid] = c2b_g[tid];
  __syncthreads();

  // conv1 (stride4, k4): out [4][16][16], thread = (ho,wo). unroll 1 on kh to
  // bound register pressure (full unroll hoisted 300+ LDS loads -> spill).
  {
    int ho = tid>>4, wo = tid&15;
    float a0=0.f,a1=0.f,a2=0.f,a3=0.f;
    #pragma unroll 1
    for (int kh=0; kh<4; kh++){
      int r = ho*4+kh;
      float er=PQ[r], pxr=PQ[64+r], pyr=PQ[128+r], pzr=PQ[192+r], ptr_=PQ[256+r], yr=PQ[320+r], phr=PQ[384+r];
      #pragma unroll
      for (int kw=0; kw<4; kw++){
        int c = wo*4+kw;
        if (r == c) continue;
        float ec=PQ[c], pxc=PQ[64+c], pyc=PQ[128+c], pzc=PQ[192+c], ptc=PQ[256+c], yc=PQ[320+c], phc=PQ[384+c];
        float dy = yr-yc, dp = phr-phc;
        float delta = sqrtf(fabsf(dy*dy + dp*dp));
        float pmin = fminf(ptr_, ptc);
        float kt = pmin * delta;
        float zz = pmin / (ptr_ + ptc + 1e-8f);
        float sx_ = pxr+pxc, sy_ = pyr+pyc, sz_ = pzr+pzc;
        float m2 = er*er + ec*ec - (sx_*sx_ + sy_*sy_ + sz_*sz_);
        int wb = kh*4+kw;
        a0 += delta*CW[0*64+wb] + kt*CW[0*64+16+wb] + zz*CW[0*64+32+wb] + m2*CW[0*64+48+wb];
        a1 += delta*CW[1*64+wb] + kt*CW[1*64+16+wb] + zz*CW[1*64+32+wb] + m2*CW[1*64+48+wb];
        a2 += delta*CW[2*64+wb] + kt*CW[2*64+16+wb] + zz*CW[2*64+32+wb] + m2*CW[2*64+48+wb];
        a3 += delta*CW[3*64+wb] + kt*CW[3*64+16+wb] + zz*CW[3*64+32+wb] + m2*CW[3*64+48+wb];
      }
    }
    C1O[0*256 + tid] = a0 + CW[256+0];
    C1O[1*256 + tid] = a1 + CW[256+1];
    C1O[2*256 + tid] = a2 + CW[256+2];
    C1O[3*256 + tid] = a3 + CW[256+3];
  }
  __syncthreads();

  // conv2 (stride2, k2, pad1) -> G_bias [n][co][i][j] (9x9)
  for (int idx = tid; idx < 324; idx += 256) {
    int co = idx/81, rem = idx%81, i = rem/9, j = rem%9;
    float s = CW[324+co];
    #pragma unroll
    for (int ci=0; ci<4; ci++){
      #pragma unroll
      for (int kh=0; kh<2; kh++){
        int ri = 2*i - 1 + kh;
        if (ri < 0 || ri >= 16) continue;
        #pragma unroll
        for (int kw=0; kw<2; kw++){
          int cj = 2*j - 1 + kw;
          if (cj < 0 || cj >= 16) continue;
          s += CW[260 + co*16 + ci*4 + kh*2 + kw] * C1O[ci*256 + ri*16 + cj];
        }
      }
    }
    G_bias[n*324 + idx] = s;
  }
}

// ============================ K_embed2 =====================================
// BN-apply + ln + e1 + ln + e2 -> G_h. One block per sample.
__global__ __launch_bounds__(256) void k_embed2(
    const float* __restrict__ x, const float* __restrict__ fm,
    const float* __restrict__ stats,
    const float* __restrict__ bn_w, const float* __restrict__ bn_b,
    const float* __restrict__ e1w, const float* __restrict__ e1b,
    const float* __restrict__ e2w, const float* __restrict__ e2b,
    float* __restrict__ G_h)
{
  const int n   = blockIdx.x;
  const int tid = threadIdx.x;

  __shared__ __align__(16) float SX[64*68];
  __shared__ __align__(16) float SY[64*68];
  __shared__ __align__(16) float SW[3584];
  __shared__ float SSTAT[128];

  if (tid < 64) {
    float mu = stats[tid], rs = stats[64+tid];
    float sc = rs * bn_w[tid];
    SSTAT[tid]      = sc;
    SSTAT[64+tid]   = bn_b[tid] - mu*sc;
  }
  __syncthreads();

  // stage normalized xc -> SX [t=c][p], stride 68
  {
    int p = tid & 63;
    float sc = SSTAT[p], sh = SSTAT[64+p];
    for (int c = tid>>6; c < 64; c += 4) {
      float v = (c < 60) ? x[n*3840 + c*64 + p] : fm[n*256 + (c-60)*64 + p];
      SX[c*68 + p] = v*sc + sh;
    }
  }
  __syncthreads();

  ln_rows64(SX, SY, tid);
  __syncthreads();

  // e1 GEMM (64x64x64) + gelu -> SX. Weights staged in 2 halves.
  {
    int t = tid>>2, g = tid&3;
    float acc[16];
    for (int idx = tid; idx < 2048; idx += 256){ int o = idx>>5, jj = idx&31; SW[o*36+jj] = e1w[o*64 + jj]; }
    for (int idx = tid; idx < 64; idx += 256) SW[3456+idx] = e1b[idx];
    __syncthreads();
    #pragma unroll
    for (int ee=0; ee<16; ee++) acc[ee] = SW[3456 + g + 4*ee];
    #pragma unroll
    for (int j=0;j<32;j+=4){
      float4 av = ld4(SY + t*68 + j);
      #pragma unroll
      for (int ee=0; ee<16; ee++) acc[ee] += dot4(av, ld4(SW + (g+4*ee)*36 + j));
    }
    __syncthreads();
    for (int idx = tid; idx < 2048; idx += 256){ int o = idx>>5, jj = idx&31; SW[o*36+jj] = e1w[o*64 + 32 + jj]; }
    __syncthreads();
    #pragma unroll
    for (int j=0;j<32;j+=4){
      float4 av = ld4(SY + t*68 + 32 + j);
      #pragma unroll
      for (int ee=0; ee<16; ee++) acc[ee] += dot4(av, ld4(SW + (g+4*ee)*36 + j));
    }
    #pragma unroll
    for (int ee=0; ee<16; ee++) SX[t*68 + g + 4*ee] = geluf(acc[ee]);
  }
  __syncthreads();

  // ln rows SX -> SY; stage e2 (32x64, stride 68) + bias
  ln_rows64(SX, SY, tid);
  for (int idx = tid; idx < 2048; idx += 256){ int o = idx>>6, j = idx&63; SW[o*68+j] = e2w[idx]; }
  for (int idx = tid; idx < 32; idx += 256) SW[3456+idx] = e2b[idx];
  __syncthreads();

  // e2 GEMM (64x32x64) + gelu -> G_h
  {
    int t = tid>>2, g = tid&3;
    float acc[8];
    #pragma unroll
    for (int ee=0; ee<8; ee++) acc[ee] = SW[3456 + g + 4*ee];
    #pragma unroll
    for (int j=0;j<64;j+=4){
      float4 av = ld4(SY + t*68 + j);
      #pragma unroll
      for (int ee=0; ee<8; ee++) acc[ee] += dot4(av, ld4(SW + (g+4*ee)*68 + j));
    }
    #pragma unroll
    for (int ee=0; ee<8; ee++) G_h[n*2048 + t*32 + g + 4*ee] = geluf(acc[ee]);
  }
}

// ============================ K_layer ======================================
// One particle-transformer layer. Weight pointers pre-offset on host.
__global__ __launch_bounds__(256) void k_layer(
    const int* __restrict__ ji,
    const float* __restrict__ in_w,  const float* __restrict__ in_b,
    const float* __restrict__ out_w, const float* __restrict__ out_b,
    const float* __restrict__ f1w,   const float* __restrict__ f1b,
    const float* __restrict__ f2w,   const float* __restrict__ f2b,
    const float* __restrict__ wres,
    float* __restrict__ G_h, const float* __restrict__ G_bias)
{
  const int n   = blockIdx.x;
  const int tid = threadIdx.x;

  __shared__ __align__(16) float SH[64*36];
  __shared__ __align__(16) float SX[64*36];
  __shared__ __align__(16) float SY[64*68];
  __shared__ __align__(16) float SW[3584];
  __shared__ float SBIAS[324];
  __shared__ int s_njet;

  if (tid == 0) s_njet = ji[n*2+1];
  for (int idx = tid; idx < 2048; idx += 256) {
    int t = idx>>5, e = idx&31;
    SH[t*36 + e] = G_h[n*2048 + idx];
  }
  for (int idx = tid; idx < 324; idx += 256) SBIAS[idx] = G_bias[n*324 + idx];
  __syncthreads();

  // L1: a = ln(h) -> SX (stride 36); stage in_w (96x32 -> stride 36) + in_b
  ln_rows32(SH, SX, tid);
  for (int idx = tid; idx < 3072; idx += 256){ int e = idx>>5, j = idx&31; SW[e*36+j] = in_w[idx]; }
  for (int idx = tid; idx < 96; idx += 256) SW[3456+idx] = in_b[idx];
  __syncthreads();

  // L2: k,v GEMM (64 tokens x 64 outs), write transposed into SY
  {
    int t = tid>>2, g = tid&3;
    float acc[16];
    #pragma unroll
    for (int ee=0; ee<16; ee++) acc[ee] = SW[3456 + 32 + g + 4*ee];
    #pragma unroll
    for (int j=0;j<32;j+=4){
      float4 av = ld4(SX + t*36 + j);
      #pragma unroll
      for (int ee=0; ee<16; ee++) acc[ee] += dot4(av, ld4(SW + (32+g+4*ee)*36 + j));
    }
    #pragma unroll
    for (int ee=0; ee<16; ee++){
      int ew = 32 + g + 4*ee;
      if (ew < 64) SY[(ew-32)*68 + t] = acc[ee];
      else         SY[2176 + (ew-64)*68 + t] = acc[ee];
    }
  }
  __syncthreads();

  // L3: attention (online softmax, 16-key chunks, runtime loop to bound regs)
  float od[8];
  {
    int hh = tid>>6, l = tid&63;
    float qd[8];
    #pragma unroll
    for (int d=0;d<8;d++){
      int e = hh*8+d;
      float a_ = SW[3456+e];
      #pragma unroll
      for (int k=0;k<8;k++) a_ += dot4(ld4(SX + l*36 + k*4), ld4(SW + e*36 + k*4));
      qd[d] = a_ * 0.35355339059327373f;
    }
    int njet = s_njet;
    float m = -3.4e38f, lsum = 0.f;
    #pragma unroll
    for (int d=0;d<8;d++) od[d] = 0.f;
    #pragma unroll 1
    for (int s0 = 0; s0 < 64; s0 += 16) {
      float sc[16];
      #pragma unroll
      for (int j=0;j<16;j++) sc[j]=0.f;
      #pragma unroll
      for (int d=0;d<8;d++){
        const float* kr = SY + (hh*8+d)*68 + s0;
        float qv = qd[d];
        #pragma unroll
        for (int j=0;j<16;j+=4){
          float4 kv4 = ld4(kr+j);
          sc[j]  +=qv*kv4.x; sc[j+1]+=qv*kv4.y;
          sc[j+2]+=qv*kv4.z; sc[j+3]+=qv*kv4.w;
        }
      }
      float cm = -3.4e38f;
      #pragma unroll
      for (int j=0;j<16;j++){
        int s = s0+j;
        float a_ = sc[j];
        if (s0 == 0 && l < 9 && j < 9) a_ += SBIAS[hh*81 + l*9 + j];
        a_ = (s >= njet) ? -1000000000.0f : a_;
        sc[j] = a_;
        cm = fmaxf(cm, a_);
      }
      float nm = fmaxf(m, cm);
      float corr = __expf(m - nm);        // first chunk: exp(-inf)=0
      lsum *= corr;
      #pragma unroll
      for (int d=0;d<8;d++) od[d] *= corr;
      #pragma unroll
      for (int j=0;j<16;j++){ sc[j] = __expf(sc[j]-nm); lsum += sc[j]; }
      #pragma unroll
      for (int d=0;d<8;d++){
        const float* vr = SY + 2176 + (hh*8+d)*68 + s0;
        float a_ = 0.f;
        #pragma unroll
        for (int j=0;j<16;j+=4){
          float4 vv = ld4(vr+j);
          a_ += sc[j]*vv.x + sc[j+1]*vv.y + sc[j+2]*vv.z + sc[j+3]*vv.w;
        }
        od[d] += a_;
      }
      m = nm;
    }
    float inv = 1.f/lsum;
    #pragma unroll
    for (int d=0;d<8;d++) od[d] *= inv;
  }
  __syncthreads();          // everyone done reading SX (a) and SW
  {
    int hh = tid>>6, l = tid&63;
    #pragma unroll
    for (int d=0;d<8;d++) SX[l*36 + hh*8 + d] = od[d];
  }
  for (int idx = tid; idx < 1024; idx += 256){ int e = idx>>5, j = idx&31; SW[e*36+j] = out_w[idx]; }
  for (int idx = tid; idx < 32; idx += 256) SW[3456+idx] = out_b[idx];
  __syncthreads();

  // L4: out-proj GEMM -> y in SY (stride 36)
  {
    int t = tid>>2, g = tid&3;
    float acc[8];
    #pragma unroll
    for (int ee=0; ee<8; ee++) acc[ee] = SW[3456 + g + 4*ee];
    #pragma unroll
    for (int j=0;j<32;j+=4){
      float4 av = ld4(SX + t*36 + j);
      #pragma unroll
      for (int ee=0; ee<8; ee++) acc[ee] += dot4(av, ld4(SW + (g+4*ee)*36 + j));
    }
    #pragma unroll
    for (int ee=0; ee<8; ee++) SY[t*36 + g + 4*ee] = acc[ee];
  }
  __syncthreads();

  // L5: h = ln(y) + h
  {
    int r = tid>>2, g = tid&3;
    const float* row = SY + r*36;
    float v[8]; float s = 0.f;
    #pragma unroll
    for (int k=0;k<8;k++){ v[k] = row[g*8+k]; s += v[k]; }
    s += __shfl_xor(s,1); s += __shfl_xor(s,2);
    float mean = s * 0.03125f;
    float q = 0.f;
    #pragma unroll
    for (int k=0;k<8;k++){ float d = v[k]-mean; q += d*d; }
    q += __shfl_xor(q,1); q += __shfl_xor(q,2);
    float irs = rsqrtf(q*0.03125f + 1e-5f);
    #pragma unroll
    for (int k=0;k<8;k++){ int e = g*8+k; SH[r*36+e] = (v[k]-mean)*irs + SH[r*36+e]; }
  }
  __syncthreads();

  // L6: t = ln(h) -> SX; stage f1 (64x32)
  ln_rows32(SH, SX, tid);
  for (int idx = tid; idx < 2048; idx += 256){ int e = idx>>5, j = idx&31; SW[e*36+j] = f1w[idx]; }
  for (int idx = tid; idx < 64; idx += 256) SW[3456+idx] = f1b[idx];
  __syncthreads();

  // L7: g1 = gelu(GEMM 64x64x32) -> SY stride 68
  {
    int t = tid>>2, g = tid&3;
    float acc[16];
    #pragma unroll
    for (int ee=0; ee<16; ee++) acc[ee] = SW[3456 + g + 4*ee];
    #pragma unroll
    for (int j=0;j<32;j+=4){
      float4 av = ld4(SX + t*36 + j);
      #pragma unroll
      for (int ee=0; ee<16; ee++) acc[ee] += dot4(av, ld4(SW + (g+4*ee)*36 + j));
    }
    #pragma unroll
    for (int ee=0; ee<16; ee++) SY[t*68 + g + 4*ee] = geluf(acc[ee]);
  }
  __syncthreads();

  // L8: ln64 rows SY in-place; stage f2 (32x64, stride 68) + bias + wres
  {
    int r = tid>>2, g = tid&3;
    float* row = SY + r*68;
    float v[16]; float s = 0.f;
    #pragma unroll
    for (int k=0;k<16;k++){ v[k] = row[g*16+k]; s += v[k]; }
    s += __shfl_xor(s,1); s += __shfl_xor(s,2);
    float mean = s * 0.015625f;
    float q = 0.f;
    #pragma unroll
    for (int k=0;k<16;k++){ float d = v[k]-mean; q += d*d; }
    q += __shfl_xor(q,1); q += __shfl_xor(q,2);
    float irs = rsqrtf(q*0.015625f + 1e-5f);
    #pragma unroll
    for (int k=0;k<16;k++) row[g*16+k] = (v[k]-mean)*irs;
  }
  for (int idx = tid; idx < 2048; idx += 256){ int e = idx>>6, j = idx&63; SW[e*68+j] = f2w[idx]; }
  for (int idx = tid; idx < 32; idx += 256){ SW[3456+idx] = f2b[idx]; SW[3488+idx] = wres[idx]; }
  __syncthreads();

  // L9: g2 GEMM (64x32x64); h = g2 + wres*h -> G_h
  {
    int t = tid>>2, g = tid&3;
    float acc[8];
    #pragma unroll
    for (int ee=0; ee<8; ee++) acc[ee] = SW[3456 + g + 4*ee];
    #pragma unroll
    for (int j=0;j<64;j+=4){
      float4 av = ld4(SY + t*68 + j);
      #pragma unroll
      for (int ee=0; ee<8; ee++) acc[ee] += dot4(av, ld4(SW + (g+4*ee)*68 + j));
    }
    #pragma unroll
    for (int ee=0; ee<8; ee++){
      int e = g+4*ee;
      G_h[n*2048 + t*32 + e] = acc[ee] + SW[3488+e]*SH[t*36+e];
    }
  }
}

// ============================ K_cls ========================================
// Both cls-attention layers + head. One block per sample.
__global__ __launch_bounds__(256) void k_cls(
    const int* __restrict__ ji,
    const float* __restrict__ cb_in_w, const float* __restrict__ cb_in_b,
    const float* __restrict__ cb_out_w, const float* __restrict__ cb_out_b,
    const float* __restrict__ cb_f1_w, const float* __restrict__ cb_f1_b,
    const float* __restrict__ cb_f2_w, const float* __restrict__ cb_f2_b,
    const float* __restrict__ cb_wres, const float* __restrict__ cb_cattn,
    const float* __restrict__ cls_tok, const float* __restrict__ norm_w, const float* __restrict__ norm_b,
    const float* __restrict__ m1w, const float* __restrict__ m1b,
    const float* __restrict__ mhw, const float* __restrict__ mhb,
    const float* __restrict__ mfw, const float* __restrict__ mfb,
    const float* __restrict__ G_h, float* __restrict__ out)
{
  const int n   = blockIdx.x;
  const int tid = threadIdx.x;

  __shared__ __align__(16) float SH[64*36];
  __shared__ __align__(16) float SX[64*36];
  __shared__ __align__(16) float SY[64*68];
  __shared__ __align__(16) float SW[3584];
  __shared__ __align__(16) float SV[320];
  __shared__ __align__(16) float csh[32];
  __shared__ int s_njet;

  if (tid == 0) s_njet = ji[n*2+1];
  for (int idx = tid; idx < 2048; idx += 256) {
    int t = idx>>5, e = idx&31;
    SH[t*36 + e] = G_h[n*2048 + idx];
  }
  __syncthreads();

  ln_rows32(SH, SX, tid);
  if (tid < 32) csh[tid] = cls_tok[tid];
  __syncthreads();

  for (int cl = 0; cl < 2; cl++) {
    const float* iw = cb_in_w + cl*3072;
    const float* ib = cb_in_b + cl*96;

    // C1: u0 = ln(csh) -> SV[0..31]; stage iw/ib
    if (tid < 32) {
      float v = csh[tid];
      float s = v;
      s += __shfl_xor(s,1); s += __shfl_xor(s,2); s += __shfl_xor(s,4); s += __shfl_xor(s,8); s += __shfl_xor(s,16);
      float mean = s * 0.03125f;
      float d = v - mean;
      float q = d*d;
      q += __shfl_xor(q,1); q += __shfl_xor(q,2); q += __shfl_xor(q,4); q += __shfl_xor(q,8); q += __shfl_xor(q,16);
      float irs = rsqrtf(q*0.03125f + 1e-5f);
      SV[tid] = d*irs;
    }
    for (int idx = tid; idx < 3072; idx += 256){ int e = idx>>5, j = idx&31; SW[e*36+j] = iw[idx]; }
    for (int idx = tid; idx < 96; idx += 256) SW[3456+idx] = ib[idx];
    __syncthreads();

    // C2: q from raw cls (tid<32) -> SV[32..63]; C3: k,v over 65 rows -> SY
    if (tid < 32) {
      int e = tid;
      float a_ = SW[3456+e];
      #pragma unroll
      for (int k=0;k<8;k++) a_ += dot4(ld4(&csh[k*4]), ld4(SW + e*36 + k*4));
      SV[32+e] = a_ * 0.35355339059327373f;
    }
    {
      int g = tid & 3;
      for (int s = tid>>2; s < 65; s += 64) {
        const float* u = (s == 0) ? SV : (SX + (s-1)*36);
        float4 uv[8];
        #pragma unroll
        for (int k=0;k<8;k++) uv[k] = ld4(u + k*4);
        #pragma unroll
        for (int ee=0; ee<16; ee++){
          int ew = 32 + g + 4*ee;
          float a_ = SW[3456+ew];
          #pragma unroll
          for (int k=0;k<8;k++) a_ += dot4(uv[k], ld4(SW + ew*36 + k*4));
          if (ew < 64) SY[(ew-32)*68 + s] = a_;
          else         SY[2176 + (ew-64)*68 + s] = a_;
        }
      }
    }
    __syncthreads();

    // C4: attention over 65 keys; wave=head, lane=key (lane0 also key 64)
    {
      int hh = tid>>6, l = tid&63;
      int njet = s_njet;
      float q8[8];
      #pragma unroll
      for (int d=0;d<8;d++) q8[d] = SV[32 + hh*8 + d];
      float sc_ = 0.f;
      #pragma unroll
      for (int d=0;d<8;d++) sc_ += q8[d]*SY[(hh*8+d)*68 + l];
      if (l > 0 && (l-1) >= njet) sc_ = -1000000000.0f;
      float sc64 = 0.f;
      if (l == 0){
        #pragma unroll
        for (int d=0;d<8;d++) sc64 += q8[d]*SY[(hh*8+d)*68 + 64];
        if (63 >= njet) sc64 = -1000000000.0f;
      }
      float mx = sc_;
      if (l == 0) mx = fmaxf(mx, sc64);
      mx = fmaxf(mx, __shfl_xor(mx,1));  mx = fmaxf(mx, __shfl_xor(mx,2));
      mx = fmaxf(mx, __shfl_xor(mx,4));  mx = fmaxf(mx, __shfl_xor(mx,8));
      mx = fmaxf(mx, __shfl_xor(mx,16)); mx = fmaxf(mx, __shfl_xor(mx,32));
      float p   = __expf(sc_ - mx);
      float p64 = (l==0) ? __expf(sc64 - mx) : 0.f;
      float ssum = p + p64;
      ssum += __shfl_xor(ssum,1); ssum += __shfl_xor(ssum,2); ssum += __shfl_xor(ssum,4);
      ssum += __shfl_xor(ssum,8); ssum += __shfl_xor(ssum,16); ssum += __shfl_xor(ssum,32);
      float inv = 1.f/ssum;
      #pragma unroll
      for (int d=0;d<8;d++){
        float term = p * SY[2176 + (hh*8+d)*68 + l];
        if (l == 0) term += p64 * SY[2176 + (hh*8+d)*68 + 64];
        term += __shfl_xor(term,1); term += __shfl_xor(term,2); term += __shfl_xor(term,4);
        term += __shfl_xor(term,8); term += __shfl_xor(term,16); term += __shfl_xor(term,32);
        if (l == 0) SV[64 + hh*8 + d] = term*inv;
      }
    }
    __syncthreads();

    // C5: out proj + cattn permute -> SV[96..127]
    if (tid < 32) {
      int e = tid;
      const float* wrow = cb_out_w + (cl*32 + e)*32;
      float a_ = cb_out_b[cl*32 + e];
      #pragma unroll
      for (int j=0;j<32;j++) a_ += SV[64+j]*wrow[j];
      float ca = cb_cattn[cl*4 + (e>>3)];
      SV[96 + (e&7)*4 + (e>>3)] = a_*ca;
    }
    __syncthreads();

    // C6: cls = ln(a2) + cls
    if (tid < 32) {
      float v = SV[96+tid];
      float s = v;
      s += __shfl_xor(s,1); s += __shfl_xor(s,2); s += __shfl_xor(s,4); s += __shfl_xor(s,8); s += __shfl_xor(s,16);
      float mean = s * 0.03125f;
      float d = v - mean;
      float q = d*d;
      q += __shfl_xor(q,1); q += __shfl_xor(q,2); q += __shfl_xor(q,4); q += __shfl_xor(q,8); q += __shfl_xor(q,16);
      float irs = rsqrtf(q*0.03125f + 1e-5f);
      csh[tid] = d*irs + csh[tid];
    }
    __syncthreads();

    // C7: FFN on cls vector
    if (tid < 32) {
      float v = csh[tid];
      float s = v;
      s += __shfl_xor(s,1); s += __shfl_xor(s,2); s += __shfl_xor(s,4); s += __shfl_xor(s,8); s += __shfl_xor(s,16);
      float mean = s * 0.03125f;
      float d = v - mean;
      float q = d*d;
      q += __shfl_xor(q,1); q += __shfl_xor(q,2); q += __shfl_xor(q,4); q += __shfl_xor(q,8); q += __shfl_xor(q,16);
      float irs = rsqrtf(q*0.03125f + 1e-5f);
      SV[tid] = d*irs;
    }
    __syncthreads();
    if (tid < 64) {
      int o = tid;
      const float* wrow = cb_f1_w + (cl*64+o)*32;
      float a_ = cb_f1_b[cl*64+o];
      #pragma unroll
      for (int j=0;j<32;j++) a_ += SV[j]*wrow[j];
      SV[128+o] = geluf(a_);
    }
    __syncthreads();
    if (tid < 64) {
      float v = SV[128+tid];
      float s = v;
      s += __shfl_xor(s,1); s += __shfl_xor(s,2); s += __shfl_xor(s,4); s += __shfl_xor(s,8);
      s += __shfl_xor(s,16); s += __shfl_xor(s,32);
      float mean = s * 0.015625f;
      float d = v - mean;
      float q = d*d;
      q += __shfl_xor(q,1); q += __shfl_xor(q,2); q += __shfl_xor(q,4); q += __shfl_xor(q,8);
      q += __shfl_xor(q,16); q += __shfl_xor(q,32);
      float irs = rsqrtf(q*0.015625f + 1e-5f);
      SV[192+tid] = d*irs;
    }
    __syncthreads();
    if (tid < 32) {
      int e = tid;
      const float* wrow = cb_f2_w + (cl*32+e)*64;
      float a_ = cb_f2_b[cl*32+e];
      #pragma unroll
      for (int j=0;j<64;j++) a_ += SV[192+j]*wrow[j];
      csh[e] = a_ + cb_wres[cl*32+e]*csh[e];
    }
    __syncthreads();
  }

  // ================== head ==================================================
  if (tid < 32) {
    float v = csh[tid];
    float s = v;
    s += __shfl_xor(s,1); s += __shfl_xor(s,2); s += __shfl_xor(s,4); s += __shfl_xor(s,8); s += __shfl_xor(s,16);
    float mean = s * 0.03125f;
    float d = v - mean;
    float q = d*d;
    q += __shfl_xor(q,1); q += __shfl_xor(q,2); q += __shfl_xor(q,4); q += __shfl_xor(q,8); q += __shfl_xor(q,16);
    float irs = rsqrtf(q*0.03125f + 1e-5f);
    SV[tid] = d*irs*norm_w[tid] + norm_b[tid];
  }
  __syncthreads();
  if (tid < 32) {
    float a_ = m1b[tid];
    const float* wrow = m1w + tid*32;
    #pragma unroll
    for (int j=0;j<32;j++) a_ += SV[j]*wrow[j];
    SV[64+tid] = fmaxf(a_, 0.f);
  }
  __syncthreads();
  if (tid < 32) {
    float a_ = mhb[tid];
    const float* wrow = mhw + tid*32;
    #pragma unroll
    for (int j=0;j<32;j++) a_ += SV[64+j]*wrow[j];
    SV[128+tid] = fmaxf(a_, 0.f);
  }
  __syncthreads();
  if (tid == 0) {
    float a_ = mfb[0];
    #pragma unroll
    for (int j=0;j<32;j++) a_ += SV[128+j]*mfw[j];
    out[n] = 1.f/(1.f + expf(-a_));
  }
}

// ---------------------------------------------------------------------------
extern "C" void kernel_launch(void* const* d_in, const int* in_sizes, int n_in,
                              void* d_out, int out_size, void* d_ws, size_t ws_size,
                              hipStream_t stream) {
  (void)in_sizes; (void)n_in; (void)out_size; (void)ws_size;
  const float* x     = (const float*)d_in[0];
  const float* fm    = (const float*)d_in[1];
  const int*   ji    = (const int*)  d_in[2];
  const float* bn_w  = (const float*)d_in[3];
  const float* bn_b  = (const float*)d_in[4];
  const float* e1w   = (const float*)d_in[5];
  const float* e1b   = (const float*)d_in[6];
  const float* e2w   = (const float*)d_in[7];
  const float* e2b   = (const float*)d_in[8];
  const float* c1w   = (const float*)d_in[9];
  const float* c1b   = (const float*)d_in[10];
  const float* c2w   = (const float*)d_in[11];
  const float* c2b   = (const float*)d_in[12];
  const float* pb_in_w  = (const float*)d_in[13];
  const float* pb_in_b  = (const float*)d_in[14];
  const float* pb_out_w = (const float*)d_in[15];
  const float* pb_out_b = (const float*)d_in[16];
  const float* pb_f1_w  = (const float*)d_in[17];
  const float* pb_f1_b  = (const float*)d_in[18];
  const float* pb_f2_w  = (const float*)d_in[19];
  const float* pb_f2_b  = (const float*)d_in[20];
  const float* pb_wres  = (const float*)d_in[21];
  const float* cb_in_w  = (const float*)d_in[22];
  const float* cb_in_b  = (const float*)d_in[23];
  const float* cb_out_w = (const float*)d_in[24];
  const float* cb_out_b = (const float*)d_in[25];
  const float* cb_f1_w  = (const float*)d_in[26];
  const float* cb_f1_b  = (const float*)d_in[27];
  const float* cb_f2_w  = (const float*)d_in[28];
  const float* cb_f2_b  = (const float*)d_in[29];
  const float* cb_wres  = (const float*)d_in[30];
  const float* cb_cattn = (const float*)d_in[31];
  const float* cls_tok  = (const float*)d_in[32];
  const float* norm_w   = (const float*)d_in[33];
  const float* norm_b   = (const float*)d_in[34];
  const float* m1w      = (const float*)d_in[35];
  const float* m1b      = (const float*)d_in[36];
  const float* mhw      = (const float*)d_in[37];
  const float* mhb      = (const float*)d_in[38];
  const float* mfw      = (const float*)d_in[39];
  const float* mfb      = (const float*)d_in[40];

  float* part   = (float*)d_ws;                 // 32768 floats
  float* stats  = part + 32768;                 // 128 floats
  float* G_h    = part + 40960;                 // 2048*2048 floats
  float* G_bias = G_h + 2048*2048;              // 2048*324 floats

  bn_stats_partial<<<256, 256, 0, stream>>>(x, fm, part);
  bn_stats_final<<<1, 64, 0, stream>>>(part, stats);
  k_feat<<<2048, 256, 0, stream>>>(fm, c1w, c1b, c2w, c2b, G_bias);
  k_embed2<<<2048, 256, 0, stream>>>(x, fm, stats, bn_w, bn_b, e1w, e1b, e2w, e2b, G_h);
  for (int li = 0; li < 4; li++) {
    k_layer<<<2048, 256, 0, stream>>>(ji,
        pb_in_w + li*3072, pb_in_b + li*96,
        pb_out_w + li*1024, pb_out_b + li*32,
        pb_f1_w + li*2048, pb_f1_b + li*64,
        pb_f2_w + li*2048, pb_f2_b + li*32,
        pb_wres + li*32, G_h, G_bias);
  }
  k_cls<<<2048, 256, 0, stream>>>(ji, cb_in_w, cb_in_b, cb_out_w, cb_out_b,
                                  cb_f1_w, cb_f1_b, cb_f2_w, cb_f2_b,
                                  cb_wres, cb_cattn, cls_tok, norm_w, norm_b,
                                  m1w, m1b, mhw, mhb, mfw, mfb, G_h, (float*)d_out);
}

// Round 6
// 781.885 us; speedup vs baseline: 4.3286x; 2.0879x over previous
//
#include <hip/hip_runtime.h>

// ---------------------------------------------------------------------------
// Part_65712999629561: ParticleTransformer forward, N=2048, P=64, E=32, H=4,
// D=8. Split kernels: stats, feat(conv), embed, 4x layer, cls.
// R5 post-mortem: k_embed2 spilled (256 VGPR, 1.79 GB scratch) — full-unroll
// GEMM j-loops hoist ~130 LDS loads with acc[16] live.
// R6: all 64-token GEMMs restructured to 4x4 register tiles (16 tok-groups x
// 16 out-groups), unroll-2 K loops. ~60 live VGPR per GEMM and 8.5x less LDS
// traffic per FMA.
// ---------------------------------------------------------------------------

__device__ __forceinline__ float4 ld4(const float* p){ return *reinterpret_cast<const float4*>(p); }
__device__ __forceinline__ float dot4(float4 a, float4 b){ return a.x*b.x + a.y*b.y + a.z*b.z + a.w*b.w; }
__device__ __forceinline__ float geluf(float v){ return 0.5f*v*(1.0f + erff(v*0.70710678118654752f)); }

// ---------------- Kernel A: batchnorm stats --------------------------------
__global__ void bn_stats_partial(const float* __restrict__ x, const float* __restrict__ fm,
                                 float* __restrict__ part) {
  int p  = threadIdx.x & 63;
  int rg = threadIdx.x >> 6;
  float s = 0.f, s2 = 0.f;
  for (int R = blockIdx.x*4 + rg; R < 2048*64; R += 1024) {
    int n_ = R >> 6, c = R & 63;
    float v = (c < 60) ? x[n_*3840 + c*64 + p] : fm[n_*256 + (c-60)*64 + p];
    s += v; s2 += v*v;
  }
  __shared__ float sm[256], sm2[256];
  sm[threadIdx.x] = s; sm2[threadIdx.x] = s2;
  __syncthreads();
  if (threadIdx.x < 64) {
    part[blockIdx.x*128 + p]      = sm[p]+sm[64+p]+sm[128+p]+sm[192+p];
    part[blockIdx.x*128 + 64 + p] = sm2[p]+sm2[64+p]+sm2[128+p]+sm2[192+p];
  }
}

__global__ void bn_stats_final(const float* __restrict__ part, float* __restrict__ stats) {
  int p = threadIdx.x; // 64 threads
  float s = 0.f, s2 = 0.f;
  for (int b = 0; b < 256; b++){ s += part[b*128+p]; s2 += part[b*128+64+p]; }
  float mean = s * (1.f/131072.f);
  float var  = s2 * (1.f/131072.f) - mean*mean;
  stats[p]      = mean;
  stats[64+p]   = rsqrtf(var + 1e-5f);
}

// ---------------- row-LN helpers (256 threads, 64 rows, 4 lanes/row) --------
__device__ __forceinline__ void ln_rows32(const float* src, float* dst, int tid){
  int r = tid>>2, g = tid&3;
  const float* row = src + r*36;
  float v[8]; float s = 0.f;
  #pragma unroll
  for (int k=0;k<8;k++){ v[k] = row[g*8+k]; s += v[k]; }
  s += __shfl_xor(s,1); s += __shfl_xor(s,2);
  float mean = s * 0.03125f;
  float q = 0.f;
  #pragma unroll
  for (int k=0;k<8;k++){ float d = v[k]-mean; q += d*d; }
  q += __shfl_xor(q,1); q += __shfl_xor(q,2);
  float irs = rsqrtf(q*0.03125f + 1e-5f);
  float* drow = dst + r*36;
  #pragma unroll
  for (int k=0;k<8;k++) drow[g*8+k] = (v[k]-mean)*irs;
}

__device__ __forceinline__ void ln_rows64(const float* src, float* dst, int tid){
  int r = tid>>2, g = tid&3;
  const float* row = src + r*68;
  float v[16]; float s = 0.f;
  #pragma unroll
  for (int k=0;k<16;k++){ v[k] = row[g*16+k]; s += v[k]; }
  s += __shfl_xor(s,1); s += __shfl_xor(s,2);
  float mean = s * 0.015625f;
  float q = 0.f;
  #pragma unroll
  for (int k=0;k<16;k++){ float d = v[k]-mean; q += d*d; }
  q += __shfl_xor(q,1); q += __shfl_xor(q,2);
  float irs = rsqrtf(q*0.015625f + 1e-5f);
  float* drow = dst + r*68;
  #pragma unroll
  for (int k=0;k<16;k++) drow[g*16+k] = (v[k]-mean)*irs;
}

// ============================ K_feat =======================================
__global__ __launch_bounds__(256) void k_feat(
    const float* __restrict__ fm,
    const float* __restrict__ c1w_g, const float* __restrict__ c1b_g,
    const float* __restrict__ c2w_g, const float* __restrict__ c2b_g,
    float* __restrict__ G_bias)
{
  const int n   = blockIdx.x;
  const int tid = threadIdx.x;
  __shared__ float PQ[448];
  __shared__ float C1O[1024];
  __shared__ float CW[328];

  if (tid < 64) {
    int p = tid;
    float e_  = fm[n*256 + p];
    float px_ = fm[n*256 + 64 + p];
    float py_ = fm[n*256 + 128 + p];
    float pz_ = fm[n*256 + 192 + p];
    float pt_ = sqrtf(px_*px_ + py_*py_ + 1e-8f);
    float y_  = 0.5f * logf((e_ + pz_ + 1e-8f) / (e_ - pz_ + 1e-8f));
    float ph_ = atan2f(py_, px_ + 1e-8f);
    if (ph_ < 0.f) ph_ += 6.283185307179586f;
    PQ[0*64+p]=e_; PQ[1*64+p]=px_; PQ[2*64+p]=py_; PQ[3*64+p]=pz_;
    PQ[4*64+p]=pt_; PQ[5*64+p]=y_; PQ[6*64+p]=ph_;
  }
  CW[tid < 256 ? tid : 0] = c1w_g[tid < 256 ? tid : 0];
  if (tid < 4)  CW[256+tid] = c1b_g[tid];
  if (tid < 64) CW[260+tid] = c2w_g[tid];
  if (tid < 4)  CW[324+tid] = c2b_g[tid];
  __syncthreads();

  {
    int ho = tid>>4, wo = tid&15;
    float a0=0.f,a1=0.f,a2=0.f,a3=0.f;
    #pragma unroll 1
    for (int kh=0; kh<4; kh++){
      int r = ho*4+kh;
      float er=PQ[r], pxr=PQ[64+r], pyr=PQ[128+r], pzr=PQ[192+r], ptr_=PQ[256+r], yr=PQ[320+r], phr=PQ[384+r];
      #pragma unroll
      for (int kw=0; kw<4; kw++){
        int c = wo*4+kw;
        if (r == c) continue;
        float ec=PQ[c], pxc=PQ[64+c], pyc=PQ[128+c], pzc=PQ[192+c], ptc=PQ[256+c], yc=PQ[320+c], phc=PQ[384+c];
        float dy = yr-yc, dp = phr-phc;
        float delta = sqrtf(fabsf(dy*dy + dp*dp));
        float pmin = fminf(ptr_, ptc);
        float kt = pmin * delta;
        float zz = pmin / (ptr_ + ptc + 1e-8f);
        float sx_ = pxr+pxc, sy_ = pyr+pyc, sz_ = pzr+pzc;
        float m2 = er*er + ec*ec - (sx_*sx_ + sy_*sy_ + sz_*sz_);
        int wb = kh*4+kw;
        a0 += delta*CW[0*64+wb] + kt*CW[0*64+16+wb] + zz*CW[0*64+32+wb] + m2*CW[0*64+48+wb];
        a1 += delta*CW[1*64+wb] + kt*CW[1*64+16+wb] + zz*CW[1*64+32+wb] + m2*CW[1*64+48+wb];
        a2 += delta*CW[2*64+wb] + kt*CW[2*64+16+wb] + zz*CW[2*64+32+wb] + m2*CW[2*64+48+wb];
        a3 += delta*CW[3*64+wb] + kt*CW[3*64+16+wb] + zz*CW[3*64+32+wb] + m2*CW[3*64+48+wb];
      }
    }
    C1O[0*256 + tid] = a0 + CW[256+0];
    C1O[1*256 + tid] = a1 + CW[256+1];
    C1O[2*256 + tid] = a2 + CW[256+2];
    C1O[3*256 + tid] = a3 + CW[256+3];
  }
  __syncthreads();

  for (int idx = tid; idx < 324; idx += 256) {
    int co = idx/81, rem = idx%81, i = rem/9, j = rem%9;
    float s = CW[324+co];
    #pragma unroll
    for (int ci=0; ci<4; ci++){
      #pragma unroll
      for (int kh=0; kh<2; kh++){
        int ri = 2*i - 1 + kh;
        if (ri < 0 || ri >= 16) continue;
        #pragma unroll
        for (int kw=0; kw<2; kw++){
          int cj = 2*j - 1 + kw;
          if (cj < 0 || cj >= 16) continue;
          s += CW[260 + co*16 + ci*4 + kh*2 + kw] * C1O[ci*256 + ri*16 + cj];
        }
      }
    }
    G_bias[n*324 + idx] = s;
  }
}

// ============================ K_embed2 =====================================
// BN-apply + ln + e1 + ln + e2 -> G_h. 4x4-tile GEMMs.
__global__ __launch_bounds__(256) void k_embed2(
    const float* __restrict__ x, const float* __restrict__ fm,
    const float* __restrict__ stats,
    const float* __restrict__ bn_w, const float* __restrict__ bn_b,
    const float* __restrict__ e1w, const float* __restrict__ e1b,
    const float* __restrict__ e2w, const float* __restrict__ e2b,
    float* __restrict__ G_h)
{
  const int n   = blockIdx.x;
  const int tid = threadIdx.x;

  __shared__ __align__(16) float SX[64*68];
  __shared__ __align__(16) float SY[64*68];
  __shared__ __align__(16) float SW[4448];   // 64x68 weights + bias @4352
  __shared__ float SSTAT[128];

  if (tid < 64) {
    float mu = stats[tid], rs = stats[64+tid];
    float sc = rs * bn_w[tid];
    SSTAT[tid]      = sc;
    SSTAT[64+tid]   = bn_b[tid] - mu*sc;
  }
  __syncthreads();

  {
    int p = tid & 63;
    float sc = SSTAT[p], sh = SSTAT[64+p];
    for (int c = tid>>6; c < 64; c += 4) {
      float v = (c < 60) ? x[n*3840 + c*64 + p] : fm[n*256 + (c-60)*64 + p];
      SX[c*68 + p] = v*sc + sh;
    }
  }
  __syncthreads();

  ln_rows64(SX, SY, tid);                                   // SY = ln(xc)
  for (int idx = tid; idx < 4096; idx += 256){ SW[(idx>>6)*68 + (idx&63)] = e1w[idx]; }
  for (int idx = tid; idx < 64; idx += 256) SW[4352+idx] = e1b[idx];
  __syncthreads();

  // e1 GEMM 64x64 K=64, 4x4 tile -> SX (stride 68) with gelu
  {
    int tg = tid>>4, og = tid&15;
    float acc[4][4];
    #pragma unroll
    for (int o=0;o<4;o++){ float b = SW[4352+og*4+o];
      #pragma unroll
      for (int i=0;i<4;i++) acc[i][o] = b; }
    #pragma unroll 2
    for (int j=0;j<64;j+=4){
      float4 av[4], wv[4];
      #pragma unroll
      for (int i=0;i<4;i++) av[i] = ld4(SY + (tg*4+i)*68 + j);
      #pragma unroll
      for (int o=0;o<4;o++) wv[o] = ld4(SW + (og*4+o)*68 + j);
      #pragma unroll
      for (int i=0;i<4;i++)
        #pragma unroll
        for (int o=0;o<4;o++) acc[i][o] += dot4(av[i], wv[o]);
    }
    __syncthreads();   // SY reads done; also SX xc reads done pre-barrier
    #pragma unroll
    for (int i=0;i<4;i++)
      #pragma unroll
      for (int o=0;o<4;o++) SX[(tg*4+i)*68 + og*4+o] = geluf(acc[i][o]);
  }
  __syncthreads();

  ln_rows64(SX, SY, tid);                                   // SY = ln(h1)
  for (int idx = tid; idx < 2048; idx += 256){ SW[(idx>>6)*68 + (idx&63)] = e2w[idx]; }
  for (int idx = tid; idx < 32; idx += 256) SW[4352+idx] = e2b[idx];
  __syncthreads();

  // e2 GEMM 64x32 K=64, 4x2 tile -> G_h with gelu
  {
    int tg = tid>>4, og = tid&15;
    float acc[4][2];
    #pragma unroll
    for (int o=0;o<2;o++){ float b = SW[4352+og*2+o];
      #pragma unroll
      for (int i=0;i<4;i++) acc[i][o] = b; }
    #pragma unroll 2
    for (int j=0;j<64;j+=4){
      float4 av[4], wv[2];
      #pragma unroll
      for (int i=0;i<4;i++) av[i] = ld4(SY + (tg*4+i)*68 + j);
      #pragma unroll
      for (int o=0;o<2;o++) wv[o] = ld4(SW + (og*2+o)*68 + j);
      #pragma unroll
      for (int i=0;i<4;i++)
        #pragma unroll
        for (int o=0;o<2;o++) acc[i][o] += dot4(av[i], wv[o]);
    }
    #pragma unroll
    for (int i=0;i<4;i++)
      #pragma unroll
      for (int o=0;o<2;o++) G_h[n*2048 + (tg*4+i)*32 + og*2+o] = geluf(acc[i][o]);
  }
}

// ============================ K_layer ======================================
__global__ __launch_bounds__(256) void k_layer(
    const int* __restrict__ ji,
    const float* __restrict__ in_w,  const float* __restrict__ in_b,
    const float* __restrict__ out_w, const float* __restrict__ out_b,
    const float* __restrict__ f1w,   const float* __restrict__ f1b,
    const float* __restrict__ f2w,   const float* __restrict__ f2b,
    const float* __restrict__ wres,
    float* __restrict__ G_h, const float* __restrict__ G_bias)
{
  const int n   = blockIdx.x;
  const int tid = threadIdx.x;

  __shared__ __align__(16) float SH[64*36];
  __shared__ __align__(16) float SX[64*36];
  __shared__ __align__(16) float SY[64*68];
  __shared__ __align__(16) float SW[3584];
  __shared__ float SBIAS[324];
  __shared__ int s_njet;

  if (tid == 0) s_njet = ji[n*2+1];
  for (int idx = tid; idx < 2048; idx += 256) {
    int t = idx>>5, e = idx&31;
    SH[t*36 + e] = G_h[n*2048 + idx];
  }
  for (int idx = tid; idx < 324; idx += 256) SBIAS[idx] = G_bias[n*324 + idx];
  __syncthreads();

  // L1: a = ln(h) -> SX; stage in_w (96x32, stride 36) + in_b @3456
  ln_rows32(SH, SX, tid);
  for (int idx = tid; idx < 3072; idx += 256){ SW[(idx>>5)*36 + (idx&31)] = in_w[idx]; }
  for (int idx = tid; idx < 96; idx += 256) SW[3456+idx] = in_b[idx];
  __syncthreads();

  // L2: k,v GEMM 64x64 K=32, 4x4 tile, transposed write into SY
  {
    int tg = tid>>4, og = tid&15;
    float acc[4][4];
    #pragma unroll
    for (int o=0;o<4;o++){ float b = SW[3456+32+og*4+o];
      #pragma unroll
      for (int i=0;i<4;i++) acc[i][o] = b; }
    #pragma unroll 2
    for (int j=0;j<32;j+=4){
      float4 av[4], wv[4];
      #pragma unroll
      for (int i=0;i<4;i++) av[i] = ld4(SX + (tg*4+i)*36 + j);
      #pragma unroll
      for (int o=0;o<4;o++) wv[o] = ld4(SW + (32+og*4+o)*36 + j);
      #pragma unroll
      for (int i=0;i<4;i++)
        #pragma unroll
        for (int o=0;o<4;o++) acc[i][o] += dot4(av[i], wv[o]);
    }
    #pragma unroll
    for (int i=0;i<4;i++)
      #pragma unroll
      for (int o=0;o<4;o++){
        int ew = 32 + og*4+o, t = tg*4+i;
        if (ew < 64) SY[(ew-32)*68 + t] = acc[i][o];
        else         SY[2176 + (ew-64)*68 + t] = acc[i][o];
      }
  }
  __syncthreads();

  // L3: attention (online softmax, runtime chunk loop). wave=head, lane=query.
  float od[8];
  {
    int hh = tid>>6, l = tid&63;
    float qd[8];
    #pragma unroll
    for (int d=0;d<8;d++){
      int e = hh*8+d;
      float a_ = SW[3456+e];
      #pragma unroll
      for (int k=0;k<8;k++) a_ += dot4(ld4(SX + l*36 + k*4), ld4(SW + e*36 + k*4));
      qd[d] = a_ * 0.35355339059327373f;
    }
    int njet = s_njet;
    float m = -3.4e38f, lsum = 0.f;
    #pragma unroll
    for (int d=0;d<8;d++) od[d] = 0.f;
    #pragma unroll 1
    for (int s0 = 0; s0 < 64; s0 += 16) {
      float sc[16];
      #pragma unroll
      for (int j=0;j<16;j++) sc[j]=0.f;
      #pragma unroll
      for (int d=0;d<8;d++){
        const float* kr = SY + (hh*8+d)*68 + s0;
        float qv = qd[d];
        #pragma unroll
        for (int j=0;j<16;j+=4){
          float4 kv4 = ld4(kr+j);
          sc[j]  +=qv*kv4.x; sc[j+1]+=qv*kv4.y;
          sc[j+2]+=qv*kv4.z; sc[j+3]+=qv*kv4.w;
        }
      }
      float cm = -3.4e38f;
      #pragma unroll
      for (int j=0;j<16;j++){
        int s = s0+j;
        float a_ = sc[j];
        if (s0 == 0 && l < 9 && j < 9) a_ += SBIAS[hh*81 + l*9 + j];
        a_ = (s >= njet) ? -1000000000.0f : a_;
        sc[j] = a_;
        cm = fmaxf(cm, a_);
      }
      float nm = fmaxf(m, cm);
      float corr = __expf(m - nm);
      lsum *= corr;
      #pragma unroll
      for (int d=0;d<8;d++) od[d] *= corr;
      #pragma unroll
      for (int j=0;j<16;j++){ sc[j] = __expf(sc[j]-nm); lsum += sc[j]; }
      #pragma unroll
      for (int d=0;d<8;d++){
        const float* vr = SY + 2176 + (hh*8+d)*68 + s0;
        float a_ = 0.f;
        #pragma unroll
        for (int j=0;j<16;j+=4){
          float4 vv = ld4(vr+j);
          a_ += sc[j]*vv.x + sc[j+1]*vv.y + sc[j+2]*vv.z + sc[j+3]*vv.w;
        }
        od[d] += a_;
      }
      m = nm;
    }
    float inv = 1.f/lsum;
    #pragma unroll
    for (int d=0;d<8;d++) od[d] *= inv;
  }
  __syncthreads();
  {
    int hh = tid>>6, l = tid&63;
    #pragma unroll
    for (int d=0;d<8;d++) SX[l*36 + hh*8 + d] = od[d];
  }
  for (int idx = tid; idx < 1024; idx += 256){ SW[(idx>>5)*36 + (idx&31)] = out_w[idx]; }
  for (int idx = tid; idx < 32; idx += 256) SW[3456+idx] = out_b[idx];
  __syncthreads();

  // L4: out-proj 64x32 K=32, 4x2 tile -> SY stride 36
  {
    int tg = tid>>4, og = tid&15;
    float acc[4][2];
    #pragma unroll
    for (int o=0;o<2;o++){ float b = SW[3456+og*2+o];
      #pragma unroll
      for (int i=0;i<4;i++) acc[i][o] = b; }
    #pragma unroll 2
    for (int j=0;j<32;j+=4){
      float4 av[4], wv[2];
      #pragma unroll
      for (int i=0;i<4;i++) av[i] = ld4(SX + (tg*4+i)*36 + j);
      #pragma unroll
      for (int o=0;o<2;o++) wv[o] = ld4(SW + (og*2+o)*36 + j);
      #pragma unroll
      for (int i=0;i<4;i++)
        #pragma unroll
        for (int o=0;o<2;o++) acc[i][o] += dot4(av[i], wv[o]);
    }
    #pragma unroll
    for (int i=0;i<4;i++)
      #pragma unroll
      for (int o=0;o<2;o++) SY[(tg*4+i)*36 + og*2+o] = acc[i][o];
  }
  __syncthreads();

  // L5: h = ln(y) + h
  {
    int r = tid>>2, g = tid&3;
    const float* row = SY + r*36;
    float v[8]; float s = 0.f;
    #pragma unroll
    for (int k=0;k<8;k++){ v[k] = row[g*8+k]; s += v[k]; }
    s += __shfl_xor(s,1); s += __shfl_xor(s,2);
    float mean = s * 0.03125f;
    float q = 0.f;
    #pragma unroll
    for (int k=0;k<8;k++){ float d = v[k]-mean; q += d*d; }
    q += __shfl_xor(q,1); q += __shfl_xor(q,2);
    float irs = rsqrtf(q*0.03125f + 1e-5f);
    #pragma unroll
    for (int k=0;k<8;k++){ int e = g*8+k; SH[r*36+e] = (v[k]-mean)*irs + SH[r*36+e]; }
  }
  __syncthreads();

  // L6: t = ln(h) -> SX; stage f1 (64x32)
  ln_rows32(SH, SX, tid);
  for (int idx = tid; idx < 2048; idx += 256){ SW[(idx>>5)*36 + (idx&31)] = f1w[idx]; }
  for (int idx = tid; idx < 64; idx += 256) SW[3456+idx] = f1b[idx];
  __syncthreads();

  // L7: g1 GEMM 64x64 K=32, 4x4 tile -> SY stride 68 with gelu
  {
    int tg = tid>>4, og = tid&15;
    float acc[4][4];
    #pragma unroll
    for (int o=0;o<4;o++){ float b = SW[3456+og*4+o];
      #pragma unroll
      for (int i=0;i<4;i++) acc[i][o] = b; }
    #pragma unroll 2
    for (int j=0;j<32;j+=4){
      float4 av[4], wv[4];
      #pragma unroll
      for (int i=0;i<4;i++) av[i] = ld4(SX + (tg*4+i)*36 + j);
      #pragma unroll
      for (int o=0;o<4;o++) wv[o] = ld4(SW + (og*4+o)*36 + j);
      #pragma unroll
      for (int i=0;i<4;i++)
        #pragma unroll
        for (int o=0;o<4;o++) acc[i][o] += dot4(av[i], wv[o]);
    }
    #pragma unroll
    for (int i=0;i<4;i++)
      #pragma unroll
      for (int o=0;o<4;o++) SY[(tg*4+i)*68 + og*4+o] = geluf(acc[i][o]);
  }
  __syncthreads();

  // L8: ln64 in-place on SY; stage f2 (32x64, stride 68) + bias + wres
  {
    int r = tid>>2, g = tid&3;
    float* row = SY + r*68;
    float v[16]; float s = 0.f;
    #pragma unroll
    for (int k=0;k<16;k++){ v[k] = row[g*16+k]; s += v[k]; }
    s += __shfl_xor(s,1); s += __shfl_xor(s,2);
    float mean = s * 0.015625f;
    float q = 0.f;
    #pragma unroll
    for (int k=0;k<16;k++){ float d = v[k]-mean; q += d*d; }
    q += __shfl_xor(q,1); q += __shfl_xor(q,2);
    float irs = rsqrtf(q*0.015625f + 1e-5f);
    #pragma unroll
    for (int k=0;k<16;k++) row[g*16+k] = (v[k]-mean)*irs;
  }
  for (int idx = tid; idx < 2048; idx += 256){ SW[(idx>>6)*68 + (idx&63)] = f2w[idx]; }
  for (int idx = tid; idx < 32; idx += 256){ SW[3456+idx] = f2b[idx]; SW[3488+idx] = wres[idx]; }
  __syncthreads();

  // L9: g2 GEMM 64x32 K=64, 4x2 tile; h = g2 + wres*h -> G_h
  {
    int tg = tid>>4, og = tid&15;
    float acc[4][2];
    #pragma unroll
    for (int o=0;o<2;o++){ float b = SW[3456+og*2+o];
      #pragma unroll
      for (int i=0;i<4;i++) acc[i][o] = b; }
    #pragma unroll 2
    for (int j=0;j<64;j+=4){
      float4 av[4], wv[2];
      #pragma unroll
      for (int i=0;i<4;i++) av[i] = ld4(SY + (tg*4+i)*68 + j);
      #pragma unroll
      for (int o=0;o<2;o++) wv[o] = ld4(SW + (og*2+o)*68 + j);
      #pragma unroll
      for (int i=0;i<4;i++)
        #pragma unroll
        for (int o=0;o<2;o++) acc[i][o] += dot4(av[i], wv[o]);
    }
    #pragma unroll
    for (int i=0;i<4;i++)
      #pragma unroll
      for (int o=0;o<2;o++){
        int e = og*2+o, t = tg*4+i;
        G_h[n*2048 + t*32 + e] = acc[i][o] + SW[3488+e]*SH[t*36+e];
      }
  }
}

// ============================ K_cls ========================================
__global__ __launch_bounds__(256) void k_cls(
    const int* __restrict__ ji,
    const float* __restrict__ cb_in_w, const float* __restrict__ cb_in_b,
    const float* __restrict__ cb_out_w, const float* __restrict__ cb_out_b,
    const float* __restrict__ cb_f1_w, const float* __restrict__ cb_f1_b,
    const float* __restrict__ cb_f2_w, const float* __restrict__ cb_f2_b,
    const float* __restrict__ cb_wres, const float* __restrict__ cb_cattn,
    const float* __restrict__ cls_tok, const float* __restrict__ norm_w, const float* __restrict__ norm_b,
    const float* __restrict__ m1w, const float* __restrict__ m1b,
    const float* __restrict__ mhw, const float* __restrict__ mhb,
    const float* __restrict__ mfw, const float* __restrict__ mfb,
    const float* __restrict__ G_h, float* __restrict__ out)
{
  const int n   = blockIdx.x;
  const int tid = threadIdx.x;

  __shared__ __align__(16) float SH[64*36];
  __shared__ __align__(16) float SX[64*36];
  __shared__ __align__(16) float SY[64*68];
  __shared__ __align__(16) float SW[3584];
  __shared__ __align__(16) float SV[320];
  __shared__ __align__(16) float csh[32];
  __shared__ int s_njet;

  if (tid == 0) s_njet = ji[n*2+1];
  for (int idx = tid; idx < 2048; idx += 256) {
    int t = idx>>5, e = idx&31;
    SH[t*36 + e] = G_h[n*2048 + idx];
  }
  __syncthreads();

  ln_rows32(SH, SX, tid);
  if (tid < 32) csh[tid] = cls_tok[tid];
  __syncthreads();

  for (int cl = 0; cl < 2; cl++) {
    const float* iw = cb_in_w + cl*3072;
    const float* ib = cb_in_b + cl*96;

    if (tid < 32) {
      float v = csh[tid];
      float s = v;
      s += __shfl_xor(s,1); s += __shfl_xor(s,2); s += __shfl_xor(s,4); s += __shfl_xor(s,8); s += __shfl_xor(s,16);
      float mean = s * 0.03125f;
      float d = v - mean;
      float q = d*d;
      q += __shfl_xor(q,1); q += __shfl_xor(q,2); q += __shfl_xor(q,4); q += __shfl_xor(q,8); q += __shfl_xor(q,16);
      float irs = rsqrtf(q*0.03125f + 1e-5f);
      SV[tid] = d*irs;
    }
    for (int idx = tid; idx < 3072; idx += 256){ SW[(idx>>5)*36 + (idx&31)] = iw[idx]; }
    for (int idx = tid; idx < 96; idx += 256) SW[3456+idx] = ib[idx];
    __syncthreads();

    if (tid < 32) {
      int e = tid;
      float a_ = SW[3456+e];
      #pragma unroll
      for (int k=0;k<8;k++) a_ += dot4(ld4(&csh[k*4]), ld4(SW + e*36 + k*4));
      SV[32+e] = a_ * 0.35355339059327373f;
    }
    {
      int g = tid & 3;
      for (int s = tid>>2; s < 65; s += 64) {
        const float* u = (s == 0) ? SV : (SX + (s-1)*36);
        float4 uv[8];
        #pragma unroll
        for (int k=0;k<8;k++) uv[k] = ld4(u + k*4);
        #pragma unroll
        for (int ee=0; ee<16; ee++){
          int ew = 32 + g + 4*ee;
          float a_ = SW[3456+ew];
          #pragma unroll
          for (int k=0;k<8;k++) a_ += dot4(uv[k], ld4(SW + ew*36 + k*4));
          if (ew < 64) SY[(ew-32)*68 + s] = a_;
          else         SY[2176 + (ew-64)*68 + s] = a_;
        }
      }
    }
    __syncthreads();

    {
      int hh = tid>>6, l = tid&63;
      int njet = s_njet;
      float q8[8];
      #pragma unroll
      for (int d=0;d<8;d++) q8[d] = SV[32 + hh*8 + d];
      float sc_ = 0.f;
      #pragma unroll
      for (int d=0;d<8;d++) sc_ += q8[d]*SY[(hh*8+d)*68 + l];
      if (l > 0 && (l-1) >= njet) sc_ = -1000000000.0f;
      float sc64 = 0.f;
      if (l == 0){
        #pragma unroll
        for (int d=0;d<8;d++) sc64 += q8[d]*SY[(hh*8+d)*68 + 64];
        if (63 >= njet) sc64 = -1000000000.0f;
      }
      float mx = sc_;
      if (l == 0) mx = fmaxf(mx, sc64);
      mx = fmaxf(mx, __shfl_xor(mx,1));  mx = fmaxf(mx, __shfl_xor(mx,2));
      mx = fmaxf(mx, __shfl_xor(mx,4));  mx = fmaxf(mx, __shfl_xor(mx,8));
      mx = fmaxf(mx, __shfl_xor(mx,16)); mx = fmaxf(mx, __shfl_xor(mx,32));
      float p   = __expf(sc_ - mx);
      float p64 = (l==0) ? __expf(sc64 - mx) : 0.f;
      float ssum = p + p64;
      ssum += __shfl_xor(ssum,1); ssum += __shfl_xor(ssum,2); ssum += __shfl_xor(ssum,4);
      ssum += __shfl_xor(ssum,8); ssum += __shfl_xor(ssum,16); ssum += __shfl_xor(ssum,32);
      float inv = 1.f/ssum;
      #pragma unroll
      for (int d=0;d<8;d++){
        float term = p * SY[2176 + (hh*8+d)*68 + l];
        if (l == 0) term += p64 * SY[2176 + (hh*8+d)*68 + 64];
        term += __shfl_xor(term,1); term += __shfl_xor(term,2); term += __shfl_xor(term,4);
        term += __shfl_xor(term,8); term += __shfl_xor(term,16); term += __shfl_xor(term,32);
        if (l == 0) SV[64 + hh*8 + d] = term*inv;
      }
    }
    __syncthreads();

    if (tid < 32) {
      int e = tid;
      const float* wrow = cb_out_w + (cl*32 + e)*32;
      float a_ = cb_out_b[cl*32 + e];
      #pragma unroll
      for (int j=0;j<32;j++) a_ += SV[64+j]*wrow[j];
      float ca = cb_cattn[cl*4 + (e>>3)];
      SV[96 + (e&7)*4 + (e>>3)] = a_*ca;
    }
    __syncthreads();

    if (tid < 32) {
      float v = SV[96+tid];
      float s = v;
      s += __shfl_xor(s,1); s += __shfl_xor(s,2); s += __shfl_xor(s,4); s += __shfl_xor(s,8); s += __shfl_xor(s,16);
      float mean = s * 0.03125f;
      float d = v - mean;
      float q = d*d;
      q += __shfl_xor(q,1); q += __shfl_xor(q,2); q += __shfl_xor(q,4); q += __shfl_xor(q,8); q += __shfl_xor(q,16);
      float irs = rsqrtf(q*0.03125f + 1e-5f);
      csh[tid] = d*irs + csh[tid];
    }
    __syncthreads();

    if (tid < 32) {
      float v = csh[tid];
      float s = v;
      s += __shfl_xor(s,1); s += __shfl_xor(s,2); s += __shfl_xor(s,4); s += __shfl_xor(s,8); s += __shfl_xor(s,16);
      float mean = s * 0.03125f;
      float d = v - mean;
      float q = d*d;
      q += __shfl_xor(q,1); q += __shfl_xor(q,2); q += __shfl_xor(q,4); q += __shfl_xor(q,8); q += __shfl_xor(q,16);
      float irs = rsqrtf(q*0.03125f + 1e-5f);
      SV[tid] = d*irs;
    }
    __syncthreads();
    if (tid < 64) {
      int o = tid;
      const float* wrow = cb_f1_w + (cl*64+o)*32;
      float a_ = cb_f1_b[cl*64+o];
      #pragma unroll
      for (int j=0;j<32;j++) a_ += SV[j]*wrow[j];
      SV[128+o] = geluf(a_);
    }
    __syncthreads();
    if (tid < 64) {
      float v = SV[128+tid];
      float s = v;
      s += __shfl_xor(s,1); s += __shfl_xor(s,2); s += __shfl_xor(s,4); s += __shfl_xor(s,8);
      s += __shfl_xor(s,16); s += __shfl_xor(s,32);
      float mean = s * 0.015625f;
      float d = v - mean;
      float q = d*d;
      q += __shfl_xor(q,1); q += __shfl_xor(q,2); q += __shfl_xor(q,4); q += __shfl_xor(q,8);
      q += __shfl_xor(q,16); q += __shfl_xor(q,32);
      float irs = rsqrtf(q*0.015625f + 1e-5f);
      SV[192+tid] = d*irs;
    }
    __syncthreads();
    if (tid < 32) {
      int e = tid;
      const float* wrow = cb_f2_w + (cl*32+e)*64;
      float a_ = cb_f2_b[cl*32+e];
      #pragma unroll
      for (int j=0;j<64;j++) a_ += SV[192+j]*wrow[j];
      csh[e] = a_ + cb_wres[cl*32+e]*csh[e];
    }
    __syncthreads();
  }

  if (tid < 32) {
    float v = csh[tid];
    float s = v;
    s += __shfl_xor(s,1); s += __shfl_xor(s,2); s += __shfl_xor(s,4); s += __shfl_xor(s,8); s += __shfl_xor(s,16);
    float mean = s * 0.03125f;
    float d = v - mean;
    float q = d*d;
    q += __shfl_xor(q,1); q += __shfl_xor(q,2); q += __shfl_xor(q,4); q += __shfl_xor(q,8); q += __shfl_xor(q,16);
    float irs = rsqrtf(q*0.03125f + 1e-5f);
    SV[tid] = d*irs*norm_w[tid] + norm_b[tid];
  }
  __syncthreads();
  if (tid < 32) {
    float a_ = m1b[tid];
    const float* wrow = m1w + tid*32;
    #pragma unroll
    for (int j=0;j<32;j++) a_ += SV[j]*wrow[j];
    SV[64+tid] = fmaxf(a_, 0.f);
  }
  __syncthreads();
  if (tid < 32) {
    float a_ = mhb[tid];
    const float* wrow = mhw + tid*32;
    #pragma unroll
    for (int j=0;j<32;j++) a_ += SV[64+j]*wrow[j];
    SV[128+tid] = fmaxf(a_, 0.f);
  }
  __syncthreads();
  if (tid == 0) {
    float a_ = mfb[0];
    #pragma unroll
    for (int j=0;j<32;j++) a_ += SV[128+j]*mfw[j];
    out[n] = 1.f/(1.f + expf(-a_));
  }
}

// ---------------------------------------------------------------------------
extern "C" void kernel_launch(void* const* d_in, const int* in_sizes, int n_in,
                              void* d_out, int out_size, void* d_ws, size_t ws_size,
                              hipStream_t stream) {
  (void)in_sizes; (void)n_in; (void)out_size; (void)ws_size;
  const float* x     = (const float*)d_in[0];
  const float* fm    = (const float*)d_in[1];
  const int*   ji    = (const int*)  d_in[2];
  const float* bn_w  = (const float*)d_in[3];
  const float* bn_b  = (const float*)d_in[4];
  const float* e1w   = (const float*)d_in[5];
  const float* e1b   = (const float*)d_in[6];
  const float* e2w   = (const float*)d_in[7];
  const float* e2b   = (const float*)d_in[8];
  const float* c1w   = (const float*)d_in[9];
  const float* c1b   = (const float*)d_in[10];
  const float* c2w   = (const float*)d_in[11];
  const float* c2b   = (const float*)d_in[12];
  const float* pb_in_w  = (const float*)d_in[13];
  const float* pb_in_b  = (const float*)d_in[14];
  const float* pb_out_w = (const float*)d_in[15];
  const float* pb_out_b = (const float*)d_in[16];
  const float* pb_f1_w  = (const float*)d_in[17];
  const float* pb_f1_b  = (const float*)d_in[18];
  const float* pb_f2_w  = (const float*)d_in[19];
  const float* pb_f2_b  = (const float*)d_in[20];
  const float* pb_wres  = (const float*)d_in[21];
  const float* cb_in_w  = (const float*)d_in[22];
  const float* cb_in_b  = (const float*)d_in[23];
  const float* cb_out_w = (const float*)d_in[24];
  const float* cb_out_b = (const float*)d_in[25];
  const float* cb_f1_w  = (const float*)d_in[26];
  const float* cb_f1_b  = (const float*)d_in[27];
  const float* cb_f2_w  = (const float*)d_in[28];
  const float* cb_f2_b  = (const float*)d_in[29];
  const float* cb_wres  = (const float*)d_in[30];
  const float* cb_cattn = (const float*)d_in[31];
  const float* cls_tok  = (const float*)d_in[32];
  const float* norm_w   = (const float*)d_in[33];
  const float* norm_b   = (const float*)d_in[34];
  const float* m1w      = (const float*)d_in[35];
  const float* m1b      = (const float*)d_in[36];
  const float* mhw      = (const float*)d_in[37];
  const float* mhb      = (const float*)d_in[38];
  const float* mfw      = (const float*)d_in[39];
  const float* mfb      = (const float*)d_in[40];

  float* part   = (float*)d_ws;                 // 32768 floats
  float* stats  = part + 32768;                 // 128 floats
  float* G_h    = part + 40960;                 // 2048*2048 floats
  float* G_bias = G_h + 2048*2048;              // 2048*324 floats

  bn_stats_partial<<<256, 256, 0, stream>>>(x, fm, part);
  bn_stats_final<<<1, 64, 0, stream>>>(part, stats);
  k_feat<<<2048, 256, 0, stream>>>(fm, c1w, c1b, c2w, c2b, G_bias);
  k_embed2<<<2048, 256, 0, stream>>>(x, fm, stats, bn_w, bn_b, e1w, e1b, e2w, e2b, G_h);
  for (int li = 0; li < 4; li++) {
    k_layer<<<2048, 256, 0, stream>>>(ji,
        pb_in_w + li*3072, pb_in_b + li*96,
        pb_out_w + li*1024, pb_out_b + li*32,
        pb_f1_w + li*2048, pb_f1_b + li*64,
        pb_f2_w + li*2048, pb_f2_b + li*32,
        pb_wres + li*32, G_h, G_bias);
  }
  k_cls<<<2048, 256, 0, stream>>>(ji, cb_in_w, cb_in_b, cb_out_w, cb_out_b,
                                  cb_f1_w, cb_f1_b, cb_f2_w, cb_f2_b,
                                  cb_wres, cb_cattn, cls_tok, norm_w, norm_b,
                                  m1w, m1b, mhw, mhb, mfw, mfb, G_h, (float*)d_out);
}

// Round 7
// 585.909 us; speedup vs baseline: 5.7764x; 1.3345x over previous
//
#include <hip/hip_runtime.h>

// ---------------------------------------------------------------------------
// Part_65712999629561: ParticleTransformer forward, N=2048, P=64, E=32, H=4,
// D=8. Split kernels: stats, feat(conv), embed, 4x layer, cls.
// R6 post-mortem: spills gone; k_cls latency-bound (VGPR 204 -> 2 blocks/CU,
// 15% VALUBusy, ~25 barriers around wave-0-only serial sections).
// R7: (1) k_cls C3 -> 4x4 tile + row-0 pass; (2) __launch_bounds__(256,3)
// on embed/layer/cls (VGPR cap 168 -> 3 waves/SIMD; LDS admits 3 blocks/CU);
// (3) drop intra-wave barriers in k_cls serial chain; drop SH from k_cls.
// ---------------------------------------------------------------------------

__device__ __forceinline__ float4 ld4(const float* p){ return *reinterpret_cast<const float4*>(p); }
__device__ __forceinline__ float dot4(float4 a, float4 b){ return a.x*b.x + a.y*b.y + a.z*b.z + a.w*b.w; }
__device__ __forceinline__ float geluf(float v){ return 0.5f*v*(1.0f + erff(v*0.70710678118654752f)); }

// ---------------- Kernel A: batchnorm stats --------------------------------
__global__ void bn_stats_partial(const float* __restrict__ x, const float* __restrict__ fm,
                                 float* __restrict__ part) {
  int p  = threadIdx.x & 63;
  int rg = threadIdx.x >> 6;
  float s = 0.f, s2 = 0.f;
  for (int R = blockIdx.x*4 + rg; R < 2048*64; R += 1024) {
    int n_ = R >> 6, c = R & 63;
    float v = (c < 60) ? x[n_*3840 + c*64 + p] : fm[n_*256 + (c-60)*64 + p];
    s += v; s2 += v*v;
  }
  __shared__ float sm[256], sm2[256];
  sm[threadIdx.x] = s; sm2[threadIdx.x] = s2;
  __syncthreads();
  if (threadIdx.x < 64) {
    part[blockIdx.x*128 + p]      = sm[p]+sm[64+p]+sm[128+p]+sm[192+p];
    part[blockIdx.x*128 + 64 + p] = sm2[p]+sm2[64+p]+sm2[128+p]+sm2[192+p];
  }
}

__global__ void bn_stats_final(const float* __restrict__ part, float* __restrict__ stats) {
  int p = threadIdx.x; // 64 threads
  float s = 0.f, s2 = 0.f;
  for (int b = 0; b < 256; b++){ s += part[b*128+p]; s2 += part[b*128+64+p]; }
  float mean = s * (1.f/131072.f);
  float var  = s2 * (1.f/131072.f) - mean*mean;
  stats[p]      = mean;
  stats[64+p]   = rsqrtf(var + 1e-5f);
}

// ---------------- row-LN helpers (256 threads, 64 rows, 4 lanes/row) --------
__device__ __forceinline__ void ln_rows32(const float* src, float* dst, int tid){
  int r = tid>>2, g = tid&3;
  const float* row = src + r*36;
  float v[8]; float s = 0.f;
  #pragma unroll
  for (int k=0;k<8;k++){ v[k] = row[g*8+k]; s += v[k]; }
  s += __shfl_xor(s,1); s += __shfl_xor(s,2);
  float mean = s * 0.03125f;
  float q = 0.f;
  #pragma unroll
  for (int k=0;k<8;k++){ float d = v[k]-mean; q += d*d; }
  q += __shfl_xor(q,1); q += __shfl_xor(q,2);
  float irs = rsqrtf(q*0.03125f + 1e-5f);
  float* drow = dst + r*36;
  #pragma unroll
  for (int k=0;k<8;k++) drow[g*8+k] = (v[k]-mean)*irs;
}

__device__ __forceinline__ void ln_rows64(const float* src, float* dst, int tid){
  int r = tid>>2, g = tid&3;
  const float* row = src + r*68;
  float v[16]; float s = 0.f;
  #pragma unroll
  for (int k=0;k<16;k++){ v[k] = row[g*16+k]; s += v[k]; }
  s += __shfl_xor(s,1); s += __shfl_xor(s,2);
  float mean = s * 0.015625f;
  float q = 0.f;
  #pragma unroll
  for (int k=0;k<16;k++){ float d = v[k]-mean; q += d*d; }
  q += __shfl_xor(q,1); q += __shfl_xor(q,2);
  float irs = rsqrtf(q*0.015625f + 1e-5f);
  float* drow = dst + r*68;
  #pragma unroll
  for (int k=0;k<16;k++) drow[g*16+k] = (v[k]-mean)*irs;
}

// ============================ K_feat =======================================
__global__ __launch_bounds__(256) void k_feat(
    const float* __restrict__ fm,
    const float* __restrict__ c1w_g, const float* __restrict__ c1b_g,
    const float* __restrict__ c2w_g, const float* __restrict__ c2b_g,
    float* __restrict__ G_bias)
{
  const int n   = blockIdx.x;
  const int tid = threadIdx.x;
  __shared__ float PQ[448];
  __shared__ float C1O[1024];
  __shared__ float CW[328];

  if (tid < 64) {
    int p = tid;
    float e_  = fm[n*256 + p];
    float px_ = fm[n*256 + 64 + p];
    float py_ = fm[n*256 + 128 + p];
    float pz_ = fm[n*256 + 192 + p];
    float pt_ = sqrtf(px_*px_ + py_*py_ + 1e-8f);
    float y_  = 0.5f * logf((e_ + pz_ + 1e-8f) / (e_ - pz_ + 1e-8f));
    float ph_ = atan2f(py_, px_ + 1e-8f);
    if (ph_ < 0.f) ph_ += 6.283185307179586f;
    PQ[0*64+p]=e_; PQ[1*64+p]=px_; PQ[2*64+p]=py_; PQ[3*64+p]=pz_;
    PQ[4*64+p]=pt_; PQ[5*64+p]=y_; PQ[6*64+p]=ph_;
  }
  CW[tid < 256 ? tid : 0] = c1w_g[tid < 256 ? tid : 0];
  if (tid < 4)  CW[256+tid] = c1b_g[tid];
  if (tid < 64) CW[260+tid] = c2w_g[tid];
  if (tid < 4)  CW[324+tid] = c2b_g[tid];
  __syncthreads();

  {
    int ho = tid>>4, wo = tid&15;
    float a0=0.f,a1=0.f,a2=0.f,a3=0.f;
    #pragma unroll 1
    for (int kh=0; kh<4; kh++){
      int r = ho*4+kh;
      float er=PQ[r], pxr=PQ[64+r], pyr=PQ[128+r], pzr=PQ[192+r], ptr_=PQ[256+r], yr=PQ[320+r], phr=PQ[384+r];
      #pragma unroll
      for (int kw=0; kw<4; kw++){
        int c = wo*4+kw;
        if (r == c) continue;
        float ec=PQ[c], pxc=PQ[64+c], pyc=PQ[128+c], pzc=PQ[192+c], ptc=PQ[256+c], yc=PQ[320+c], phc=PQ[384+c];
        float dy = yr-yc, dp = phr-phc;
        float delta = sqrtf(fabsf(dy*dy + dp*dp));
        float pmin = fminf(ptr_, ptc);
        float kt = pmin * delta;
        float zz = pmin / (ptr_ + ptc + 1e-8f);
        float sx_ = pxr+pxc, sy_ = pyr+pyc, sz_ = pzr+pzc;
        float m2 = er*er + ec*ec - (sx_*sx_ + sy_*sy_ + sz_*sz_);
        int wb = kh*4+kw;
        a0 += delta*CW[0*64+wb] + kt*CW[0*64+16+wb] + zz*CW[0*64+32+wb] + m2*CW[0*64+48+wb];
        a1 += delta*CW[1*64+wb] + kt*CW[1*64+16+wb] + zz*CW[1*64+32+wb] + m2*CW[1*64+48+wb];
        a2 += delta*CW[2*64+wb] + kt*CW[2*64+16+wb] + zz*CW[2*64+32+wb] + m2*CW[2*64+48+wb];
        a3 += delta*CW[3*64+wb] + kt*CW[3*64+16+wb] + zz*CW[3*64+32+wb] + m2*CW[3*64+48+wb];
      }
    }
    C1O[0*256 + tid] = a0 + CW[256+0];
    C1O[1*256 + tid] = a1 + CW[256+1];
    C1O[2*256 + tid] = a2 + CW[256+2];
    C1O[3*256 + tid] = a3 + CW[256+3];
  }
  __syncthreads();

  for (int idx = tid; idx < 324; idx += 256) {
    int co = idx/81, rem = idx%81, i = rem/9, j = rem%9;
    float s = CW[324+co];
    #pragma unroll
    for (int ci=0; ci<4; ci++){
      #pragma unroll
      for (int kh=0; kh<2; kh++){
        int ri = 2*i - 1 + kh;
        if (ri < 0 || ri >= 16) continue;
        #pragma unroll
        for (int kw=0; kw<2; kw++){
          int cj = 2*j - 1 + kw;
          if (cj < 0 || cj >= 16) continue;
          s += CW[260 + co*16 + ci*4 + kh*2 + kw] * C1O[ci*256 + ri*16 + cj];
        }
      }
    }
    G_bias[n*324 + idx] = s;
  }
}

// ============================ K_embed2 =====================================
__global__ __launch_bounds__(256, 3) void k_embed2(
    const float* __restrict__ x, const float* __restrict__ fm,
    const float* __restrict__ stats,
    const float* __restrict__ bn_w, const float* __restrict__ bn_b,
    const float* __restrict__ e1w, const float* __restrict__ e1b,
    const float* __restrict__ e2w, const float* __restrict__ e2b,
    float* __restrict__ G_h)
{
  const int n   = blockIdx.x;
  const int tid = threadIdx.x;

  __shared__ __align__(16) float SX[64*68];
  __shared__ __align__(16) float SY[64*68];
  __shared__ __align__(16) float SW[4448];
  __shared__ float SSTAT[128];

  if (tid < 64) {
    float mu = stats[tid], rs = stats[64+tid];
    float sc = rs * bn_w[tid];
    SSTAT[tid]      = sc;
    SSTAT[64+tid]   = bn_b[tid] - mu*sc;
  }
  __syncthreads();

  {
    int p = tid & 63;
    float sc = SSTAT[p], sh = SSTAT[64+p];
    for (int c = tid>>6; c < 64; c += 4) {
      float v = (c < 60) ? x[n*3840 + c*64 + p] : fm[n*256 + (c-60)*64 + p];
      SX[c*68 + p] = v*sc + sh;
    }
  }
  __syncthreads();

  ln_rows64(SX, SY, tid);
  for (int idx = tid; idx < 4096; idx += 256){ SW[(idx>>6)*68 + (idx&63)] = e1w[idx]; }
  for (int idx = tid; idx < 64; idx += 256) SW[4352+idx] = e1b[idx];
  __syncthreads();

  // e1 GEMM 64x64 K=64, 4x4 tile -> SX (stride 68) with gelu
  {
    int tg = tid>>4, og = tid&15;
    float acc[4][4];
    #pragma unroll
    for (int o=0;o<4;o++){ float b = SW[4352+og*4+o];
      #pragma unroll
      for (int i=0;i<4;i++) acc[i][o] = b; }
    #pragma unroll 2
    for (int j=0;j<64;j+=4){
      float4 av[4], wv[4];
      #pragma unroll
      for (int i=0;i<4;i++) av[i] = ld4(SY + (tg*4+i)*68 + j);
      #pragma unroll
      for (int o=0;o<4;o++) wv[o] = ld4(SW + (og*4+o)*68 + j);
      #pragma unroll
      for (int i=0;i<4;i++)
        #pragma unroll
        for (int o=0;o<4;o++) acc[i][o] += dot4(av[i], wv[o]);
    }
    __syncthreads();
    #pragma unroll
    for (int i=0;i<4;i++)
      #pragma unroll
      for (int o=0;o<4;o++) SX[(tg*4+i)*68 + og*4+o] = geluf(acc[i][o]);
  }
  __syncthreads();

  ln_rows64(SX, SY, tid);
  for (int idx = tid; idx < 2048; idx += 256){ SW[(idx>>6)*68 + (idx&63)] = e2w[idx]; }
  for (int idx = tid; idx < 32; idx += 256) SW[4352+idx] = e2b[idx];
  __syncthreads();

  // e2 GEMM 64x32 K=64, 4x2 tile -> G_h with gelu
  {
    int tg = tid>>4, og = tid&15;
    float acc[4][2];
    #pragma unroll
    for (int o=0;o<2;o++){ float b = SW[4352+og*2+o];
      #pragma unroll
      for (int i=0;i<4;i++) acc[i][o] = b; }
    #pragma unroll 2
    for (int j=0;j<64;j+=4){
      float4 av[4], wv[2];
      #pragma unroll
      for (int i=0;i<4;i++) av[i] = ld4(SY + (tg*4+i)*68 + j);
      #pragma unroll
      for (int o=0;o<2;o++) wv[o] = ld4(SW + (og*2+o)*68 + j);
      #pragma unroll
      for (int i=0;i<4;i++)
        #pragma unroll
        for (int o=0;o<2;o++) acc[i][o] += dot4(av[i], wv[o]);
    }
    #pragma unroll
    for (int i=0;i<4;i++)
      #pragma unroll
      for (int o=0;o<2;o++) G_h[n*2048 + (tg*4+i)*32 + og*2+o] = geluf(acc[i][o]);
  }
}

// ============================ K_layer ======================================
__global__ __launch_bounds__(256, 3) void k_layer(
    const int* __restrict__ ji,
    const float* __restrict__ in_w,  const float* __restrict__ in_b,
    const float* __restrict__ out_w, const float* __restrict__ out_b,
    const float* __restrict__ f1w,   const float* __restrict__ f1b,
    const float* __restrict__ f2w,   const float* __restrict__ f2b,
    const float* __restrict__ wres,
    float* __restrict__ G_h, const float* __restrict__ G_bias)
{
  const int n   = blockIdx.x;
  const int tid = threadIdx.x;

  __shared__ __align__(16) float SH[64*36];
  __shared__ __align__(16) float SX[64*36];
  __shared__ __align__(16) float SY[64*68];
  __shared__ __align__(16) float SW[3584];
  __shared__ float SBIAS[324];
  __shared__ int s_njet;

  if (tid == 0) s_njet = ji[n*2+1];
  for (int idx = tid; idx < 2048; idx += 256) {
    int t = idx>>5, e = idx&31;
    SH[t*36 + e] = G_h[n*2048 + idx];
  }
  for (int idx = tid; idx < 324; idx += 256) SBIAS[idx] = G_bias[n*324 + idx];
  __syncthreads();

  // L1: a = ln(h) -> SX; stage in_w (96x32, stride 36) + in_b @3456
  ln_rows32(SH, SX, tid);
  for (int idx = tid; idx < 3072; idx += 256){ SW[(idx>>5)*36 + (idx&31)] = in_w[idx]; }
  for (int idx = tid; idx < 96; idx += 256) SW[3456+idx] = in_b[idx];
  __syncthreads();

  // L2: k,v GEMM 64x64 K=32, 4x4 tile, transposed write into SY
  {
    int tg = tid>>4, og = tid&15;
    float acc[4][4];
    #pragma unroll
    for (int o=0;o<4;o++){ float b = SW[3456+32+og*4+o];
      #pragma unroll
      for (int i=0;i<4;i++) acc[i][o] = b; }
    #pragma unroll 2
    for (int j=0;j<32;j+=4){
      float4 av[4], wv[4];
      #pragma unroll
      for (int i=0;i<4;i++) av[i] = ld4(SX + (tg*4+i)*36 + j);
      #pragma unroll
      for (int o=0;o<4;o++) wv[o] = ld4(SW + (32+og*4+o)*36 + j);
      #pragma unroll
      for (int i=0;i<4;i++)
        #pragma unroll
        for (int o=0;o<4;o++) acc[i][o] += dot4(av[i], wv[o]);
    }
    #pragma unroll
    for (int i=0;i<4;i++)
      #pragma unroll
      for (int o=0;o<4;o++){
        int ew = 32 + og*4+o, t = tg*4+i;
        if (ew < 64) SY[(ew-32)*68 + t] = acc[i][o];
        else         SY[2176 + (ew-64)*68 + t] = acc[i][o];
      }
  }
  __syncthreads();

  // L3: attention (online softmax, runtime chunk loop). wave=head, lane=query.
  float od[8];
  {
    int hh = tid>>6, l = tid&63;
    float qd[8];
    #pragma unroll
    for (int d=0;d<8;d++){
      int e = hh*8+d;
      float a_ = SW[3456+e];
      #pragma unroll
      for (int k=0;k<8;k++) a_ += dot4(ld4(SX + l*36 + k*4), ld4(SW + e*36 + k*4));
      qd[d] = a_ * 0.35355339059327373f;
    }
    int njet = s_njet;
    float m = -3.4e38f, lsum = 0.f;
    #pragma unroll
    for (int d=0;d<8;d++) od[d] = 0.f;
    #pragma unroll 1
    for (int s0 = 0; s0 < 64; s0 += 16) {
      float sc[16];
      #pragma unroll
      for (int j=0;j<16;j++) sc[j]=0.f;
      #pragma unroll
      for (int d=0;d<8;d++){
        const float* kr = SY + (hh*8+d)*68 + s0;
        float qv = qd[d];
        #pragma unroll
        for (int j=0;j<16;j+=4){
          float4 kv4 = ld4(kr+j);
          sc[j]  +=qv*kv4.x; sc[j+1]+=qv*kv4.y;
          sc[j+2]+=qv*kv4.z; sc[j+3]+=qv*kv4.w;
        }
      }
      float cm = -3.4e38f;
      #pragma unroll
      for (int j=0;j<16;j++){
        int s = s0+j;
        float a_ = sc[j];
        if (s0 == 0 && l < 9 && j < 9) a_ += SBIAS[hh*81 + l*9 + j];
        a_ = (s >= njet) ? -1000000000.0f : a_;
        sc[j] = a_;
        cm = fmaxf(cm, a_);
      }
      float nm = fmaxf(m, cm);
      float corr = __expf(m - nm);
      lsum *= corr;
      #pragma unroll
      for (int d=0;d<8;d++) od[d] *= corr;
      #pragma unroll
      for (int j=0;j<16;j++){ sc[j] = __expf(sc[j]-nm); lsum += sc[j]; }
      #pragma unroll
      for (int d=0;d<8;d++){
        const float* vr = SY + 2176 + (hh*8+d)*68 + s0;
        float a_ = 0.f;
        #pragma unroll
        for (int j=0;j<16;j+=4){
          float4 vv = ld4(vr+j);
          a_ += sc[j]*vv.x + sc[j+1]*vv.y + sc[j+2]*vv.z + sc[j+3]*vv.w;
        }
        od[d] += a_;
      }
      m = nm;
    }
    float inv = 1.f/lsum;
    #pragma unroll
    for (int d=0;d<8;d++) od[d] *= inv;
  }
  __syncthreads();
  {
    int hh = tid>>6, l = tid&63;
    #pragma unroll
    for (int d=0;d<8;d++) SX[l*36 + hh*8 + d] = od[d];
  }
  for (int idx = tid; idx < 1024; idx += 256){ SW[(idx>>5)*36 + (idx&31)] = out_w[idx]; }
  for (int idx = tid; idx < 32; idx += 256) SW[3456+idx] = out_b[idx];
  __syncthreads();

  // L4: out-proj 64x32 K=32, 4x2 tile -> SY stride 36
  {
    int tg = tid>>4, og = tid&15;
    float acc[4][2];
    #pragma unroll
    for (int o=0;o<2;o++){ float b = SW[3456+og*2+o];
      #pragma unroll
      for (int i=0;i<4;i++) acc[i][o] = b; }
    #pragma unroll 2
    for (int j=0;j<32;j+=4){
      float4 av[4], wv[2];
      #pragma unroll
      for (int i=0;i<4;i++) av[i] = ld4(SX + (tg*4+i)*36 + j);
      #pragma unroll
      for (int o=0;o<2;o++) wv[o] = ld4(SW + (og*2+o)*36 + j);
      #pragma unroll
      for (int i=0;i<4;i++)
        #pragma unroll
        for (int o=0;o<2;o++) acc[i][o] += dot4(av[i], wv[o]);
    }
    #pragma unroll
    for (int i=0;i<4;i++)
      #pragma unroll
      for (int o=0;o<2;o++) SY[(tg*4+i)*36 + og*2+o] = acc[i][o];
  }
  __syncthreads();

  // L5: h = ln(y) + h
  {
    int r = tid>>2, g = tid&3;
    const float* row = SY + r*36;
    float v[8]; float s = 0.f;
    #pragma unroll
    for (int k=0;k<8;k++){ v[k] = row[g*8+k]; s += v[k]; }
    s += __shfl_xor(s,1); s += __shfl_xor(s,2);
    float mean = s * 0.03125f;
    float q = 0.f;
    #pragma unroll
    for (int k=0;k<8;k++){ float d = v[k]-mean; q += d*d; }
    q += __shfl_xor(q,1); q += __shfl_xor(q,2);
    float irs = rsqrtf(q*0.03125f + 1e-5f);
    #pragma unroll
    for (int k=0;k<8;k++){ int e = g*8+k; SH[r*36+e] = (v[k]-mean)*irs + SH[r*36+e]; }
  }
  __syncthreads();

  // L6: t = ln(h) -> SX; stage f1 (64x32)
  ln_rows32(SH, SX, tid);
  for (int idx = tid; idx < 2048; idx += 256){ SW[(idx>>5)*36 + (idx&31)] = f1w[idx]; }
  for (int idx = tid; idx < 64; idx += 256) SW[3456+idx] = f1b[idx];
  __syncthreads();

  // L7: g1 GEMM 64x64 K=32, 4x4 tile -> SY stride 68 with gelu
  {
    int tg = tid>>4, og = tid&15;
    float acc[4][4];
    #pragma unroll
    for (int o=0;o<4;o++){ float b = SW[3456+og*4+o];
      #pragma unroll
      for (int i=0;i<4;i++) acc[i][o] = b; }
    #pragma unroll 2
    for (int j=0;j<32;j+=4){
      float4 av[4], wv[4];
      #pragma unroll
      for (int i=0;i<4;i++) av[i] = ld4(SX + (tg*4+i)*36 + j);
      #pragma unroll
      for (int o=0;o<4;o++) wv[o] = ld4(SW + (og*4+o)*36 + j);
      #pragma unroll
      for (int i=0;i<4;i++)
        #pragma unroll
        for (int o=0;o<4;o++) acc[i][o] += dot4(av[i], wv[o]);
    }
    #pragma unroll
    for (int i=0;i<4;i++)
      #pragma unroll
      for (int o=0;o<4;o++) SY[(tg*4+i)*68 + og*4+o] = geluf(acc[i][o]);
  }
  __syncthreads();

  // L8: ln64 in-place on SY; stage f2 (32x64, stride 68) + bias + wres
  {
    int r = tid>>2, g = tid&3;
    float* row = SY + r*68;
    float v[16]; float s = 0.f;
    #pragma unroll
    for (int k=0;k<16;k++){ v[k] = row[g*16+k]; s += v[k]; }
    s += __shfl_xor(s,1); s += __shfl_xor(s,2);
    float mean = s * 0.015625f;
    float q = 0.f;
    #pragma unroll
    for (int k=0;k<16;k++){ float d = v[k]-mean; q += d*d; }
    q += __shfl_xor(q,1); q += __shfl_xor(q,2);
    float irs = rsqrtf(q*0.015625f + 1e-5f);
    #pragma unroll
    for (int k=0;k<16;k++) row[g*16+k] = (v[k]-mean)*irs;
  }
  for (int idx = tid; idx < 2048; idx += 256){ SW[(idx>>6)*68 + (idx&63)] = f2w[idx]; }
  for (int idx = tid; idx < 32; idx += 256){ SW[3456+idx] = f2b[idx]; SW[3488+idx] = wres[idx]; }
  __syncthreads();

  // L9: g2 GEMM 64x32 K=64, 4x2 tile; h = g2 + wres*h -> G_h
  {
    int tg = tid>>4, og = tid&15;
    float acc[4][2];
    #pragma unroll
    for (int o=0;o<2;o++){ float b = SW[3456+og*2+o];
      #pragma unroll
      for (int i=0;i<4;i++) acc[i][o] = b; }
    #pragma unroll 2
    for (int j=0;j<64;j+=4){
      float4 av[4], wv[2];
      #pragma unroll
      for (int i=0;i<4;i++) av[i] = ld4(SY + (tg*4+i)*68 + j);
      #pragma unroll
      for (int o=0;o<2;o++) wv[o] = ld4(SW + (og*2+o)*68 + j);
      #pragma unroll
      for (int i=0;i<4;i++)
        #pragma unroll
        for (int o=0;o<2;o++) acc[i][o] += dot4(av[i], wv[o]);
    }
    #pragma unroll
    for (int i=0;i<4;i++)
      #pragma unroll
      for (int o=0;o<2;o++){
        int e = og*2+o, t = tg*4+i;
        G_h[n*2048 + t*32 + e] = acc[i][o] + SW[3488+e]*SH[t*36+e];
      }
  }
}

// ============================ K_cls ========================================
// Both cls layers + head. SX = ln(h) persists; serial chain is wave-0-only
// (no barriers needed inside it).
__global__ __launch_bounds__(256, 3) void k_cls(
    const int* __restrict__ ji,
    const float* __restrict__ cb_in_w, const float* __restrict__ cb_in_b,
    const float* __restrict__ cb_out_w, const float* __restrict__ cb_out_b,
    const float* __restrict__ cb_f1_w, const float* __restrict__ cb_f1_b,
    const float* __restrict__ cb_f2_w, const float* __restrict__ cb_f2_b,
    const float* __restrict__ cb_wres, const float* __restrict__ cb_cattn,
    const float* __restrict__ cls_tok, const float* __restrict__ norm_w, const float* __restrict__ norm_b,
    const float* __restrict__ m1w, const float* __restrict__ m1b,
    const float* __restrict__ mhw, const float* __restrict__ mhb,
    const float* __restrict__ mfw, const float* __restrict__ mfb,
    const float* __restrict__ G_h, float* __restrict__ out)
{
  const int n   = blockIdx.x;
  const int tid = threadIdx.x;

  __shared__ __align__(16) float SX[64*36];
  __shared__ __align__(16) float SY[64*68];
  __shared__ __align__(16) float SW[3584];
  __shared__ __align__(16) float SV[320];
  __shared__ __align__(16) float csh[32];
  __shared__ int s_njet;

  if (tid == 0) s_njet = ji[n*2+1];
  for (int idx = tid; idx < 2048; idx += 256) {
    int t = idx>>5, e = idx&31;
    SX[t*36 + e] = G_h[n*2048 + idx];
  }
  __syncthreads();

  ln_rows32(SX, SX, tid);   // in-place: each lane owns its 8 elements
  if (tid < 32) csh[tid] = cls_tok[tid];
  __syncthreads();

  for (int cl = 0; cl < 2; cl++) {
    const float* iw = cb_in_w + cl*3072;
    const float* ib = cb_in_b + cl*96;

    // C1: u0 = ln(csh) -> SV[0..31] (wave 0)
    if (tid < 32) {
      float v = csh[tid];
      float s = v;
      s += __shfl_xor(s,1); s += __shfl_xor(s,2); s += __shfl_xor(s,4); s += __shfl_xor(s,8); s += __shfl_xor(s,16);
      float mean = s * 0.03125f;
      float d = v - mean;
      float q = d*d;
      q += __shfl_xor(q,1); q += __shfl_xor(q,2); q += __shfl_xor(q,4); q += __shfl_xor(q,8); q += __shfl_xor(q,16);
      float irs = rsqrtf(q*0.03125f + 1e-5f);
      SV[tid] = d*irs;
    }
    for (int idx = tid; idx < 3072; idx += 256){ SW[(idx>>5)*36 + (idx&31)] = iw[idx]; }
    for (int idx = tid; idx < 96; idx += 256) SW[3456+idx] = ib[idx];
    __syncthreads();

    // C2: q from raw cls (wave 0) -> SV[32..63]
    if (tid < 32) {
      int e = tid;
      float a_ = SW[3456+e];
      #pragma unroll
      for (int k=0;k<8;k++) a_ += dot4(ld4(&csh[k*4]), ld4(SW + e*36 + k*4));
      SV[32+e] = a_ * 0.35355339059327373f;
    }
    // C3a: row 0 (u0) k,v by tid<64
    if (tid < 64) {
      int ew = 32 + tid;
      float a_ = SW[3456+ew];
      #pragma unroll
      for (int k=0;k<8;k++) a_ += dot4(ld4(SV + k*4), ld4(SW + ew*36 + k*4));
      if (ew < 64) SY[(ew-32)*68] = a_;
      else         SY[2176 + (ew-64)*68] = a_;
    }
    // C3b: rows 1..64 (= h rows 0..63), 4x4 register tile
    {
      int tg = tid>>4, og = tid&15;
      float acc[4][4];
      #pragma unroll
      for (int o=0;o<4;o++){ float b = SW[3456+32+og*4+o];
        #pragma unroll
        for (int i=0;i<4;i++) acc[i][o] = b; }
      #pragma unroll 2
      for (int j=0;j<32;j+=4){
        float4 av[4], wv[4];
        #pragma unroll
        for (int i=0;i<4;i++) av[i] = ld4(SX + (tg*4+i)*36 + j);
        #pragma unroll
        for (int o=0;o<4;o++) wv[o] = ld4(SW + (32+og*4+o)*36 + j);
        #pragma unroll
        for (int i=0;i<4;i++)
          #pragma unroll
          for (int o=0;o<4;o++) acc[i][o] += dot4(av[i], wv[o]);
      }
      #pragma unroll
      for (int i=0;i<4;i++)
        #pragma unroll
        for (int o=0;o<4;o++){
          int ew = 32 + og*4+o, s = tg*4+i + 1;
          if (ew < 64) SY[(ew-32)*68 + s] = acc[i][o];
          else         SY[2176 + (ew-64)*68 + s] = acc[i][o];
        }
    }
    __syncthreads();

    // C4: attention over 65 keys; wave=head, lane=key (lane0 also key 64)
    {
      int hh = tid>>6, l = tid&63;
      int njet = s_njet;
      float q8[8];
      #pragma unroll
      for (int d=0;d<8;d++) q8[d] = SV[32 + hh*8 + d];
      float sc_ = 0.f;
      #pragma unroll
      for (int d=0;d<8;d++) sc_ += q8[d]*SY[(hh*8+d)*68 + l];
      if (l > 0 && (l-1) >= njet) sc_ = -1000000000.0f;
      float sc64 = 0.f;
      if (l == 0){
        #pragma unroll
        for (int d=0;d<8;d++) sc64 += q8[d]*SY[(hh*8+d)*68 + 64];
        if (63 >= njet) sc64 = -1000000000.0f;
      }
      float mx = sc_;
      if (l == 0) mx = fmaxf(mx, sc64);
      mx = fmaxf(mx, __shfl_xor(mx,1));  mx = fmaxf(mx, __shfl_xor(mx,2));
      mx = fmaxf(mx, __shfl_xor(mx,4));  mx = fmaxf(mx, __shfl_xor(mx,8));
      mx = fmaxf(mx, __shfl_xor(mx,16)); mx = fmaxf(mx, __shfl_xor(mx,32));
      float p   = __expf(sc_ - mx);
      float p64 = (l==0) ? __expf(sc64 - mx) : 0.f;
      float ssum = p + p64;
      ssum += __shfl_xor(ssum,1); ssum += __shfl_xor(ssum,2); ssum += __shfl_xor(ssum,4);
      ssum += __shfl_xor(ssum,8); ssum += __shfl_xor(ssum,16); ssum += __shfl_xor(ssum,32);
      float inv = 1.f/ssum;
      #pragma unroll
      for (int d=0;d<8;d++){
        float term = p * SY[2176 + (hh*8+d)*68 + l];
        if (l == 0) term += p64 * SY[2176 + (hh*8+d)*68 + 64];
        term += __shfl_xor(term,1); term += __shfl_xor(term,2); term += __shfl_xor(term,4);
        term += __shfl_xor(term,8); term += __shfl_xor(term,16); term += __shfl_xor(term,32);
        if (l == 0) SV[64 + hh*8 + d] = term*inv;
      }
    }
    __syncthreads();   // SV[64..95] written by lane0 of waves 0..3

    // ---- serial chain: all wave 0 — no barriers needed between sections ----
    // C5: out proj + cattn permute -> SV[96..127]
    if (tid < 32) {
      int e = tid;
      const float* wrow = cb_out_w + (cl*32 + e)*32;
      float a_ = cb_out_b[cl*32 + e];
      #pragma unroll
      for (int j=0;j<32;j++) a_ += SV[64+j]*wrow[j];
      float ca = cb_cattn[cl*4 + (e>>3)];
      SV[96 + (e&7)*4 + (e>>3)] = a_*ca;
    }
    // C6: cls = ln(a2) + cls
    if (tid < 32) {
      float v = SV[96+tid];
      float s = v;
      s += __shfl_xor(s,1); s += __shfl_xor(s,2); s += __shfl_xor(s,4); s += __shfl_xor(s,8); s += __shfl_xor(s,16);
      float mean = s * 0.03125f;
      float d = v - mean;
      float q = d*d;
      q += __shfl_xor(q,1); q += __shfl_xor(q,2); q += __shfl_xor(q,4); q += __shfl_xor(q,8); q += __shfl_xor(q,16);
      float irs = rsqrtf(q*0.03125f + 1e-5f);
      csh[tid] = d*irs + csh[tid];
    }
    // C7: FFN on cls vector (ln -> f1(gelu) -> ln -> f2 + wres*cls)
    if (tid < 32) {
      float v = csh[tid];
      float s = v;
      s += __shfl_xor(s,1); s += __shfl_xor(s,2); s += __shfl_xor(s,4); s += __shfl_xor(s,8); s += __shfl_xor(s,16);
      float mean = s * 0.03125f;
      float d = v - mean;
      float q = d*d;
      q += __shfl_xor(q,1); q += __shfl_xor(q,2); q += __shfl_xor(q,4); q += __shfl_xor(q,8); q += __shfl_xor(q,16);
      float irs = rsqrtf(q*0.03125f + 1e-5f);
      SV[tid] = d*irs;
    }
    if (tid < 64) {
      int o = tid;
      const float* wrow = cb_f1_w + (cl*64+o)*32;
      float a_ = cb_f1_b[cl*64+o];
      #pragma unroll
      for (int j=0;j<32;j++) a_ += SV[j]*wrow[j];
      SV[128+o] = geluf(a_);
    }
    if (tid < 64) {
      float v = SV[128+tid];
      float s = v;
      s += __shfl_xor(s,1); s += __shfl_xor(s,2); s += __shfl_xor(s,4); s += __shfl_xor(s,8);
      s += __shfl_xor(s,16); s += __shfl_xor(s,32);
      float mean = s * 0.015625f;
      float d = v - mean;
      float q = d*d;
      q += __shfl_xor(q,1); q += __shfl_xor(q,2); q += __shfl_xor(q,4); q += __shfl_xor(q,8);
      q += __shfl_xor(q,16); q += __shfl_xor(q,32);
      float irs = rsqrtf(q*0.015625f + 1e-5f);
      SV[192+tid] = d*irs;
    }
    if (tid < 32) {
      int e = tid;
      const float* wrow = cb_f2_w + (cl*32+e)*64;
      float a_ = cb_f2_b[cl*32+e];
      #pragma unroll
      for (int j=0;j<64;j++) a_ += SV[192+j]*wrow[j];
      csh[e] = a_ + cb_wres[cl*32+e]*csh[e];
    }
    // next iteration's staging barrier provides cross-wave sync
  }

  // head: all wave 0, no barriers
  if (tid < 32) {
    float v = csh[tid];
    float s = v;
    s += __shfl_xor(s,1); s += __shfl_xor(s,2); s += __shfl_xor(s,4); s += __shfl_xor(s,8); s += __shfl_xor(s,16);
    float mean = s * 0.03125f;
    float d = v - mean;
    float q = d*d;
    q += __shfl_xor(q,1); q += __shfl_xor(q,2); q += __shfl_xor(q,4); q += __shfl_xor(q,8); q += __shfl_xor(q,16);
    float irs = rsqrtf(q*0.03125f + 1e-5f);
    SV[tid] = d*irs*norm_w[tid] + norm_b[tid];
  }
  if (tid < 32) {
    float a_ = m1b[tid];
    const float* wrow = m1w + tid*32;
    #pragma unroll
    for (int j=0;j<32;j++) a_ += SV[j]*wrow[j];
    SV[64+tid] = fmaxf(a_, 0.f);
  }
  if (tid < 32) {
    float a_ = mhb[tid];
    const float* wrow = mhw + tid*32;
    #pragma unroll
    for (int j=0;j<32;j++) a_ += SV[64+j]*wrow[j];
    SV[128+tid] = fmaxf(a_, 0.f);
  }
  if (tid == 0) {
    float a_ = mfb[0];
    #pragma unroll
    for (int j=0;j<32;j++) a_ += SV[128+j]*mfw[j];
    out[n] = 1.f/(1.f + expf(-a_));
  }
}

// ---------------------------------------------------------------------------
extern "C" void kernel_launch(void* const* d_in, const int* in_sizes, int n_in,
                              void* d_out, int out_size, void* d_ws, size_t ws_size,
                              hipStream_t stream) {
  (void)in_sizes; (void)n_in; (void)out_size; (void)ws_size;
  const float* x     = (const float*)d_in[0];
  const float* fm    = (const float*)d_in[1];
  const int*   ji    = (const int*)  d_in[2];
  const float* bn_w  = (const float*)d_in[3];
  const float* bn_b  = (const float*)d_in[4];
  const float* e1w   = (const float*)d_in[5];
  const float* e1b   = (const float*)d_in[6];
  const float* e2w   = (const float*)d_in[7];
  const float* e2b   = (const float*)d_in[8];
  const float* c1w   = (const float*)d_in[9];
  const float* c1b   = (const float*)d_in[10];
  const float* c2w   = (const float*)d_in[11];
  const float* c2b   = (const float*)d_in[12];
  const float* pb_in_w  = (const float*)d_in[13];
  const float* pb_in_b  = (const float*)d_in[14];
  const float* pb_out_w = (const float*)d_in[15];
  const float* pb_out_b = (const float*)d_in[16];
  const float* pb_f1_w  = (const float*)d_in[17];
  const float* pb_f1_b  = (const float*)d_in[18];
  const float* pb_f2_w  = (const float*)d_in[19];
  const float* pb_f2_b  = (const float*)d_in[20];
  const float* pb_wres  = (const float*)d_in[21];
  const float* cb_in_w  = (const float*)d_in[22];
  const float* cb_in_b  = (const float*)d_in[23];
  const float* cb_out_w = (const float*)d_in[24];
  const float* cb_out_b = (const float*)d_in[25];
  const float* cb_f1_w  = (const float*)d_in[26];
  const float* cb_f1_b  = (const float*)d_in[27];
  const float* cb_f2_w  = (const float*)d_in[28];
  const float* cb_f2_b  = (const float*)d_in[29];
  const float* cb_wres  = (const float*)d_in[30];
  const float* cb_cattn = (const float*)d_in[31];
  const float* cls_tok  = (const float*)d_in[32];
  const float* norm_w   = (const float*)d_in[33];
  const float* norm_b   = (const float*)d_in[34];
  const float* m1w      = (const float*)d_in[35];
  const float* m1b      = (const float*)d_in[36];
  const float* mhw      = (const float*)d_in[37];
  const float* mhb      = (const float*)d_in[38];
  const float* mfw      = (const float*)d_in[39];
  const float* mfb      = (const float*)d_in[40];

  float* part   = (float*)d_ws;                 // 32768 floats
  float* stats  = part + 32768;                 // 128 floats
  float* G_h    = part + 40960;                 // 2048*2048 floats
  float* G_bias = G_h + 2048*2048;              // 2048*324 floats

  bn_stats_partial<<<256, 256, 0, stream>>>(x, fm, part);
  bn_stats_final<<<1, 64, 0, stream>>>(part, stats);
  k_feat<<<2048, 256, 0, stream>>>(fm, c1w, c1b, c2w, c2b, G_bias);
  k_embed2<<<2048, 256, 0, stream>>>(x, fm, stats, bn_w, bn_b, e1w, e1b, e2w, e2b, G_h);
  for (int li = 0; li < 4; li++) {
    k_layer<<<2048, 256, 0, stream>>>(ji,
        pb_in_w + li*3072, pb_in_b + li*96,
        pb_out_w + li*1024, pb_out_b + li*32,
        pb_f1_w + li*2048, pb_f1_b + li*64,
        pb_f2_w + li*2048, pb_f2_b + li*32,
        pb_wres + li*32, G_h, G_bias);
  }
  k_cls<<<2048, 256, 0, stream>>>(ji, cb_in_w, cb_in_b, cb_out_w, cb_out_b,
                                  cb_f1_w, cb_f1_b, cb_f2_w, cb_f2_b,
                                  cb_wres, cb_cattn, cls_tok, norm_w, norm_b,
                                  m1w, m1b, mhw, mhb, mfw, mfb, G_h, (float*)d_out);
}